// Round 1
// 541.435 us; speedup vs baseline: 1.3518x; 1.3518x over previous
//
#include <hip/hip_runtime.h>
#include <hip/hip_bf16.h>

#define N_NODES    100000
#define N_EDGES    1600000
#define IN_CH      128
#define HID        64
#define N_LAYERS   4
#define OUT_CH     10
#define NUM_GRAPHS 128
#define BN_EPS     1e-5f
#define CAP        64             // padded CSR row capacity; P(deg>64) ~ 1e-19 at Poisson(16)
#define NREP       8              // pooled replicas (cuts per-address atomic chains 8x)
#define NBKT       256            // dst>>9 -> buckets 0..195 (256 slots for pow2 LDS)
#define EPB        2048           // edges per block in partition kernels
#define PNB        782            // ceil(1.6M / 2048)

typedef __hip_bfloat16 bf16;
typedef unsigned int uint32;

__device__ __forceinline__ float bf2f(bf16 v) { return __bfloat162float(v); }
// unpack packed bf16x2 dword -> float2 (bf16 -> f32 is <<16)
__device__ __forceinline__ float2 unpk(uint32 p) {
    float2 r;
    r.x = __uint_as_float(p << 16);
    r.y = __uint_as_float(p & 0xffff0000u);
    return r;
}

// ---------------- zero the counter/accumulator region ------------------------
__global__ void zero_i(int* __restrict__ p, int n) {
    int i = blockIdx.x * 256 + threadIdx.x;
    int st = gridDim.x * 256;
    for (; i < n; i += st) p[i] = 0;
}

// ---------------- bucket histogram (LDS-aggregated) --------------------------
__global__ void bhist(const int* __restrict__ dst, int* __restrict__ ghist) {
    __shared__ int h[NBKT];
    int t = threadIdx.x;
    h[t] = 0;
    __syncthreads();
    long base = (long)blockIdx.x * EPB;
    for (int u = 0; u < 8; u++) {
        long e = base + u * 256 + t;
        if (e < N_EDGES) atomicAdd(&h[dst[e] >> 9], 1);
    }
    __syncthreads();
    if (h[t]) atomicAdd(&ghist[t], h[t]);
}

// ---------------- bucket scan + cntg (binary search) + ybf pad-row zero ------
__global__ void bscan(const int* __restrict__ ghist, int* __restrict__ gcursor,
                      const int* __restrict__ batch, int* __restrict__ cntg,
                      bf16* __restrict__ ybfA, bf16* __restrict__ ybfB) {
    __shared__ int sh[NBKT];
    int t = threadIdx.x;                          // 256 threads
    int v = ghist[t];
    sh[t] = v;
    __syncthreads();
    for (int off = 1; off < NBKT; off <<= 1) {
        int a = (t >= off) ? sh[t - off] : 0;
        __syncthreads();
        sh[t] += a;
        __syncthreads();
    }
    gcursor[t] = sh[t] - v;                       // exclusive bucket base
    if (t < NUM_GRAPHS) {                         // per-graph node counts
        int g = t, lo = 0, hi = N_NODES;
        while (lo < hi) { int m = (lo + hi) >> 1; if (batch[m] < g) lo = m + 1; else hi = m; }
        int lb = lo;
        lo = 0; hi = N_NODES;
        while (lo < hi) { int m = (lo + hi) >> 1; if (batch[m] < g + 1) lo = m + 1; else hi = m; }
        cntg[g] = lo - lb;
    }
    if (t < HID) {                                // sentinel zero-row for tail-free gather
        ybfA[(long)N_NODES * HID + t] = __float2bfloat16(0.f);
        ybfB[(long)N_NODES * HID + t] = __float2bfloat16(0.f);
    }
}

// ---------------- partition edges into bucket order --------------------------
__global__ void bpart(const int* __restrict__ src, const int* __restrict__ dst,
                      int* __restrict__ gcursor, int2* __restrict__ epart) {
    __shared__ int h[NBKT];
    __shared__ int cur[NBKT];
    int t = threadIdx.x;
    h[t] = 0;
    __syncthreads();
    long base = (long)blockIdx.x * EPB;
    int myd[8], mys[8];
    for (int u = 0; u < 8; u++) {
        long e = base + u * 256 + t;
        if (e < N_EDGES) {
            myd[u] = dst[e];
            mys[u] = src[e];
            atomicAdd(&h[myd[u] >> 9], 1);
        } else myd[u] = -1;
    }
    __syncthreads();
    if (h[t]) cur[t] = atomicAdd(&gcursor[t], h[t]);
    __syncthreads();
    for (int u = 0; u < 8; u++) {
        if (myd[u] >= 0) {
            int pos = atomicAdd(&cur[myd[u] >> 9], 1);
            epart[pos] = make_int2(mys[u], myd[u]);
        }
    }
}

// ---------------- fill padded CSR from bucket-sorted edges -------------------
__global__ void fillp(const int2* __restrict__ epart, int* __restrict__ cnt,
                      int* __restrict__ col) {
    int t = threadIdx.x;
    long base = (long)blockIdx.x * EPB;
    for (int u = 0; u < 8; u++) {
        long e = base + u * 256 + t;
        if (e < N_EDGES) {
            int2 p = epart[e];
            int slot = atomicAdd(&cnt[p.y], 1);
            col[p.y * CAP + slot] = p.x;
        }
    }
}

// ---------------- pad each row to a multiple of 32 with sentinel -------------
__global__ void pad_rows(const int* __restrict__ cnt, int* __restrict__ col) {
    int n = blockIdx.x * 256 + threadIdx.x;       // 391 blocks
    if (n >= N_NODES) return;
    int c = cnt[n];
    int c32 = (c + 31) & ~31;
    for (int s = c; s < c32; s++) col[n * CAP + s] = N_NODES;
}

// ---------------- layer-0 pre-projection: ybf = bf16(x @ W1f) (no bias) ------
// 4 nodes per wave: W1 column loads amortized 4x.
__global__ void proj0(const float* __restrict__ x, const float* __restrict__ W1,
                      bf16* __restrict__ ybf) {
    __shared__ float xsh[4][4][IN_CH];            // 8 KB
    const int wave = threadIdx.x >> 6, lane = threadIdx.x & 63;
    const int nb = blockIdx.x * 16 + wave * 4;    // 6250 * 16 == 100000
    #pragma unroll
    for (int r = 0; r < 4; r++) {
        float2 v = ((const float2*)(x + (long)(nb + r) * IN_CH))[lane];
        xsh[wave][r][2 * lane]     = v.x;         // 2-way bank alias: free
        xsh[wave][r][2 * lane + 1] = v.y;
    }
    // per-wave LDS slice: wave-lockstep + compiler lgkmcnt; no barrier
    float a0 = 0.f, a1 = 0.f, a2 = 0.f, a3 = 0.f;
    for (int k = 0; k < IN_CH; k += 4) {
        float4 q0 = *(const float4*)&xsh[wave][0][k];
        float4 q1 = *(const float4*)&xsh[wave][1][k];
        float4 q2 = *(const float4*)&xsh[wave][2][k];
        float4 q3 = *(const float4*)&xsh[wave][3][k];
        float w0 = W1[(k + 0) * 64 + lane];
        float w1 = W1[(k + 1) * 64 + lane];
        float w2 = W1[(k + 2) * 64 + lane];
        float w3 = W1[(k + 3) * 64 + lane];
        a0 += q0.x * w0 + q0.y * w1 + q0.z * w2 + q0.w * w3;
        a1 += q1.x * w0 + q1.y * w1 + q1.z * w2 + q1.w * w3;
        a2 += q2.x * w0 + q2.y * w1 + q2.z * w2 + q2.w * w3;
        a3 += q3.x * w0 + q3.y * w1 + q3.z * w2 + q3.w * w3;
    }
    ybf[(long)(nb + 0) * 64 + lane] = __float2bfloat16(a0);
    ybf[(long)(nb + 1) * 64 + lane] = __float2bfloat16(a1);
    ybf[(long)(nb + 2) * 64 + lane] = __float2bfloat16(a2);
    ybf[(long)(nb + 3) * 64 + lane] = __float2bfloat16(a3);
}

// ---------------- fused layer: dual-row gather -> relu -> W2 -> pool (+W1n) --
// RESTRUCTURED: each wave owns 4 nodes (block = 4 waves = 16 nodes).
// Gather per node is unchanged (lanes 0-31 row c0, lanes 32-63 row c1, packed
// bf16x2). The two 64x64 MLP matmuls are done jointly for the wave's 4 nodes:
// each W2/W1n dword is loaded ONCE per wave and applied to 4 accumulators,
// cutting per-CU L1 weight traffic 4x (12.5 MB -> 3.1 MB per layer) and
// weight-load instructions per node 128 -> 32. Numerics identical (f32 wts).
template <bool HAS_NEXT>
__global__ __launch_bounds__(256, 6)
void layer_fused(const bf16* __restrict__ ybf, const int* __restrict__ cnt,
                 const int* __restrict__ col, const int* __restrict__ batch,
                 const float* __restrict__ b1, const float* __restrict__ W2,
                 const float* __restrict__ b2, const float* __restrict__ W1n,
                 bf16* __restrict__ ynext, float* __restrict__ pooled_l) {
    __shared__ float csh[4][2][2 * HID];          // per-wave half-sum exchange (reused per r)
    __shared__ float tsh[4][4][HID];              // t rows (4 waves x 4 nodes)
    __shared__ float hsh[4][4][HID];              // h rows for the W1n matmul
    __shared__ float psh[4][HID];                 // per-wave pooling partials
    const int wave = threadIdx.x >> 6, lane = threadIdx.x & 63;
    const int hl = lane & 31;
    const bool hi = lane >= 32;
    const int nA = blockIdx.x * 16;               // 6250 blocks
    const int nW = nA + wave * 4;                 // this wave's first node
    const uint32* yrow = (const uint32*)ybf;

    // ---- phase 1: gather + t = relu(y_self + b1 + agg) for 4 nodes ----
    #pragma unroll
    for (int r = 0; r < 4; r++) {
        const int n = __builtin_amdgcn_readfirstlane(nW + r);
        const int deg32 = __builtin_amdgcn_readfirstlane((cnt[n] + 31) & ~31);
        const long s = (long)n * CAP;
        float2 a0 = {0.f, 0.f}, a1 = {0.f, 0.f}, a2 = {0.f, 0.f}, a3 = {0.f, 0.f};
        for (int i = 0; i < deg32; i += 32) {
            uint32 p[16];
            #pragma unroll
            for (int u = 0; u < 16; u++) {
                int c0 = __builtin_amdgcn_readfirstlane(col[s + i + 2 * u]);
                int c1 = __builtin_amdgcn_readfirstlane(col[s + i + 2 * u + 1]);
                int c = hi ? c1 : c0;
                p[u] = yrow[(long)c * 32 + hl];
            }
            #pragma unroll
            for (int u = 0; u < 16; u++) {
                float2 f = unpk(p[u]);
                if ((u & 3) == 0)      { a0.x += f.x; a0.y += f.y; }
                else if ((u & 3) == 1) { a1.x += f.x; a1.y += f.y; }
                else if ((u & 3) == 2) { a2.x += f.x; a2.y += f.y; }
                else                   { a3.x += f.x; a3.y += f.y; }
            }
        }
        float2 hs;
        hs.x = (a0.x + a1.x) + (a2.x + a3.x);
        hs.y = (a0.y + a1.y) + (a2.y + a3.y);
        ((float2*)&csh[wave][hi ? 1 : 0][0])[hl] = hs;   // channels (2hl, 2hl+1)
        // per-wave LDS slice: lockstep + compiler lgkmcnt; no barrier
        float t = bf2f(ybf[(long)n * 64 + lane]) + b1[lane]
                + csh[wave][0][lane] + csh[wave][1][lane];
        tsh[wave][r][lane] = fmaxf(t, 0.f);
    }

    // ---- phase 2: h = relu(t @ W2 + b2), weights loaded once per wave ----
    float hv[4];
    {
        const float bb = b2[lane];
        float h0 = bb, h1 = bb, h2 = bb, h3 = bb;
        for (int k = 0; k < 64; k += 4) {
            float4 t0 = *(const float4*)&tsh[wave][0][k];
            float4 t1 = *(const float4*)&tsh[wave][1][k];
            float4 t2 = *(const float4*)&tsh[wave][2][k];
            float4 t3 = *(const float4*)&tsh[wave][3][k];
            float w0 = W2[(k + 0) * 64 + lane];
            float w1 = W2[(k + 1) * 64 + lane];
            float w2 = W2[(k + 2) * 64 + lane];
            float w3 = W2[(k + 3) * 64 + lane];
            h0 += t0.x * w0 + t0.y * w1 + t0.z * w2 + t0.w * w3;
            h1 += t1.x * w0 + t1.y * w1 + t1.z * w2 + t1.w * w3;
            h2 += t2.x * w0 + t2.y * w1 + t2.z * w2 + t2.w * w3;
            h3 += t3.x * w0 + t3.y * w1 + t3.z * w2 + t3.w * w3;
        }
        hv[0] = fmaxf(h0, 0.f); hv[1] = fmaxf(h1, 0.f);
        hv[2] = fmaxf(h2, 0.f); hv[3] = fmaxf(h3, 0.f);
    }
    #pragma unroll
    for (int r = 0; r < 4; r++) hsh[wave][r][lane] = hv[r];

    // ---- phase 3: ynext = h @ W1n (next layer's first linear, no bias) ----
    if (HAS_NEXT) {               // reads only own wave's hsh slice: no barrier
        float y0 = 0.f, y1 = 0.f, y2 = 0.f, y3 = 0.f;
        for (int k = 0; k < 64; k += 4) {
            float4 g0 = *(const float4*)&hsh[wave][0][k];
            float4 g1 = *(const float4*)&hsh[wave][1][k];
            float4 g2 = *(const float4*)&hsh[wave][2][k];
            float4 g3 = *(const float4*)&hsh[wave][3][k];
            float w0 = W1n[(k + 0) * 64 + lane];
            float w1 = W1n[(k + 1) * 64 + lane];
            float w2 = W1n[(k + 2) * 64 + lane];
            float w3 = W1n[(k + 3) * 64 + lane];
            y0 += g0.x * w0 + g0.y * w1 + g0.z * w2 + g0.w * w3;
            y1 += g1.x * w0 + g1.y * w1 + g1.z * w2 + g1.w * w3;
            y2 += g2.x * w0 + g2.y * w1 + g2.z * w2 + g2.w * w3;
            y3 += g3.x * w0 + g3.y * w1 + g3.z * w2 + g3.w * w3;
        }
        ynext[(long)(nW + 0) * 64 + lane] = __float2bfloat16(y0);
        ynext[(long)(nW + 1) * 64 + lane] = __float2bfloat16(y1);
        ynext[(long)(nW + 2) * 64 + lane] = __float2bfloat16(y2);
        ynext[(long)(nW + 3) * 64 + lane] = __float2bfloat16(y3);
    }

    // ---- pooling: 16 nodes -> 1 atomic when block is graph-uniform ----
    const int gA = __builtin_amdgcn_readfirstlane(batch[nA]);
    const int gZ = __builtin_amdgcn_readfirstlane(batch[nA + 15]);
    float* rep = pooled_l + (long)(blockIdx.x & (NREP - 1)) * NUM_GRAPHS * HID;
    if (gA == gZ) {               // ~98% of blocks: whole block same graph
        psh[wave][lane] = (hv[0] + hv[1]) + (hv[2] + hv[3]);
        __syncthreads();
        if (wave == 0) {
            float ssum = (psh[0][lane] + psh[1][lane]) + (psh[2][lane] + psh[3][lane]);
            atomicAdd(&rep[gA * 64 + lane], ssum);
        }
    } else {                      // graph boundary inside block: per-node atomics
        #pragma unroll
        for (int r = 0; r < 4; r++) {
            const int g = __builtin_amdgcn_readfirstlane(batch[nW + r]);
            atomicAdd(&rep[g * 64 + lane], hv[r]);
        }
    }
}

// ---------------- JK projection on pooled sums (exact: pooling is linear) ----
__global__ void jk_pool(const float* __restrict__ pooled, const int* __restrict__ cntg,
                        const float* __restrict__ Wjk, const float* __restrict__ bjk,
                        float* __restrict__ pooled_jk) {
    __shared__ float sh[64];
    int g = blockIdx.x, j = threadIdx.x;          // 128 blocks x 64 threads (1 wave)
    float acc = (float)cntg[g] * bjk[j];
    for (int l = 0; l < N_LAYERS; l++) {
        float s = 0.f;
        for (int r = 0; r < NREP; r++)
            s += pooled[((long)(l * NREP + r) * NUM_GRAPHS + g) * 64 + j];
        sh[j] = s;                                // single wave: lockstep, no barrier
        const float* W = Wjk + (long)l * HID * 64;
        for (int k = 0; k < 64; k++) acc += sh[k] * W[k * 64 + j];
    }
    pooled_jk[g * 64 + j] = acc;
}

// ---------------- classifier: Linear -> BN(batch stats) -> ReLU -> Linear ----
__global__ void cls_all(const float* __restrict__ pooled_jk,
                        const float* __restrict__ Wc1, const float* __restrict__ bc1,
                        const float* __restrict__ gamma, const float* __restrict__ beta,
                        const float* __restrict__ Wc2, const float* __restrict__ bc2,
                        float* __restrict__ out) {
    __shared__ float Z[NUM_GRAPHS * HID];         // 32 KB
    __shared__ float mu[HID], rs[HID];
    int tid = threadIdx.x;                        // 256

    for (int i = tid; i < NUM_GRAPHS * HID; i += 256) {
        int g = i >> 6, j = i & 63;
        float acc = bc1[j];
        for (int k = 0; k < 64; k++) acc += pooled_jk[g * 64 + k] * Wc1[k * 64 + j];
        Z[i] = acc;
    }
    __syncthreads();
    if (tid < HID) {
        float s = 0.f, sq = 0.f;
        for (int g = 0; g < NUM_GRAPHS; g++) {
            float v = Z[g * 64 + tid];
            s += v; sq += v * v;
        }
        float m = s / NUM_GRAPHS;
        mu[tid] = m;
        rs[tid] = rsqrtf(sq / NUM_GRAPHS - m * m + BN_EPS);
    }
    __syncthreads();
    for (int i = tid; i < NUM_GRAPHS * OUT_CH; i += 256) {
        int g = i / OUT_CH, o = i % OUT_CH;
        float acc = bc2[o];
        for (int j = 0; j < 64; j++) {
            float v = (Z[g * 64 + j] - mu[j]) * rs[j] * gamma[j] + beta[j];
            acc += fmaxf(v, 0.f) * Wc2[j * OUT_CH + o];
        }
        out[i] = acc;
    }
}

// -----------------------------------------------------------------------------
extern "C" void kernel_launch(void* const* d_in, const int* in_sizes, int n_in,
                              void* d_out, int out_size, void* d_ws, size_t ws_size,
                              hipStream_t stream) {
    const float* x     = (const float*)d_in[0];
    const int*   ei    = (const int*)d_in[1];
    const int*   batch = (const int*)d_in[2];
    const float* W1f   = (const float*)d_in[3];
    const float* b1f   = (const float*)d_in[4];
    const float* W2f   = (const float*)d_in[5];
    const float* b2f   = (const float*)d_in[6];
    const float* W1r   = (const float*)d_in[7];
    const float* b1r   = (const float*)d_in[8];
    const float* W2r   = (const float*)d_in[9];
    const float* b2r   = (const float*)d_in[10];
    const float* Wjk   = (const float*)d_in[11];
    const float* bjk   = (const float*)d_in[12];
    const float* Wc1   = (const float*)d_in[13];
    const float* bc1   = (const float*)d_in[14];
    const float* gamma = (const float*)d_in[15];
    const float* beta  = (const float*)d_in[16];
    const float* Wc2   = (const float*)d_in[17];
    const float* bc2   = (const float*)d_in[18];

    const int* src = ei;
    const int* dst = ei + N_EDGES;

    // workspace layout (all segments 8-B aligned)
    float* ws        = (float*)d_ws;
    float* pooled_jk = ws;                                      // 8192 floats
    bf16*  ybfA      = (bf16*)(pooled_jk + NUM_GRAPHS * HID);   // (N+1)*64 bf16
    bf16*  ybfB      = ybfA + (long)(N_NODES + 1) * HID;        // (N+1)*64 bf16
    int*   cnt       = (int*)(ybfB + (long)(N_NODES + 1) * HID);// 100000
    float* pooled    = (float*)(cnt + N_NODES);                 // 4*8*8192 floats
    int*   ghist     = (int*)(pooled + (long)N_LAYERS * NREP * NUM_GRAPHS * HID); // 256
    int*   gcursor   = ghist + NBKT;                            // 256
    int*   cntg      = gcursor + NBKT;                          // 128
    int*   col       = cntg + NUM_GRAPHS;                       // 6.4M ints
    int2*  epart     = (int2*)(col + (long)N_NODES * CAP);      // 1.6M int2
    const int ZN = N_NODES + N_LAYERS * NREP * NUM_GRAPHS * HID + 2 * NBKT;

    // ---- CSR build: zero -> bucket hist -> scan -> partition -> fill -> pad --
    zero_i<<<360, 256, 0, stream>>>(cnt, ZN);
    bhist<<<PNB, 256, 0, stream>>>(dst, ghist);
    bscan<<<1, 256, 0, stream>>>(ghist, gcursor, batch, cntg, ybfA, ybfB);
    bpart<<<PNB, 256, 0, stream>>>(src, dst, gcursor, epart);
    fillp<<<PNB, 256, 0, stream>>>(epart, cnt, col);
    pad_rows<<<(N_NODES + 255) / 256, 256, 0, stream>>>(cnt, col);

    // ---- layer-0 pre-projection (dense, streaming; 4 nodes/wave) ----
    proj0<<<N_NODES / 16, 256, 0, stream>>>(x, W1f, ybfA);

    // ---- 4 fused layers (16 nodes per block: 4 waves x 4 nodes/wave) ----
    const int NB = N_NODES / 16;                                // 6250
    const long PL = (long)NREP * NUM_GRAPHS * HID;
    layer_fused<true><<<NB, 256, 0, stream>>>(
        ybfA, cnt, col, batch, b1f, W2f, b2f,
        W1r, ybfB, pooled);
    layer_fused<true><<<NB, 256, 0, stream>>>(
        ybfB, cnt, col, batch, b1r, W2r, b2r,
        W1r + (long)1 * HID * HID, ybfA, pooled + 1 * PL);
    layer_fused<true><<<NB, 256, 0, stream>>>(
        ybfA, cnt, col, batch, b1r + HID, W2r + (long)1 * HID * HID, b2r + HID,
        W1r + (long)2 * HID * HID, ybfB, pooled + 2 * PL);
    layer_fused<false><<<NB, 256, 0, stream>>>(
        ybfB, cnt, col, batch, b1r + 2 * HID, W2r + (long)2 * HID * HID, b2r + 2 * HID,
        nullptr, nullptr, pooled + 3 * PL);

    // ---- JK on pooled sums + classifier ----
    jk_pool<<<NUM_GRAPHS, 64, 0, stream>>>(pooled, cntg, Wjk, bjk, pooled_jk);
    cls_all<<<1, 256, 0, stream>>>(pooled_jk, Wc1, bc1, gamma, beta, Wc2, bc2,
                                   (float*)d_out);
}

// Round 2
// 480.887 us; speedup vs baseline: 1.5220x; 1.1259x over previous
//
#include <hip/hip_runtime.h>
#include <hip/hip_bf16.h>

#define N_NODES    100000
#define N_EDGES    1600000
#define IN_CH      128
#define HID        64
#define N_LAYERS   4
#define OUT_CH     10
#define NUM_GRAPHS 128
#define BN_EPS     1e-5f
#define CAP        64             // padded CSR row capacity; P(deg>64) ~ 1e-19 at Poisson(16)
#define NREP       8              // pooled replicas (cuts per-address atomic chains 8x)
#define NBKT       256            // dst>>9 -> buckets 0..195 (256 slots for pow2 LDS)
#define EPB        2048           // edges per block in partition kernels
#define PNB        782            // ceil(1.6M / 2048)

typedef __hip_bfloat16 bf16;
typedef unsigned int uint32;

__device__ __forceinline__ float bf2f(bf16 v) { return __bfloat162float(v); }
// unpack packed bf16x2 dword -> float2 (bf16 -> f32 is <<16)
__device__ __forceinline__ float2 unpk(uint32 p) {
    float2 r;
    r.x = __uint_as_float(p << 16);
    r.y = __uint_as_float(p & 0xffff0000u);
    return r;
}

// ---------------- zero the counter/accumulator region ------------------------
__global__ void zero_i(int* __restrict__ p, int n) {
    int i = blockIdx.x * 256 + threadIdx.x;
    int st = gridDim.x * 256;
    for (; i < n; i += st) p[i] = 0;
}

// ---------------- bucket histogram (LDS-aggregated) --------------------------
__global__ void bhist(const int* __restrict__ dst, int* __restrict__ ghist) {
    __shared__ int h[NBKT];
    int t = threadIdx.x;
    h[t] = 0;
    __syncthreads();
    long base = (long)blockIdx.x * EPB;
    for (int u = 0; u < 8; u++) {
        long e = base + u * 256 + t;
        if (e < N_EDGES) atomicAdd(&h[dst[e] >> 9], 1);
    }
    __syncthreads();
    if (h[t]) atomicAdd(&ghist[t], h[t]);
}

// ---------------- bucket scan + cntg (binary search) + ybf pad-row zero ------
__global__ void bscan(const int* __restrict__ ghist, int* __restrict__ gcursor,
                      const int* __restrict__ batch, int* __restrict__ cntg,
                      bf16* __restrict__ ybfA, bf16* __restrict__ ybfB) {
    __shared__ int sh[NBKT];
    int t = threadIdx.x;                          // 256 threads
    int v = ghist[t];
    sh[t] = v;
    __syncthreads();
    for (int off = 1; off < NBKT; off <<= 1) {
        int a = (t >= off) ? sh[t - off] : 0;
        __syncthreads();
        sh[t] += a;
        __syncthreads();
    }
    gcursor[t] = sh[t] - v;                       // exclusive bucket base
    if (t < NUM_GRAPHS) {                         // per-graph node counts
        int g = t, lo = 0, hi = N_NODES;
        while (lo < hi) { int m = (lo + hi) >> 1; if (batch[m] < g) lo = m + 1; else hi = m; }
        int lb = lo;
        lo = 0; hi = N_NODES;
        while (lo < hi) { int m = (lo + hi) >> 1; if (batch[m] < g + 1) lo = m + 1; else hi = m; }
        cntg[g] = lo - lb;
    }
    if (t < HID) {                                // sentinel zero-row for tail-free gather
        ybfA[(long)N_NODES * HID + t] = __float2bfloat16(0.f);
        ybfB[(long)N_NODES * HID + t] = __float2bfloat16(0.f);
    }
}

// ---------------- partition edges into bucket order --------------------------
__global__ void bpart(const int* __restrict__ src, const int* __restrict__ dst,
                      int* __restrict__ gcursor, int2* __restrict__ epart) {
    __shared__ int h[NBKT];
    __shared__ int cur[NBKT];
    int t = threadIdx.x;
    h[t] = 0;
    __syncthreads();
    long base = (long)blockIdx.x * EPB;
    int myd[8], mys[8];
    for (int u = 0; u < 8; u++) {
        long e = base + u * 256 + t;
        if (e < N_EDGES) {
            myd[u] = dst[e];
            mys[u] = src[e];
            atomicAdd(&h[myd[u] >> 9], 1);
        } else myd[u] = -1;
    }
    __syncthreads();
    if (h[t]) cur[t] = atomicAdd(&gcursor[t], h[t]);
    __syncthreads();
    for (int u = 0; u < 8; u++) {
        if (myd[u] >= 0) {
            int pos = atomicAdd(&cur[myd[u] >> 9], 1);
            epart[pos] = make_int2(mys[u], myd[u]);
        }
    }
}

// ---------------- fill padded CSR from bucket-sorted edges -------------------
__global__ void fillp(const int2* __restrict__ epart, int* __restrict__ cnt,
                      int* __restrict__ col) {
    int t = threadIdx.x;
    long base = (long)blockIdx.x * EPB;
    for (int u = 0; u < 8; u++) {
        long e = base + u * 256 + t;
        if (e < N_EDGES) {
            int2 p = epart[e];
            int slot = atomicAdd(&cnt[p.y], 1);
            col[p.y * CAP + slot] = p.x;
        }
    }
}

// ---------------- pad each row to a multiple of 32 with sentinel -------------
__global__ void pad_rows(const int* __restrict__ cnt, int* __restrict__ col) {
    int n = blockIdx.x * 256 + threadIdx.x;       // 391 blocks
    if (n >= N_NODES) return;
    int c = cnt[n];
    int c32 = (c + 31) & ~31;
    for (int s = c; s < c32; s++) col[n * CAP + s] = N_NODES;
}

// ---------------- layer-0 pre-projection: ybf = bf16(x @ W1f) (no bias) ------
// 4 nodes per wave: W1 column loads amortized 4x.
__global__ void proj0(const float* __restrict__ x, const float* __restrict__ W1,
                      bf16* __restrict__ ybf) {
    __shared__ float xsh[4][4][IN_CH];            // 8 KB
    const int wave = threadIdx.x >> 6, lane = threadIdx.x & 63;
    const int nb = blockIdx.x * 16 + wave * 4;    // 6250 * 16 == 100000
    #pragma unroll
    for (int r = 0; r < 4; r++) {
        float2 v = ((const float2*)(x + (long)(nb + r) * IN_CH))[lane];
        xsh[wave][r][2 * lane]     = v.x;         // 2-way bank alias: free
        xsh[wave][r][2 * lane + 1] = v.y;
    }
    // per-wave LDS slice: wave-lockstep + compiler lgkmcnt; no barrier
    float a0 = 0.f, a1 = 0.f, a2 = 0.f, a3 = 0.f;
    for (int k = 0; k < IN_CH; k += 4) {
        float4 q0 = *(const float4*)&xsh[wave][0][k];
        float4 q1 = *(const float4*)&xsh[wave][1][k];
        float4 q2 = *(const float4*)&xsh[wave][2][k];
        float4 q3 = *(const float4*)&xsh[wave][3][k];
        float w0 = W1[(k + 0) * 64 + lane];
        float w1 = W1[(k + 1) * 64 + lane];
        float w2 = W1[(k + 2) * 64 + lane];
        float w3 = W1[(k + 3) * 64 + lane];
        a0 += q0.x * w0 + q0.y * w1 + q0.z * w2 + q0.w * w3;
        a1 += q1.x * w0 + q1.y * w1 + q1.z * w2 + q1.w * w3;
        a2 += q2.x * w0 + q2.y * w1 + q2.z * w2 + q2.w * w3;
        a3 += q3.x * w0 + q3.y * w1 + q3.z * w2 + q3.w * w3;
    }
    ybf[(long)(nb + 0) * 64 + lane] = __float2bfloat16(a0);
    ybf[(long)(nb + 1) * 64 + lane] = __float2bfloat16(a1);
    ybf[(long)(nb + 2) * 64 + lane] = __float2bfloat16(a2);
    ybf[(long)(nb + 3) * 64 + lane] = __float2bfloat16(a3);
}

// ---------------- fused layer: dual-row gather -> relu -> W2 -> pool (+W1n) --
// Each wave owns 4 nodes (block = 4 waves = 16 nodes). Gather per node:
// lanes 0-31 row c0, lanes 32-63 row c1, packed bf16x2. The two 64x64 MLP
// matmuls are done jointly for the wave's 4 nodes: each W2/W1n dword loaded
// once per wave, applied to 4 accumulators (4x less L1 weight traffic).
template <bool HAS_NEXT>
__global__ __launch_bounds__(256, 6)
void layer_fused(const bf16* __restrict__ ybf, const int* __restrict__ cnt,
                 const int* __restrict__ col, const int* __restrict__ batch,
                 const float* __restrict__ b1, const float* __restrict__ W2,
                 const float* __restrict__ b2, const float* __restrict__ W1n,
                 bf16* __restrict__ ynext, float* __restrict__ pooled_l) {
    __shared__ float csh[4][2][2 * HID];          // per-wave half-sum exchange (reused per r)
    __shared__ float tsh[4][4][HID];              // t rows (4 waves x 4 nodes)
    __shared__ float hsh[4][4][HID];              // h rows for the W1n matmul
    __shared__ float psh[4][HID];                 // per-wave pooling partials
    const int wave = threadIdx.x >> 6, lane = threadIdx.x & 63;
    const int hl = lane & 31;
    const bool hi = lane >= 32;
    const int nA = blockIdx.x * 16;               // 6250 blocks
    const int nW = nA + wave * 4;                 // this wave's first node
    const uint32* yrow = (const uint32*)ybf;

    // ---- phase 1: gather + t = relu(y_self + b1 + agg) for 4 nodes ----
    #pragma unroll
    for (int r = 0; r < 4; r++) {
        const int n = __builtin_amdgcn_readfirstlane(nW + r);
        const int deg32 = __builtin_amdgcn_readfirstlane((cnt[n] + 31) & ~31);
        const long s = (long)n * CAP;
        float2 a0 = {0.f, 0.f}, a1 = {0.f, 0.f}, a2 = {0.f, 0.f}, a3 = {0.f, 0.f};
        for (int i = 0; i < deg32; i += 32) {
            uint32 p[16];
            #pragma unroll
            for (int u = 0; u < 16; u++) {
                int c0 = __builtin_amdgcn_readfirstlane(col[s + i + 2 * u]);
                int c1 = __builtin_amdgcn_readfirstlane(col[s + i + 2 * u + 1]);
                int c = hi ? c1 : c0;
                p[u] = yrow[(long)c * 32 + hl];
            }
            #pragma unroll
            for (int u = 0; u < 16; u++) {
                float2 f = unpk(p[u]);
                if ((u & 3) == 0)      { a0.x += f.x; a0.y += f.y; }
                else if ((u & 3) == 1) { a1.x += f.x; a1.y += f.y; }
                else if ((u & 3) == 2) { a2.x += f.x; a2.y += f.y; }
                else                   { a3.x += f.x; a3.y += f.y; }
            }
        }
        float2 hs;
        hs.x = (a0.x + a1.x) + (a2.x + a3.x);
        hs.y = (a0.y + a1.y) + (a2.y + a3.y);
        ((float2*)&csh[wave][hi ? 1 : 0][0])[hl] = hs;   // channels (2hl, 2hl+1)
        // per-wave LDS slice: lockstep + compiler lgkmcnt; no barrier
        float t = bf2f(ybf[(long)n * 64 + lane]) + b1[lane]
                + csh[wave][0][lane] + csh[wave][1][lane];
        tsh[wave][r][lane] = fmaxf(t, 0.f);
    }

    // ---- phase 2: h = relu(t @ W2 + b2), weights loaded once per wave ----
    float hv[4];
    {
        const float bb = b2[lane];
        float h0 = bb, h1 = bb, h2 = bb, h3 = bb;
        for (int k = 0; k < 64; k += 4) {
            float4 t0 = *(const float4*)&tsh[wave][0][k];
            float4 t1 = *(const float4*)&tsh[wave][1][k];
            float4 t2 = *(const float4*)&tsh[wave][2][k];
            float4 t3 = *(const float4*)&tsh[wave][3][k];
            float w0 = W2[(k + 0) * 64 + lane];
            float w1 = W2[(k + 1) * 64 + lane];
            float w2 = W2[(k + 2) * 64 + lane];
            float w3 = W2[(k + 3) * 64 + lane];
            h0 += t0.x * w0 + t0.y * w1 + t0.z * w2 + t0.w * w3;
            h1 += t1.x * w0 + t1.y * w1 + t1.z * w2 + t1.w * w3;
            h2 += t2.x * w0 + t2.y * w1 + t2.z * w2 + t2.w * w3;
            h3 += t3.x * w0 + t3.y * w1 + t3.z * w2 + t3.w * w3;
        }
        hv[0] = fmaxf(h0, 0.f); hv[1] = fmaxf(h1, 0.f);
        hv[2] = fmaxf(h2, 0.f); hv[3] = fmaxf(h3, 0.f);
    }
    #pragma unroll
    for (int r = 0; r < 4; r++) hsh[wave][r][lane] = hv[r];

    // ---- phase 3: ynext = h @ W1n (next layer's first linear, no bias) ----
    if (HAS_NEXT) {               // reads only own wave's hsh slice: no barrier
        float y0 = 0.f, y1 = 0.f, y2 = 0.f, y3 = 0.f;
        for (int k = 0; k < 64; k += 4) {
            float4 g0 = *(const float4*)&hsh[wave][0][k];
            float4 g1 = *(const float4*)&hsh[wave][1][k];
            float4 g2 = *(const float4*)&hsh[wave][2][k];
            float4 g3 = *(const float4*)&hsh[wave][3][k];
            float w0 = W1n[(k + 0) * 64 + lane];
            float w1 = W1n[(k + 1) * 64 + lane];
            float w2 = W1n[(k + 2) * 64 + lane];
            float w3 = W1n[(k + 3) * 64 + lane];
            y0 += g0.x * w0 + g0.y * w1 + g0.z * w2 + g0.w * w3;
            y1 += g1.x * w0 + g1.y * w1 + g1.z * w2 + g1.w * w3;
            y2 += g2.x * w0 + g2.y * w1 + g2.z * w2 + g2.w * w3;
            y3 += g3.x * w0 + g3.y * w1 + g3.z * w2 + g3.w * w3;
        }
        ynext[(long)(nW + 0) * 64 + lane] = __float2bfloat16(y0);
        ynext[(long)(nW + 1) * 64 + lane] = __float2bfloat16(y1);
        ynext[(long)(nW + 2) * 64 + lane] = __float2bfloat16(y2);
        ynext[(long)(nW + 3) * 64 + lane] = __float2bfloat16(y3);
    }

    // ---- pooling: 16 nodes -> 1 atomic when block is graph-uniform ----
    const int gA = __builtin_amdgcn_readfirstlane(batch[nA]);
    const int gZ = __builtin_amdgcn_readfirstlane(batch[nA + 15]);
    float* rep = pooled_l + (long)(blockIdx.x & (NREP - 1)) * NUM_GRAPHS * HID;
    if (gA == gZ) {               // ~98% of blocks: whole block same graph
        psh[wave][lane] = (hv[0] + hv[1]) + (hv[2] + hv[3]);
        __syncthreads();
        if (wave == 0) {
            float ssum = (psh[0][lane] + psh[1][lane]) + (psh[2][lane] + psh[3][lane]);
            atomicAdd(&rep[gA * 64 + lane], ssum);
        }
    } else {                      // graph boundary inside block: per-node atomics
        #pragma unroll
        for (int r = 0; r < 4; r++) {
            const int g = __builtin_amdgcn_readfirstlane(batch[nW + r]);
            atomicAdd(&rep[g * 64 + lane], hv[r]);
        }
    }
}

// ---------------- JK proj + classifier Linear1 + BN-stat atomics -------------
// One block per graph, 4 waves. Wave l owns JK layer l (replica-sum + partial
// pjk). Then the 4 waves split the Z inner product (16 k each). Wave 0 writes
// Z and atomically accumulates per-channel sum / sumsq for batch-norm stats.
__global__ void jk_cls1(const float* __restrict__ pooled, const int* __restrict__ cntg,
                        const float* __restrict__ Wjk, const float* __restrict__ bjk,
                        const float* __restrict__ Wc1, const float* __restrict__ bc1,
                        float* __restrict__ Z, float* __restrict__ zstats) {
    __shared__ float sh[4][HID];                  // per-layer summed pooled rows
    __shared__ float pacc[4][HID];                // per-wave partial pjk
    __shared__ float pj[HID];                     // full pjk row
    __shared__ float zacc[4][HID];                // per-wave partial Z
    const int g = blockIdx.x;                     // 128 blocks
    const int wave = threadIdx.x >> 6, j = threadIdx.x & 63;

    // stage 1: wave w = layer w. Sum NREP replicas, then partial JK matmul.
    float s = 0.f;
    for (int r = 0; r < NREP; r++)
        s += pooled[((long)(wave * NREP + r) * NUM_GRAPHS + g) * 64 + j];
    sh[wave][j] = s;                              // own-wave slice: lockstep, no barrier
    const float* W = Wjk + (long)wave * HID * 64;
    float a = 0.f;
    for (int k = 0; k < 64; k += 4) {
        float4 sv = *(const float4*)&sh[wave][k];
        a += sv.x * W[(k + 0) * 64 + j];
        a += sv.y * W[(k + 1) * 64 + j];
        a += sv.z * W[(k + 2) * 64 + j];
        a += sv.w * W[(k + 3) * 64 + j];
    }
    pacc[wave][j] = a;
    __syncthreads();

    // full pjk row (every thread computes same value for its j)
    if (wave == 0)
        pj[j] = (float)cntg[g] * bjk[j]
              + (pacc[0][j] + pacc[1][j]) + (pacc[2][j] + pacc[3][j]);
    __syncthreads();

    // stage 2: wave w handles k in [16w, 16w+16) of Z = pjk @ Wc1
    float z = 0.f;
    for (int k = 16 * wave; k < 16 * wave + 16; k += 4) {
        float4 pv = *(const float4*)&pj[k];
        z += pv.x * Wc1[(k + 0) * 64 + j];
        z += pv.y * Wc1[(k + 1) * 64 + j];
        z += pv.z * Wc1[(k + 2) * 64 + j];
        z += pv.w * Wc1[(k + 3) * 64 + j];
    }
    zacc[wave][j] = z;
    __syncthreads();
    if (wave == 0) {
        float zv = bc1[j] + (zacc[0][j] + zacc[1][j]) + (zacc[2][j] + zacc[3][j]);
        Z[g * 64 + j] = zv;
        atomicAdd(&zstats[j], zv);
        atomicAdd(&zstats[HID + j], zv * zv);
    }
}

// ---------------- classifier tail: BN(batch stats) -> ReLU -> Linear ---------
__global__ void cls2(const float* __restrict__ Z, const float* __restrict__ zstats,
                     const float* __restrict__ gamma, const float* __restrict__ beta,
                     const float* __restrict__ Wc2, const float* __restrict__ bc2,
                     float* __restrict__ out) {
    __shared__ float v[HID];
    const int g = blockIdx.x, j = threadIdx.x;    // 128 blocks x 64 threads
    float mu = zstats[j] * (1.f / NUM_GRAPHS);
    float var = zstats[HID + j] * (1.f / NUM_GRAPHS) - mu * mu;
    float rs = rsqrtf(var + BN_EPS);
    float zv = Z[g * 64 + j];
    v[j] = fmaxf(gamma[j] * (zv - mu) * rs + beta[j], 0.f);
    // single wave: lockstep + compiler lgkmcnt; no barrier
    if (j < OUT_CH) {
        float acc = bc2[j];
        for (int k = 0; k < 64; k++) acc += v[k] * Wc2[k * OUT_CH + j];
        out[g * OUT_CH + j] = acc;
    }
}

// -----------------------------------------------------------------------------
extern "C" void kernel_launch(void* const* d_in, const int* in_sizes, int n_in,
                              void* d_out, int out_size, void* d_ws, size_t ws_size,
                              hipStream_t stream) {
    const float* x     = (const float*)d_in[0];
    const int*   ei    = (const int*)d_in[1];
    const int*   batch = (const int*)d_in[2];
    const float* W1f   = (const float*)d_in[3];
    const float* b1f   = (const float*)d_in[4];
    const float* W2f   = (const float*)d_in[5];
    const float* b2f   = (const float*)d_in[6];
    const float* W1r   = (const float*)d_in[7];
    const float* b1r   = (const float*)d_in[8];
    const float* W2r   = (const float*)d_in[9];
    const float* b2r   = (const float*)d_in[10];
    const float* Wjk   = (const float*)d_in[11];
    const float* bjk   = (const float*)d_in[12];
    const float* Wc1   = (const float*)d_in[13];
    const float* bc1   = (const float*)d_in[14];
    const float* gamma = (const float*)d_in[15];
    const float* beta  = (const float*)d_in[16];
    const float* Wc2   = (const float*)d_in[17];
    const float* bc2   = (const float*)d_in[18];

    const int* src = ei;
    const int* dst = ei + N_EDGES;

    // workspace layout (all segments 8-B aligned)
    float* ws        = (float*)d_ws;
    float* Z         = ws;                                      // 8192 floats (cls Z)
    bf16*  ybfA      = (bf16*)(Z + NUM_GRAPHS * HID);           // (N+1)*64 bf16
    bf16*  ybfB      = ybfA + (long)(N_NODES + 1) * HID;        // (N+1)*64 bf16
    int*   cnt       = (int*)(ybfB + (long)(N_NODES + 1) * HID);// 100000
    float* pooled    = (float*)(cnt + N_NODES);                 // 4*8*8192 floats
    int*   ghist     = (int*)(pooled + (long)N_LAYERS * NREP * NUM_GRAPHS * HID); // 256
    int*   gcursor   = ghist + NBKT;                            // 256
    int*   cntg      = gcursor + NBKT;                          // 128
    float* zstats    = (float*)(cntg + NUM_GRAPHS);             // 128 (sum | sumsq)
    int*   col       = (int*)(zstats + 2 * HID);                // 6.4M ints
    int2*  epart     = (int2*)(col + (long)N_NODES * CAP);      // 1.6M int2
    // zeroed span: cnt .. zstats (cntg zeroed harmlessly; bscan rewrites it)
    const int ZN = N_NODES + N_LAYERS * NREP * NUM_GRAPHS * HID
                 + 2 * NBKT + NUM_GRAPHS + 2 * HID;

    // ---- CSR build: zero -> bucket hist -> scan -> partition -> fill -> pad --
    zero_i<<<360, 256, 0, stream>>>(cnt, ZN);
    bhist<<<PNB, 256, 0, stream>>>(dst, ghist);
    bscan<<<1, 256, 0, stream>>>(ghist, gcursor, batch, cntg, ybfA, ybfB);
    bpart<<<PNB, 256, 0, stream>>>(src, dst, gcursor, epart);
    fillp<<<PNB, 256, 0, stream>>>(epart, cnt, col);
    pad_rows<<<(N_NODES + 255) / 256, 256, 0, stream>>>(cnt, col);

    // ---- layer-0 pre-projection (dense, streaming; 4 nodes/wave) ----
    proj0<<<N_NODES / 16, 256, 0, stream>>>(x, W1f, ybfA);

    // ---- 4 fused layers (16 nodes per block: 4 waves x 4 nodes/wave) ----
    const int NB = N_NODES / 16;                                // 6250
    const long PL = (long)NREP * NUM_GRAPHS * HID;
    layer_fused<true><<<NB, 256, 0, stream>>>(
        ybfA, cnt, col, batch, b1f, W2f, b2f,
        W1r, ybfB, pooled);
    layer_fused<true><<<NB, 256, 0, stream>>>(
        ybfB, cnt, col, batch, b1r, W2r, b2r,
        W1r + (long)1 * HID * HID, ybfA, pooled + 1 * PL);
    layer_fused<true><<<NB, 256, 0, stream>>>(
        ybfA, cnt, col, batch, b1r + HID, W2r + (long)1 * HID * HID, b2r + HID,
        W1r + (long)2 * HID * HID, ybfB, pooled + 2 * PL);
    layer_fused<false><<<NB, 256, 0, stream>>>(
        ybfB, cnt, col, batch, b1r + 2 * HID, W2r + (long)2 * HID * HID, b2r + 2 * HID,
        nullptr, nullptr, pooled + 3 * PL);

    // ---- JK + classifier: wide tail (128 blocks each) ----
    jk_cls1<<<NUM_GRAPHS, 256, 0, stream>>>(pooled, cntg, Wjk, bjk, Wc1, bc1,
                                            Z, zstats);
    cls2<<<NUM_GRAPHS, 64, 0, stream>>>(Z, zstats, gamma, beta, Wc2, bc2,
                                        (float*)d_out);
}

// Round 3
// 477.342 us; speedup vs baseline: 1.5333x; 1.0074x over previous
//
#include <hip/hip_runtime.h>
#include <hip/hip_bf16.h>

#define N_NODES    100000
#define N_EDGES    1600000
#define IN_CH      128
#define HID        64
#define N_LAYERS   4
#define OUT_CH     10
#define NUM_GRAPHS 128
#define BN_EPS     1e-5f
#define CAP        64             // padded CSR row capacity; P(deg>64) ~ 1e-19 at Poisson(16)
#define NREP       8              // pooled replicas (cuts per-address atomic chains 8x)
#define NBKT       256            // dst>>9 -> buckets 0..195 (256 slots for pow2 LDS)
#define EPB        2048           // edges per block in partition kernels
#define PNB        782            // ceil(1.6M / 2048)

typedef __hip_bfloat16 bf16;
typedef unsigned int uint32;
typedef float f32x2 __attribute__((ext_vector_type(2)));
typedef float f32x4 __attribute__((ext_vector_type(4)));

__device__ __forceinline__ float bf2f(bf16 v) { return __bfloat162float(v); }
// unpack packed bf16x2 dword -> f32x2 pair (bf16 -> f32 is <<16)
__device__ __forceinline__ f32x2 unpk2(uint32 p) {
    f32x2 r;
    r.x = __uint_as_float(p << 16);
    r.y = __uint_as_float(p & 0xffff0000u);
    return r;
}

// ---------------- zero the counter/accumulator region ------------------------
__global__ void zero_i(int* __restrict__ p, int n) {
    int i = blockIdx.x * 256 + threadIdx.x;
    int st = gridDim.x * 256;
    for (; i < n; i += st) p[i] = 0;
}

// ---------------- bucket histogram (LDS-aggregated) --------------------------
__global__ void bhist(const int* __restrict__ dst, int* __restrict__ ghist) {
    __shared__ int h[NBKT];
    int t = threadIdx.x;
    h[t] = 0;
    __syncthreads();
    long base = (long)blockIdx.x * EPB;
    for (int u = 0; u < 8; u++) {
        long e = base + u * 256 + t;
        if (e < N_EDGES) atomicAdd(&h[dst[e] >> 9], 1);
    }
    __syncthreads();
    if (h[t]) atomicAdd(&ghist[t], h[t]);
}

// ---------------- bucket scan + cntg (binary search) + ybf pad-row zero ------
__global__ void bscan(const int* __restrict__ ghist, int* __restrict__ gcursor,
                      const int* __restrict__ batch, int* __restrict__ cntg,
                      bf16* __restrict__ ybfA, bf16* __restrict__ ybfB) {
    __shared__ int sh[NBKT];
    int t = threadIdx.x;                          // 256 threads
    int v = ghist[t];
    sh[t] = v;
    __syncthreads();
    for (int off = 1; off < NBKT; off <<= 1) {
        int a = (t >= off) ? sh[t - off] : 0;
        __syncthreads();
        sh[t] += a;
        __syncthreads();
    }
    gcursor[t] = sh[t] - v;                       // exclusive bucket base
    if (t < NUM_GRAPHS) {                         // per-graph node counts
        int g = t, lo = 0, hi = N_NODES;
        while (lo < hi) { int m = (lo + hi) >> 1; if (batch[m] < g) lo = m + 1; else hi = m; }
        int lb = lo;
        lo = 0; hi = N_NODES;
        while (lo < hi) { int m = (lo + hi) >> 1; if (batch[m] < g + 1) lo = m + 1; else hi = m; }
        cntg[g] = lo - lb;
    }
    if (t < HID) {                                // sentinel zero-row for tail-free gather
        ybfA[(long)N_NODES * HID + t] = __float2bfloat16(0.f);
        ybfB[(long)N_NODES * HID + t] = __float2bfloat16(0.f);
    }
}

// ---------------- partition edges into bucket order --------------------------
__global__ void bpart(const int* __restrict__ src, const int* __restrict__ dst,
                      int* __restrict__ gcursor, int2* __restrict__ epart) {
    __shared__ int h[NBKT];
    __shared__ int cur[NBKT];
    int t = threadIdx.x;
    h[t] = 0;
    __syncthreads();
    long base = (long)blockIdx.x * EPB;
    int myd[8], mys[8];
    for (int u = 0; u < 8; u++) {
        long e = base + u * 256 + t;
        if (e < N_EDGES) {
            myd[u] = dst[e];
            mys[u] = src[e];
            atomicAdd(&h[myd[u] >> 9], 1);
        } else myd[u] = -1;
    }
    __syncthreads();
    if (h[t]) cur[t] = atomicAdd(&gcursor[t], h[t]);
    __syncthreads();
    for (int u = 0; u < 8; u++) {
        if (myd[u] >= 0) {
            int pos = atomicAdd(&cur[myd[u] >> 9], 1);
            epart[pos] = make_int2(mys[u], myd[u]);
        }
    }
}

// ---------------- fill padded CSR from bucket-sorted edges -------------------
__global__ void fillp(const int2* __restrict__ epart, int* __restrict__ cnt,
                      int* __restrict__ col) {
    int t = threadIdx.x;
    long base = (long)blockIdx.x * EPB;
    for (int u = 0; u < 8; u++) {
        long e = base + u * 256 + t;
        if (e < N_EDGES) {
            int2 p = epart[e];
            int slot = atomicAdd(&cnt[p.y], 1);
            col[p.y * CAP + slot] = p.x;
        }
    }
}

// ---------------- pad each row to a multiple of 32 with sentinel -------------
__global__ void pad_rows(const int* __restrict__ cnt, int* __restrict__ col) {
    int n = blockIdx.x * 256 + threadIdx.x;       // 391 blocks
    if (n >= N_NODES) return;
    int c = cnt[n];
    int c32 = (c + 31) & ~31;
    for (int s = c; s < c32; s++) col[n * CAP + s] = N_NODES;
}

// ---------------- layer-0 pre-projection: ybf = bf16(x @ W1f) (no bias) ------
// 4 nodes per wave; x staged TRANSPOSED ([k][r]) so the MACs run as packed
// v_pk_fma_f32 pairs (2 nodes per instruction) on broadcast ds_read_b128.
__global__ void proj0(const float* __restrict__ x, const float* __restrict__ W1,
                      bf16* __restrict__ ybf) {
    __shared__ __align__(16) float xshT[4][IN_CH][4];   // 8 KB
    const int wave = threadIdx.x >> 6, lane = threadIdx.x & 63;
    const int nb = blockIdx.x * 16 + wave * 4;    // 6250 * 16 == 100000
    #pragma unroll
    for (int r = 0; r < 4; r++) {
        float2 v = ((const float2*)(x + (long)(nb + r) * IN_CH))[lane];
        xshT[wave][2 * lane][r]     = v.x;
        xshT[wave][2 * lane + 1][r] = v.y;
    }
    // per-wave LDS slice: wave-lockstep + compiler lgkmcnt; no barrier
    f32x2 aA = {0.f, 0.f}, aB = {0.f, 0.f};
    #pragma unroll 8
    for (int k = 0; k < IN_CH; k++) {
        f32x4 q = *(const f32x4*)&xshT[wave][k][0];  // broadcast read
        float w = W1[k * 64 + lane];
        f32x2 wv = {w, w};
        aA += (f32x2){q.x, q.y} * wv;                // -> v_pk_fma_f32
        aB += (f32x2){q.z, q.w} * wv;
    }
    ybf[(long)(nb + 0) * 64 + lane] = __float2bfloat16(aA.x);
    ybf[(long)(nb + 1) * 64 + lane] = __float2bfloat16(aA.y);
    ybf[(long)(nb + 2) * 64 + lane] = __float2bfloat16(aB.x);
    ybf[(long)(nb + 3) * 64 + lane] = __float2bfloat16(aB.y);
}

// ---------------- fused layer: dual-row gather -> relu -> W2 -> pool (+W1n) --
// Each wave owns 4 nodes. Gather: lanes 0-31 row c0, lanes 32-63 row c1,
// 32-bit byte offsets (SADDR-form loads), packed f32x2 accumulate.
// MLPs: t/h staged transposed [k][r]; two f32x2 accumulators per lane run
// as v_pk_fma_f32 (2 nodes/instr) -> FMA VALU halved vs scalar.
template <bool HAS_NEXT>
__global__ __launch_bounds__(256, 6)
void layer_fused(const bf16* __restrict__ ybf, const int* __restrict__ cnt,
                 const int* __restrict__ col, const int* __restrict__ batch,
                 const float* __restrict__ b1, const float* __restrict__ W2,
                 const float* __restrict__ b2, const float* __restrict__ W1n,
                 bf16* __restrict__ ynext, float* __restrict__ pooled_l) {
    __shared__ __align__(16) float csh[4][2][2 * HID];  // half-sum exchange, 4 KB
    __shared__ __align__(16) float tshT[4][HID][4];     // t transposed [k][r], 4 KB
    __shared__ __align__(16) float hshT[4][HID][4];     // h transposed [k][r], 4 KB
    __shared__ float psh[4][HID];                       // pooling partials, 1 KB
    const int wave = threadIdx.x >> 6, lane = threadIdx.x & 63;
    const int hl = lane & 31;
    const bool hi = lane >= 32;
    const uint32 hl4 = (uint32)hl * 4u;
    const int nA = blockIdx.x * 16;               // 6250 blocks
    const int nW = nA + wave * 4;                 // this wave's first node
    const char* ybase = (const char*)ybf;

    // ---- phase 1: gather + t = relu(y_self + b1 + agg) for 4 nodes ----
    #pragma unroll
    for (int r = 0; r < 4; r++) {
        const int n = __builtin_amdgcn_readfirstlane(nW + r);
        const int deg32 = __builtin_amdgcn_readfirstlane((cnt[n] + 31) & ~31);
        const long s = (long)n * CAP;
        f32x2 a0 = {0.f, 0.f}, a1 = {0.f, 0.f}, a2 = {0.f, 0.f}, a3 = {0.f, 0.f};
        for (int i = 0; i < deg32; i += 32) {
            uint32 p[16];
            #pragma unroll
            for (int u = 0; u < 16; u++) {
                int c0 = __builtin_amdgcn_readfirstlane(col[s + i + 2 * u]);
                int c1 = __builtin_amdgcn_readfirstlane(col[s + i + 2 * u + 1]);
                uint32 off = ((uint32)(hi ? c1 : c0) << 7) + hl4;  // 32-bit SADDR form
                p[u] = *(const uint32*)(ybase + off);
            }
            #pragma unroll
            for (int u = 0; u < 16; u++) {
                f32x2 f = unpk2(p[u]);             // 2 bit-ops + 1 v_pk_add_f32
                if ((u & 3) == 0)      a0 += f;
                else if ((u & 3) == 1) a1 += f;
                else if ((u & 3) == 2) a2 += f;
                else                   a3 += f;
            }
        }
        f32x2 hs = (a0 + a1) + (a2 + a3);
        ((f32x2*)&csh[wave][hi ? 1 : 0][0])[hl] = hs;   // channels (2hl, 2hl+1)
        // per-wave LDS slice: lockstep + compiler lgkmcnt; no barrier
        float t = bf2f(ybf[(long)n * 64 + lane]) + b1[lane]
                + csh[wave][0][lane] + csh[wave][1][lane];
        tshT[wave][lane][r] = fmaxf(t, 0.f);
    }

    // ---- phase 2: h = relu(t @ W2 + b2), packed pairs, wts loaded once/wave --
    float hv0, hv1, hv2, hv3;
    {
        const float bb = b2[lane];
        f32x2 hA = {bb, bb}, hB = {bb, bb};
        #pragma unroll 8
        for (int k = 0; k < 64; k++) {
            f32x4 tv = *(const f32x4*)&tshT[wave][k][0];  // broadcast read
            float w = W2[k * 64 + lane];
            f32x2 wv = {w, w};
            hA += (f32x2){tv.x, tv.y} * wv;
            hB += (f32x2){tv.z, tv.w} * wv;
        }
        hv0 = fmaxf(hA.x, 0.f); hv1 = fmaxf(hA.y, 0.f);
        hv2 = fmaxf(hB.x, 0.f); hv3 = fmaxf(hB.y, 0.f);
    }
    *(f32x4*)&hshT[wave][lane][0] = (f32x4){hv0, hv1, hv2, hv3};

    // ---- phase 3: ynext = h @ W1n (next layer's first linear, no bias) ----
    if (HAS_NEXT) {               // reads only own wave's hshT slice: no barrier
        f32x2 yA = {0.f, 0.f}, yB = {0.f, 0.f};
        #pragma unroll 8
        for (int k = 0; k < 64; k++) {
            f32x4 gv = *(const f32x4*)&hshT[wave][k][0];
            float w = W1n[k * 64 + lane];
            f32x2 wv = {w, w};
            yA += (f32x2){gv.x, gv.y} * wv;
            yB += (f32x2){gv.z, gv.w} * wv;
        }
        ynext[(long)(nW + 0) * 64 + lane] = __float2bfloat16(yA.x);
        ynext[(long)(nW + 1) * 64 + lane] = __float2bfloat16(yA.y);
        ynext[(long)(nW + 2) * 64 + lane] = __float2bfloat16(yB.x);
        ynext[(long)(nW + 3) * 64 + lane] = __float2bfloat16(yB.y);
    }

    // ---- pooling: 16 nodes -> 1 atomic when block is graph-uniform ----
    const int gA = __builtin_amdgcn_readfirstlane(batch[nA]);
    const int gZ = __builtin_amdgcn_readfirstlane(batch[nA + 15]);
    float* rep = pooled_l + (long)(blockIdx.x & (NREP - 1)) * NUM_GRAPHS * HID;
    if (gA == gZ) {               // ~98% of blocks: whole block same graph
        psh[wave][lane] = (hv0 + hv1) + (hv2 + hv3);
        __syncthreads();
        if (wave == 0) {
            float ssum = (psh[0][lane] + psh[1][lane]) + (psh[2][lane] + psh[3][lane]);
            atomicAdd(&rep[gA * 64 + lane], ssum);
        }
    } else {                      // graph boundary inside block: per-node atomics
        const int g0 = __builtin_amdgcn_readfirstlane(batch[nW + 0]);
        atomicAdd(&rep[g0 * 64 + lane], hv0);
        const int g1 = __builtin_amdgcn_readfirstlane(batch[nW + 1]);
        atomicAdd(&rep[g1 * 64 + lane], hv1);
        const int g2 = __builtin_amdgcn_readfirstlane(batch[nW + 2]);
        atomicAdd(&rep[g2 * 64 + lane], hv2);
        const int g3 = __builtin_amdgcn_readfirstlane(batch[nW + 3]);
        atomicAdd(&rep[g3 * 64 + lane], hv3);
    }
}

// ---------------- JK proj + classifier Linear1 + BN-stat atomics -------------
// One block per graph, 4 waves. Wave l owns JK layer l (replica-sum + partial
// pjk). Then the 4 waves split the Z inner product (16 k each). Wave 0 writes
// Z and atomically accumulates per-channel sum / sumsq for batch-norm stats.
__global__ void jk_cls1(const float* __restrict__ pooled, const int* __restrict__ cntg,
                        const float* __restrict__ Wjk, const float* __restrict__ bjk,
                        const float* __restrict__ Wc1, const float* __restrict__ bc1,
                        float* __restrict__ Z, float* __restrict__ zstats) {
    __shared__ __align__(16) float sh[4][HID];    // per-layer summed pooled rows
    __shared__ float pacc[4][HID];                // per-wave partial pjk
    __shared__ __align__(16) float pj[HID];       // full pjk row
    __shared__ float zacc[4][HID];                // per-wave partial Z
    const int g = blockIdx.x;                     // 128 blocks
    const int wave = threadIdx.x >> 6, j = threadIdx.x & 63;

    // stage 1: wave w = layer w. Sum NREP replicas, then partial JK matmul.
    float s = 0.f;
    for (int r = 0; r < NREP; r++)
        s += pooled[((long)(wave * NREP + r) * NUM_GRAPHS + g) * 64 + j];
    sh[wave][j] = s;                              // own-wave slice: lockstep, no barrier
    const float* W = Wjk + (long)wave * HID * 64;
    float a = 0.f;
    for (int k = 0; k < 64; k += 4) {
        f32x4 sv = *(const f32x4*)&sh[wave][k];
        a += sv.x * W[(k + 0) * 64 + j];
        a += sv.y * W[(k + 1) * 64 + j];
        a += sv.z * W[(k + 2) * 64 + j];
        a += sv.w * W[(k + 3) * 64 + j];
    }
    pacc[wave][j] = a;
    __syncthreads();

    // full pjk row (every thread computes same value for its j)
    if (wave == 0)
        pj[j] = (float)cntg[g] * bjk[j]
              + (pacc[0][j] + pacc[1][j]) + (pacc[2][j] + pacc[3][j]);
    __syncthreads();

    // stage 2: wave w handles k in [16w, 16w+16) of Z = pjk @ Wc1
    float z = 0.f;
    for (int k = 16 * wave; k < 16 * wave + 16; k += 4) {
        f32x4 pv = *(const f32x4*)&pj[k];
        z += pv.x * Wc1[(k + 0) * 64 + j];
        z += pv.y * Wc1[(k + 1) * 64 + j];
        z += pv.z * Wc1[(k + 2) * 64 + j];
        z += pv.w * Wc1[(k + 3) * 64 + j];
    }
    zacc[wave][j] = z;
    __syncthreads();
    if (wave == 0) {
        float zv = bc1[j] + (zacc[0][j] + zacc[1][j]) + (zacc[2][j] + zacc[3][j]);
        Z[g * 64 + j] = zv;
        atomicAdd(&zstats[j], zv);
        atomicAdd(&zstats[HID + j], zv * zv);
    }
}

// ---------------- classifier tail: BN(batch stats) -> ReLU -> Linear ---------
__global__ void cls2(const float* __restrict__ Z, const float* __restrict__ zstats,
                     const float* __restrict__ gamma, const float* __restrict__ beta,
                     const float* __restrict__ Wc2, const float* __restrict__ bc2,
                     float* __restrict__ out) {
    __shared__ float v[HID];
    const int g = blockIdx.x, j = threadIdx.x;    // 128 blocks x 64 threads
    float mu = zstats[j] * (1.f / NUM_GRAPHS);
    float var = zstats[HID + j] * (1.f / NUM_GRAPHS) - mu * mu;
    float rs = rsqrtf(var + BN_EPS);
    float zv = Z[g * 64 + j];
    v[j] = fmaxf(gamma[j] * (zv - mu) * rs + beta[j], 0.f);
    // single wave: lockstep + compiler lgkmcnt; no barrier
    if (j < OUT_CH) {
        float acc = bc2[j];
        for (int k = 0; k < 64; k++) acc += v[k] * Wc2[k * OUT_CH + j];
        out[g * OUT_CH + j] = acc;
    }
}

// -----------------------------------------------------------------------------
extern "C" void kernel_launch(void* const* d_in, const int* in_sizes, int n_in,
                              void* d_out, int out_size, void* d_ws, size_t ws_size,
                              hipStream_t stream) {
    const float* x     = (const float*)d_in[0];
    const int*   ei    = (const int*)d_in[1];
    const int*   batch = (const int*)d_in[2];
    const float* W1f   = (const float*)d_in[3];
    const float* b1f   = (const float*)d_in[4];
    const float* W2f   = (const float*)d_in[5];
    const float* b2f   = (const float*)d_in[6];
    const float* W1r   = (const float*)d_in[7];
    const float* b1r   = (const float*)d_in[8];
    const float* W2r   = (const float*)d_in[9];
    const float* b2r   = (const float*)d_in[10];
    const float* Wjk   = (const float*)d_in[11];
    const float* bjk   = (const float*)d_in[12];
    const float* Wc1   = (const float*)d_in[13];
    const float* bc1   = (const float*)d_in[14];
    const float* gamma = (const float*)d_in[15];
    const float* beta  = (const float*)d_in[16];
    const float* Wc2   = (const float*)d_in[17];
    const float* bc2   = (const float*)d_in[18];

    const int* src = ei;
    const int* dst = ei + N_EDGES;

    // workspace layout (all segments 8-B aligned)
    float* ws        = (float*)d_ws;
    float* Z         = ws;                                      // 8192 floats (cls Z)
    bf16*  ybfA      = (bf16*)(Z + NUM_GRAPHS * HID);           // (N+1)*64 bf16
    bf16*  ybfB      = ybfA + (long)(N_NODES + 1) * HID;        // (N+1)*64 bf16
    int*   cnt       = (int*)(ybfB + (long)(N_NODES + 1) * HID);// 100000
    float* pooled    = (float*)(cnt + N_NODES);                 // 4*8*8192 floats
    int*   ghist     = (int*)(pooled + (long)N_LAYERS * NREP * NUM_GRAPHS * HID); // 256
    int*   gcursor   = ghist + NBKT;                            // 256
    int*   cntg      = gcursor + NBKT;                          // 128
    float* zstats    = (float*)(cntg + NUM_GRAPHS);             // 128 (sum | sumsq)
    int*   col       = (int*)(zstats + 2 * HID);                // 6.4M ints
    int2*  epart     = (int2*)(col + (long)N_NODES * CAP);      // 1.6M int2
    // zeroed span: cnt .. zstats (cntg zeroed harmlessly; bscan rewrites it)
    const int ZN = N_NODES + N_LAYERS * NREP * NUM_GRAPHS * HID
                 + 2 * NBKT + NUM_GRAPHS + 2 * HID;

    // ---- CSR build: zero -> bucket hist -> scan -> partition -> fill -> pad --
    zero_i<<<360, 256, 0, stream>>>(cnt, ZN);
    bhist<<<PNB, 256, 0, stream>>>(dst, ghist);
    bscan<<<1, 256, 0, stream>>>(ghist, gcursor, batch, cntg, ybfA, ybfB);
    bpart<<<PNB, 256, 0, stream>>>(src, dst, gcursor, epart);
    fillp<<<PNB, 256, 0, stream>>>(epart, cnt, col);
    pad_rows<<<(N_NODES + 255) / 256, 256, 0, stream>>>(cnt, col);

    // ---- layer-0 pre-projection (dense, streaming; 4 nodes/wave) ----
    proj0<<<N_NODES / 16, 256, 0, stream>>>(x, W1f, ybfA);

    // ---- 4 fused layers (16 nodes per block: 4 waves x 4 nodes/wave) ----
    const int NB = N_NODES / 16;                                // 6250
    const long PL = (long)NREP * NUM_GRAPHS * HID;
    layer_fused<true><<<NB, 256, 0, stream>>>(
        ybfA, cnt, col, batch, b1f, W2f, b2f,
        W1r, ybfB, pooled);
    layer_fused<true><<<NB, 256, 0, stream>>>(
        ybfB, cnt, col, batch, b1r, W2r, b2r,
        W1r + (long)1 * HID * HID, ybfA, pooled + 1 * PL);
    layer_fused<true><<<NB, 256, 0, stream>>>(
        ybfA, cnt, col, batch, b1r + HID, W2r + (long)1 * HID * HID, b2r + HID,
        W1r + (long)2 * HID * HID, ybfB, pooled + 2 * PL);
    layer_fused<false><<<NB, 256, 0, stream>>>(
        ybfB, cnt, col, batch, b1r + 2 * HID, W2r + (long)2 * HID * HID, b2r + 2 * HID,
        nullptr, nullptr, pooled + 3 * PL);

    // ---- JK + classifier: wide tail (128 blocks each) ----
    jk_cls1<<<NUM_GRAPHS, 256, 0, stream>>>(pooled, cntg, Wjk, bjk, Wc1, bc1,
                                            Z, zstats);
    cls2<<<NUM_GRAPHS, 64, 0, stream>>>(Z, zstats, gamma, beta, Wc2, bc2,
                                        (float*)d_out);
}

// Round 5
// 470.037 us; speedup vs baseline: 1.5572x; 1.0155x over previous
//
#include <hip/hip_runtime.h>
#include <hip/hip_bf16.h>

#define N_NODES    100000
#define N_EDGES    1600000
#define IN_CH      128
#define HID        64
#define N_LAYERS   4
#define OUT_CH     10
#define NUM_GRAPHS 128
#define BN_EPS     1e-5f
#define CAP        64             // padded CSR row capacity; P(deg>64) ~ 1e-19 at Poisson(16)
#define NREP       8              // pooled replicas (cuts per-address atomic chains 8x)
#define NBKT       256            // dst>>9 -> buckets 0..195 (256 slots for pow2 LDS)
#define EPB        2048           // edges per block in partition kernels
#define PNB        782            // ceil(1.6M / 2048)

typedef __hip_bfloat16 bf16;
typedef unsigned int uint32;
typedef float f32x2 __attribute__((ext_vector_type(2)));
typedef float f32x4 __attribute__((ext_vector_type(4)));

__device__ __forceinline__ float bf2f(bf16 v) { return __bfloat162float(v); }
// unpack packed bf16x2 dword -> f32x2 pair (bf16 -> f32 is <<16)
__device__ __forceinline__ f32x2 unpk2(uint32 p) {
    f32x2 r;
    r.x = __uint_as_float(p << 16);
    r.y = __uint_as_float(p & 0xffff0000u);
    return r;
}

// ---------------- zero the counter/accumulator region ------------------------
__global__ void zero_i(int* __restrict__ p, int n) {
    int i = blockIdx.x * 256 + threadIdx.x;
    int st = gridDim.x * 256;
    for (; i < n; i += st) p[i] = 0;
}

// ---------------- bucket histogram (LDS-aggregated) --------------------------
__global__ void bhist(const int* __restrict__ dst, int* __restrict__ ghist) {
    __shared__ int h[NBKT];
    int t = threadIdx.x;
    h[t] = 0;
    __syncthreads();
    long base = (long)blockIdx.x * EPB;
    for (int u = 0; u < 8; u++) {
        long e = base + u * 256 + t;
        if (e < N_EDGES) atomicAdd(&h[dst[e] >> 9], 1);
    }
    __syncthreads();
    if (h[t]) atomicAdd(&ghist[t], h[t]);
}

// ---------------- bucket scan + cntg (binary search) + ybf pad-row zero ------
__global__ void bscan(const int* __restrict__ ghist, int* __restrict__ gcursor,
                      const int* __restrict__ batch, int* __restrict__ cntg,
                      bf16* __restrict__ ybfA, bf16* __restrict__ ybfB) {
    __shared__ int sh[NBKT];
    int t = threadIdx.x;                          // 256 threads
    int v = ghist[t];
    sh[t] = v;
    __syncthreads();
    for (int off = 1; off < NBKT; off <<= 1) {
        int a = (t >= off) ? sh[t - off] : 0;
        __syncthreads();
        sh[t] += a;
        __syncthreads();
    }
    gcursor[t] = sh[t] - v;                       // exclusive bucket base
    if (t < NUM_GRAPHS) {                         // per-graph node counts
        int g = t, lo = 0, hi = N_NODES;
        while (lo < hi) { int m = (lo + hi) >> 1; if (batch[m] < g) lo = m + 1; else hi = m; }
        int lb = lo;
        lo = 0; hi = N_NODES;
        while (lo < hi) { int m = (lo + hi) >> 1; if (batch[m] < g + 1) lo = m + 1; else hi = m; }
        cntg[g] = lo - lb;
    }
    if (t < HID) {                                // sentinel zero-row for tail-free gather
        ybfA[(long)N_NODES * HID + t] = __float2bfloat16(0.f);
        ybfB[(long)N_NODES * HID + t] = __float2bfloat16(0.f);
    }
}

// ---------------- partition edges into bucket order --------------------------
__global__ void bpart(const int* __restrict__ src, const int* __restrict__ dst,
                      int* __restrict__ gcursor, int2* __restrict__ epart) {
    __shared__ int h[NBKT];
    __shared__ int cur[NBKT];
    int t = threadIdx.x;
    h[t] = 0;
    __syncthreads();
    long base = (long)blockIdx.x * EPB;
    int myd[8], mys[8];
    for (int u = 0; u < 8; u++) {
        long e = base + u * 256 + t;
        if (e < N_EDGES) {
            myd[u] = dst[e];
            mys[u] = src[e];
            atomicAdd(&h[myd[u] >> 9], 1);
        } else myd[u] = -1;
    }
    __syncthreads();
    if (h[t]) cur[t] = atomicAdd(&gcursor[t], h[t]);
    __syncthreads();
    for (int u = 0; u < 8; u++) {
        if (myd[u] >= 0) {
            int pos = atomicAdd(&cur[myd[u] >> 9], 1);
            epart[pos] = make_int2(mys[u], myd[u]);
        }
    }
}

// ---------------- fill padded CSR from bucket-sorted edges -------------------
__global__ void fillp(const int2* __restrict__ epart, int* __restrict__ cnt,
                      int* __restrict__ col) {
    int t = threadIdx.x;
    long base = (long)blockIdx.x * EPB;
    for (int u = 0; u < 8; u++) {
        long e = base + u * 256 + t;
        if (e < N_EDGES) {
            int2 p = epart[e];
            int slot = atomicAdd(&cnt[p.y], 1);
            col[p.y * CAP + slot] = p.x;
        }
    }
}

// ---------------- pad each row to a multiple of 32 with sentinel -------------
__global__ void pad_rows(const int* __restrict__ cnt, int* __restrict__ col) {
    int n = blockIdx.x * 256 + threadIdx.x;       // 391 blocks
    if (n >= N_NODES) return;
    int c = cnt[n];
    int c32 = (c + 31) & ~31;
    for (int s = c; s < c32; s++) col[n * CAP + s] = N_NODES;
}

// ---------------- layer-0 pre-projection: ybf = bf16(x @ W1f) (no bias) ------
// 4 nodes per wave; x staged TRANSPOSED ([k][r]) so the MACs run as packed
// pairs on broadcast ds_read_b128.
__global__ void proj0(const float* __restrict__ x, const float* __restrict__ W1,
                      bf16* __restrict__ ybf) {
    __shared__ __align__(16) float xshT[4][IN_CH][4];   // 8 KB
    const int wave = threadIdx.x >> 6, lane = threadIdx.x & 63;
    const int nb = blockIdx.x * 16 + wave * 4;    // 6250 * 16 == 100000
    #pragma unroll
    for (int r = 0; r < 4; r++) {
        float2 v = ((const float2*)(x + (long)(nb + r) * IN_CH))[lane];
        xshT[wave][2 * lane][r]     = v.x;
        xshT[wave][2 * lane + 1][r] = v.y;
    }
    // per-wave LDS slice: wave-lockstep + compiler lgkmcnt; no barrier
    f32x2 aA = {0.f, 0.f}, aB = {0.f, 0.f};
    #pragma unroll 8
    for (int k = 0; k < IN_CH; k++) {
        f32x4 q = *(const f32x4*)&xshT[wave][k][0];  // broadcast read
        float w = W1[k * 64 + lane];
        f32x2 wv = {w, w};
        aA += (f32x2){q.x, q.y} * wv;
        aB += (f32x2){q.z, q.w} * wv;
    }
    ybf[(long)(nb + 0) * 64 + lane] = __float2bfloat16(aA.x);
    ybf[(long)(nb + 1) * 64 + lane] = __float2bfloat16(aA.y);
    ybf[(long)(nb + 2) * 64 + lane] = __float2bfloat16(aB.x);
    ybf[(long)(nb + 3) * 64 + lane] = __float2bfloat16(aB.y);
}

// ---------------- fused layer: b128 gather -> relu -> W2 -> pool (+W1n) ------
// Each wave owns 4 nodes. Gather: 8 edge-groups (lane>>3) x 8 channels/lane
// (lane&7 -> dwords 4j..4j+3): ONE global_load_dwordx4 fetches 8 rows' worth
// per step; 4 steps cover a 32-edge chunk (vs 16 dword loads + 32
// readfirstlanes before). Group partials reduce through a conflict-free LDS
// exchange (stride 65 -> 2-way max, free). MLPs: round-2 scalar-FMA form
// (packed f32 is not double-rate on CDNA4 -- round-3 lesson).
template <bool HAS_NEXT>
__global__ __launch_bounds__(256, 6)
void layer_fused(const bf16* __restrict__ ybf, const int* __restrict__ cnt,
                 const int* __restrict__ col, const int* __restrict__ batch,
                 const float* __restrict__ b1, const float* __restrict__ W2,
                 const float* __restrict__ b2, const float* __restrict__ W1n,
                 bf16* __restrict__ ynext, float* __restrict__ pooled_l) {
    __shared__ float csh[4][8][65];               // group partials, 8320 B (stride 65: conflict-free)
    __shared__ float tsh[4][4][HID];              // t rows, 4 KB
    __shared__ float hsh[4][4][HID];              // h rows, 4 KB
    __shared__ float psh[4][HID];                 // pooling partials, 1 KB
    const int wave = threadIdx.x >> 6, lane = threadIdx.x & 63;
    const int eg = lane >> 3;                     // edge group 0..7
    const int j  = lane & 7;                      // dword-quad index in row
    const uint32 joff = (uint32)j * 16u;
    const int nA = blockIdx.x * 16;               // 6250 blocks
    const int nW = nA + wave * 4;                 // this wave's first node
    const char* ybase = (const char*)ybf;

    // ---- phase 1: gather + t = relu(y_self + b1 + agg) for 4 nodes ----
    #pragma unroll
    for (int r = 0; r < 4; r++) {
        const int n = __builtin_amdgcn_readfirstlane(nW + r);
        const int deg32 = __builtin_amdgcn_readfirstlane((cnt[n] + 31) & ~31);
        const int s = n * CAP;                    // < 6.4M, fits int
        float acc[8] = {0.f, 0.f, 0.f, 0.f, 0.f, 0.f, 0.f, 0.f};
        for (int i = 0; i < deg32; i += 32) {
            uint4 p[4];
            #pragma unroll
            for (int t = 0; t < 4; t++) {
                int c = col[s + i + 8 * t + eg];   // 8-lane broadcast vector load
                uint32 off = ((uint32)c << 7) + joff;
                p[t] = *(const uint4*)(ybase + off);
            }
            #pragma unroll
            for (int t = 0; t < 4; t++) {
                f32x2 f0 = unpk2(p[t].x); acc[0] += f0.x; acc[1] += f0.y;
                f32x2 f1 = unpk2(p[t].y); acc[2] += f1.x; acc[3] += f1.y;
                f32x2 f2 = unpk2(p[t].z); acc[4] += f2.x; acc[5] += f2.y;
                f32x2 f3 = unpk2(p[t].w); acc[6] += f3.x; acc[7] += f3.y;
            }
        }
        #pragma unroll
        for (int d = 0; d < 8; d++) csh[wave][eg][8 * j + d] = acc[d];
        // per-wave LDS slice: lockstep + compiler lgkmcnt; no barrier
        float sumv = 0.f;
        #pragma unroll
        for (int ee = 0; ee < 8; ee++) sumv += csh[wave][ee][lane];
        float t = bf2f(ybf[(long)n * 64 + lane]) + b1[lane] + sumv;
        tsh[wave][r][lane] = fmaxf(t, 0.f);
    }

    // ---- phase 2: h = relu(t @ W2 + b2), weights loaded once per wave ----
    float hv0, hv1, hv2, hv3;
    {
        const float bb = b2[lane];
        float h0 = bb, h1 = bb, h2 = bb, h3 = bb;
        for (int k = 0; k < 64; k += 4) {
            float4 t0 = *(const float4*)&tsh[wave][0][k];
            float4 t1 = *(const float4*)&tsh[wave][1][k];
            float4 t2 = *(const float4*)&tsh[wave][2][k];
            float4 t3 = *(const float4*)&tsh[wave][3][k];
            float w0 = W2[(k + 0) * 64 + lane];
            float w1 = W2[(k + 1) * 64 + lane];
            float w2 = W2[(k + 2) * 64 + lane];
            float w3 = W2[(k + 3) * 64 + lane];
            h0 += t0.x * w0 + t0.y * w1 + t0.z * w2 + t0.w * w3;
            h1 += t1.x * w0 + t1.y * w1 + t1.z * w2 + t1.w * w3;
            h2 += t2.x * w0 + t2.y * w1 + t2.z * w2 + t2.w * w3;
            h3 += t3.x * w0 + t3.y * w1 + t3.z * w2 + t3.w * w3;
        }
        hv0 = fmaxf(h0, 0.f); hv1 = fmaxf(h1, 0.f);
        hv2 = fmaxf(h2, 0.f); hv3 = fmaxf(h3, 0.f);
    }
    hsh[wave][0][lane] = hv0;
    hsh[wave][1][lane] = hv1;
    hsh[wave][2][lane] = hv2;
    hsh[wave][3][lane] = hv3;

    // ---- phase 3: ynext = h @ W1n (next layer's first linear, no bias) ----
    if (HAS_NEXT) {               // reads only own wave's hsh slice: no barrier
        float y0 = 0.f, y1 = 0.f, y2 = 0.f, y3 = 0.f;
        for (int k = 0; k < 64; k += 4) {
            float4 g0 = *(const float4*)&hsh[wave][0][k];
            float4 g1 = *(const float4*)&hsh[wave][1][k];
            float4 g2 = *(const float4*)&hsh[wave][2][k];
            float4 g3 = *(const float4*)&hsh[wave][3][k];
            float w0 = W1n[(k + 0) * 64 + lane];
            float w1 = W1n[(k + 1) * 64 + lane];
            float w2 = W1n[(k + 2) * 64 + lane];
            float w3 = W1n[(k + 3) * 64 + lane];
            y0 += g0.x * w0 + g0.y * w1 + g0.z * w2 + g0.w * w3;
            y1 += g1.x * w0 + g1.y * w1 + g1.z * w2 + g1.w * w3;
            y2 += g2.x * w0 + g2.y * w1 + g2.z * w2 + g2.w * w3;
            y3 += g3.x * w0 + g3.y * w1 + g3.z * w2 + g3.w * w3;
        }
        ynext[(long)(nW + 0) * 64 + lane] = __float2bfloat16(y0);
        ynext[(long)(nW + 1) * 64 + lane] = __float2bfloat16(y1);
        ynext[(long)(nW + 2) * 64 + lane] = __float2bfloat16(y2);
        ynext[(long)(nW + 3) * 64 + lane] = __float2bfloat16(y3);
    }

    // ---- pooling: 16 nodes -> 1 atomic when block is graph-uniform ----
    const int gA = __builtin_amdgcn_readfirstlane(batch[nA]);
    const int gZ = __builtin_amdgcn_readfirstlane(batch[nA + 15]);
    float* rep = pooled_l + (long)(blockIdx.x & (NREP - 1)) * NUM_GRAPHS * HID;
    if (gA == gZ) {               // ~98% of blocks: whole block same graph
        psh[wave][lane] = (hv0 + hv1) + (hv2 + hv3);
        __syncthreads();
        if (wave == 0) {
            float ssum = (psh[0][lane] + psh[1][lane]) + (psh[2][lane] + psh[3][lane]);
            atomicAdd(&rep[gA * 64 + lane], ssum);
        }
    } else {                      // graph boundary inside block: per-node atomics
        const int g0 = __builtin_amdgcn_readfirstlane(batch[nW + 0]);
        atomicAdd(&rep[g0 * 64 + lane], hv0);
        const int g1 = __builtin_amdgcn_readfirstlane(batch[nW + 1]);
        atomicAdd(&rep[g1 * 64 + lane], hv1);
        const int g2 = __builtin_amdgcn_readfirstlane(batch[nW + 2]);
        atomicAdd(&rep[g2 * 64 + lane], hv2);
        const int g3 = __builtin_amdgcn_readfirstlane(batch[nW + 3]);
        atomicAdd(&rep[g3 * 64 + lane], hv3);
    }
}

// ---------------- JK proj + classifier Linear1 + BN-stat atomics -------------
__global__ void jk_cls1(const float* __restrict__ pooled, const int* __restrict__ cntg,
                        const float* __restrict__ Wjk, const float* __restrict__ bjk,
                        const float* __restrict__ Wc1, const float* __restrict__ bc1,
                        float* __restrict__ Z, float* __restrict__ zstats) {
    __shared__ __align__(16) float sh[4][HID];    // per-layer summed pooled rows
    __shared__ float pacc[4][HID];                // per-wave partial pjk
    __shared__ __align__(16) float pj[HID];       // full pjk row
    __shared__ float zacc[4][HID];                // per-wave partial Z
    const int g = blockIdx.x;                     // 128 blocks
    const int wave = threadIdx.x >> 6, j = threadIdx.x & 63;

    // stage 1: wave w = layer w. Sum NREP replicas, then partial JK matmul.
    float s = 0.f;
    for (int r = 0; r < NREP; r++)
        s += pooled[((long)(wave * NREP + r) * NUM_GRAPHS + g) * 64 + j];
    sh[wave][j] = s;                              // own-wave slice: lockstep, no barrier
    const float* W = Wjk + (long)wave * HID * 64;
    float a = 0.f;
    for (int k = 0; k < 64; k += 4) {
        f32x4 sv = *(const f32x4*)&sh[wave][k];
        a += sv.x * W[(k + 0) * 64 + j];
        a += sv.y * W[(k + 1) * 64 + j];
        a += sv.z * W[(k + 2) * 64 + j];
        a += sv.w * W[(k + 3) * 64 + j];
    }
    pacc[wave][j] = a;
    __syncthreads();

    // full pjk row (every thread computes same value for its j)
    if (wave == 0)
        pj[j] = (float)cntg[g] * bjk[j]
              + (pacc[0][j] + pacc[1][j]) + (pacc[2][j] + pacc[3][j]);
    __syncthreads();

    // stage 2: wave w handles k in [16w, 16w+16) of Z = pjk @ Wc1
    float z = 0.f;
    for (int k = 16 * wave; k < 16 * wave + 16; k += 4) {
        f32x4 pv = *(const f32x4*)&pj[k];
        z += pv.x * Wc1[(k + 0) * 64 + j];
        z += pv.y * Wc1[(k + 1) * 64 + j];
        z += pv.z * Wc1[(k + 2) * 64 + j];
        z += pv.w * Wc1[(k + 3) * 64 + j];
    }
    zacc[wave][j] = z;
    __syncthreads();
    if (wave == 0) {
        float zv = bc1[j] + (zacc[0][j] + zacc[1][j]) + (zacc[2][j] + zacc[3][j]);
        Z[g * 64 + j] = zv;
        atomicAdd(&zstats[j], zv);
        atomicAdd(&zstats[HID + j], zv * zv);
    }
}

// ---------------- classifier tail: BN(batch stats) -> ReLU -> Linear ---------
__global__ void cls2(const float* __restrict__ Z, const float* __restrict__ zstats,
                     const float* __restrict__ gamma, const float* __restrict__ beta,
                     const float* __restrict__ Wc2, const float* __restrict__ bc2,
                     float* __restrict__ out) {
    __shared__ float v[HID];
    const int g = blockIdx.x, j = threadIdx.x;    // 128 blocks x 64 threads
    float mu = zstats[j] * (1.f / NUM_GRAPHS);
    float var = zstats[HID + j] * (1.f / NUM_GRAPHS) - mu * mu;
    float rs = rsqrtf(var + BN_EPS);
    float zv = Z[g * 64 + j];
    v[j] = fmaxf(gamma[j] * (zv - mu) * rs + beta[j], 0.f);
    // single wave: lockstep + compiler lgkmcnt; no barrier
    if (j < OUT_CH) {
        float acc = bc2[j];
        for (int k = 0; k < 64; k++) acc += v[k] * Wc2[k * OUT_CH + j];
        out[g * OUT_CH + j] = acc;
    }
}

// -----------------------------------------------------------------------------
extern "C" void kernel_launch(void* const* d_in, const int* in_sizes, int n_in,
                              void* d_out, int out_size, void* d_ws, size_t ws_size,
                              hipStream_t stream) {
    const float* x     = (const float*)d_in[0];
    const int*   ei    = (const int*)d_in[1];
    const int*   batch = (const int*)d_in[2];
    const float* W1f   = (const float*)d_in[3];
    const float* b1f   = (const float*)d_in[4];
    const float* W2f   = (const float*)d_in[5];
    const float* b2f   = (const float*)d_in[6];
    const float* W1r   = (const float*)d_in[7];
    const float* b1r   = (const float*)d_in[8];
    const float* W2r   = (const float*)d_in[9];
    const float* b2r   = (const float*)d_in[10];
    const float* Wjk   = (const float*)d_in[11];
    const float* bjk   = (const float*)d_in[12];
    const float* Wc1   = (const float*)d_in[13];
    const float* bc1   = (const float*)d_in[14];
    const float* gamma = (const float*)d_in[15];
    const float* beta  = (const float*)d_in[16];
    const float* Wc2   = (const float*)d_in[17];
    const float* bc2   = (const float*)d_in[18];

    const int* src = ei;
    const int* dst = ei + N_EDGES;

    // workspace layout (all segments 8-B aligned)
    float* ws        = (float*)d_ws;
    float* Z         = ws;                                      // 8192 floats (cls Z)
    bf16*  ybfA      = (bf16*)(Z + NUM_GRAPHS * HID);           // (N+1)*64 bf16
    bf16*  ybfB      = ybfA + (long)(N_NODES + 1) * HID;        // (N+1)*64 bf16
    int*   cnt       = (int*)(ybfB + (long)(N_NODES + 1) * HID);// 100000
    float* pooled    = (float*)(cnt + N_NODES);                 // 4*8*8192 floats
    int*   ghist     = (int*)(pooled + (long)N_LAYERS * NREP * NUM_GRAPHS * HID); // 256
    int*   gcursor   = ghist + NBKT;                            // 256
    int*   cntg      = gcursor + NBKT;                          // 128
    float* zstats    = (float*)(cntg + NUM_GRAPHS);             // 128 (sum | sumsq)
    int*   col       = (int*)(zstats + 2 * HID);                // 6.4M ints
    int2*  epart     = (int2*)(col + (long)N_NODES * CAP);      // 1.6M int2
    // zeroed span: cnt .. zstats (cntg zeroed harmlessly; bscan rewrites it)
    const int ZN = N_NODES + N_LAYERS * NREP * NUM_GRAPHS * HID
                 + 2 * NBKT + NUM_GRAPHS + 2 * HID;

    // ---- CSR build: zero -> bucket hist -> scan -> partition -> fill -> pad --
    zero_i<<<360, 256, 0, stream>>>(cnt, ZN);
    bhist<<<PNB, 256, 0, stream>>>(dst, ghist);
    bscan<<<1, 256, 0, stream>>>(ghist, gcursor, batch, cntg, ybfA, ybfB);
    bpart<<<PNB, 256, 0, stream>>>(src, dst, gcursor, epart);
    fillp<<<PNB, 256, 0, stream>>>(epart, cnt, col);
    pad_rows<<<(N_NODES + 255) / 256, 256, 0, stream>>>(cnt, col);

    // ---- layer-0 pre-projection (dense, streaming; 4 nodes/wave) ----
    proj0<<<N_NODES / 16, 256, 0, stream>>>(x, W1f, ybfA);

    // ---- 4 fused layers (16 nodes per block: 4 waves x 4 nodes/wave) ----
    const int NB = N_NODES / 16;                                // 6250
    const long PL = (long)NREP * NUM_GRAPHS * HID;
    layer_fused<true><<<NB, 256, 0, stream>>>(
        ybfA, cnt, col, batch, b1f, W2f, b2f,
        W1r, ybfB, pooled);
    layer_fused<true><<<NB, 256, 0, stream>>>(
        ybfB, cnt, col, batch, b1r, W2r, b2r,
        W1r + (long)1 * HID * HID, ybfA, pooled + 1 * PL);
    layer_fused<true><<<NB, 256, 0, stream>>>(
        ybfA, cnt, col, batch, b1r + HID, W2r + (long)1 * HID * HID, b2r + HID,
        W1r + (long)2 * HID * HID, ybfB, pooled + 2 * PL);
    layer_fused<false><<<NB, 256, 0, stream>>>(
        ybfB, cnt, col, batch, b1r + 2 * HID, W2r + (long)2 * HID * HID, b2r + 2 * HID,
        nullptr, nullptr, pooled + 3 * PL);

    // ---- JK + classifier: wide tail (128 blocks each) ----
    jk_cls1<<<NUM_GRAPHS, 256, 0, stream>>>(pooled, cntg, Wjk, bjk, Wc1, bc1,
                                            Z, zstats);
    cls2<<<NUM_GRAPHS, 64, 0, stream>>>(Z, zstats, gamma, beta, Wc2, bc2,
                                        (float*)d_out);
}

// Round 6
// 427.827 us; speedup vs baseline: 1.7108x; 1.0987x over previous
//
#include <hip/hip_runtime.h>
#include <hip/hip_bf16.h>

#define N_NODES    100000
#define N_EDGES    1600000
#define IN_CH      128
#define HID        64
#define N_LAYERS   4
#define OUT_CH     10
#define NUM_GRAPHS 128
#define BN_EPS     1e-5f
#define CAP        64             // padded CSR row capacity; P(deg>64) ~ 1e-19 at Poisson(16)
#define NREP       8              // pooled replicas (cuts per-address atomic chains 8x)
#define NBKT       256            // dst>>9 -> buckets 0..195 (256 slots for pow2 LDS)
#define NBUCK      196            // ceil(100000 / 512) actual buckets
#define EPB        2048           // edges per block in partition kernels
#define PNB        782            // ceil(1.6M / 2048)
#define BCAP       10272          // per-bucket edge capacity (mean 8192, sd 90: 22 sigma)

typedef __hip_bfloat16 bf16;
typedef unsigned int uint32;
typedef float f32x2 __attribute__((ext_vector_type(2)));
typedef float f32x4 __attribute__((ext_vector_type(4)));

__device__ __forceinline__ float bf2f(bf16 v) { return __bfloat162float(v); }
// unpack packed bf16x2 dword -> f32x2 pair (bf16 -> f32 is <<16)
__device__ __forceinline__ f32x2 unpk2(uint32 p) {
    f32x2 r;
    r.x = __uint_as_float(p << 16);
    r.y = __uint_as_float(p & 0xffff0000u);
    return r;
}

// ---------------- zero the accumulator/stat region ---------------------------
__global__ void zero_i(int* __restrict__ p, int n) {
    int i = blockIdx.x * 256 + threadIdx.x;
    int st = gridDim.x * 256;
    for (; i < n; i += st) p[i] = 0;
}

// ---------------- bucket histogram (LDS-aggregated) --------------------------
__global__ void bhist(const int* __restrict__ dst, int* __restrict__ ghist) {
    __shared__ int h[NBKT];
    int t = threadIdx.x;
    h[t] = 0;
    __syncthreads();
    long base = (long)blockIdx.x * EPB;
    for (int u = 0; u < 8; u++) {
        long e = base + u * 256 + t;
        if (e < N_EDGES) atomicAdd(&h[dst[e] >> 9], 1);
    }
    __syncthreads();
    if (h[t]) atomicAdd(&ghist[t], h[t]);
}

// ---------------- bucket scan + cntg (binary search) + ybf pad-row zero ------
__global__ void bscan(const int* __restrict__ ghist, int* __restrict__ gcursor,
                      int* __restrict__ gbase,
                      const int* __restrict__ batch, int* __restrict__ cntg,
                      bf16* __restrict__ ybfA, bf16* __restrict__ ybfB) {
    __shared__ int sh[NBKT];
    int t = threadIdx.x;                          // 256 threads
    int v = ghist[t];
    sh[t] = v;
    __syncthreads();
    for (int off = 1; off < NBKT; off <<= 1) {
        int a = (t >= off) ? sh[t - off] : 0;
        __syncthreads();
        sh[t] += a;
        __syncthreads();
    }
    gcursor[t] = sh[t] - v;                       // exclusive bucket base (bpart cursor)
    gbase[t]   = sh[t] - v;                       // immutable copy for bfill
    if (t < NUM_GRAPHS) {                         // per-graph node counts
        int g = t, lo = 0, hi = N_NODES;
        while (lo < hi) { int m = (lo + hi) >> 1; if (batch[m] < g) lo = m + 1; else hi = m; }
        int lb = lo;
        lo = 0; hi = N_NODES;
        while (lo < hi) { int m = (lo + hi) >> 1; if (batch[m] < g + 1) lo = m + 1; else hi = m; }
        cntg[g] = lo - lb;
    }
    if (t < HID) {                                // sentinel zero-row for tail-free gather
        ybfA[(long)N_NODES * HID + t] = __float2bfloat16(0.f);
        ybfB[(long)N_NODES * HID + t] = __float2bfloat16(0.f);
    }
}

// ---------------- partition edges into bucket order (packed 4-B records) -----
// record = src | (dst&511)<<17  (src < 2^17, local dst < 2^9)
__global__ void bpart(const int* __restrict__ src, const int* __restrict__ dst,
                      int* __restrict__ gcursor, int* __restrict__ epart) {
    __shared__ int h[NBKT];
    __shared__ int cur[NBKT];
    int t = threadIdx.x;
    h[t] = 0;
    __syncthreads();
    long base = (long)blockIdx.x * EPB;
    int myd[8], mys[8];
    for (int u = 0; u < 8; u++) {
        long e = base + u * 256 + t;
        if (e < N_EDGES) {
            myd[u] = dst[e];
            mys[u] = src[e];
            atomicAdd(&h[myd[u] >> 9], 1);
        } else myd[u] = -1;
    }
    __syncthreads();
    if (h[t]) cur[t] = atomicAdd(&gcursor[t], h[t]);
    __syncthreads();
    for (int u = 0; u < 8; u++) {
        if (myd[u] >= 0) {
            int pos = atomicAdd(&cur[myd[u] >> 9], 1);
            epart[pos] = mys[u] | ((myd[u] & 511) << 17);
        }
    }
}

// ---------------- per-bucket LDS counting sort -> coalesced CSR fill ---------
// Replaces fillp + pad_rows. One block per bucket (512 nodes, ~8.2K edges):
// count degrees in LDS, scan, scatter srcs into sorted LDS array, then write
// each row (data + sentinel pad to deg32) as sequential int4 stores plus
// cnt[n]. Write-allocate traffic drops ~78 MB -> ~13 MB (full lines only).
__global__ __launch_bounds__(256)
void bfill(const int* __restrict__ epart, const int* __restrict__ gbase,
           const int* __restrict__ ghist, int* __restrict__ cnt,
           int* __restrict__ col) {
    __shared__ int lcnt[512];
    __shared__ int loff[512];
    __shared__ int psum[256];
    __shared__ int lsrc[BCAP];
    const int b = blockIdx.x;                     // 196 blocks
    const int t = threadIdx.x;                    // 256 threads
    const int n0 = b << 9;
    const int nN = min(512, N_NODES - n0);        // nodes in this bucket
    const int base = gbase[b];
    const int m = ghist[b];

    lcnt[t] = 0; lcnt[t + 256] = 0;
    __syncthreads();
    // pass 1: per-node degree
    for (int e = t; e < m; e += 256)
        atomicAdd(&lcnt[(uint32)epart[base + e] >> 17], 1);
    __syncthreads();
    // block scan over 512 counts (2 per thread + 256-wide Hillis-Steele)
    int c0 = lcnt[2 * t], c1 = lcnt[2 * t + 1];
    psum[t] = c0 + c1;
    __syncthreads();
    for (int off = 1; off < 256; off <<= 1) {
        int a = (t >= off) ? psum[t - off] : 0;
        __syncthreads();
        psum[t] += a;
        __syncthreads();
    }
    int eb = psum[t] - (c0 + c1);                 // exclusive base of pair
    loff[2 * t] = eb;
    loff[2 * t + 1] = eb + c0;
    lcnt[2 * t] = 0; lcnt[2 * t + 1] = 0;         // reuse as scatter cursor
    __syncthreads();
    // pass 2: scatter srcs into per-node runs
    for (int e = t; e < m; e += 256) {
        uint32 v = (uint32)epart[base + e];
        int ln = v >> 17;
        int slot = atomicAdd(&lcnt[ln], 1);
        lsrc[loff[ln] + slot] = (int)(v & 0x1FFFFu);
    }
    __syncthreads();
    // write rows: data + sentinel pad to deg32, int4 stores; plus cnt
    for (int ln = t; ln < nN; ln += 256) {
        int deg = lcnt[ln];
        int st  = loff[ln];
        int n   = n0 + ln;
        cnt[n] = deg;
        int d32 = (deg + 31) & ~31;
        int* row = col + n * CAP;
        for (int s4 = 0; s4 < d32; s4 += 4) {
            int4 q;
            q.x = (s4 + 0 < deg) ? lsrc[st + s4 + 0] : N_NODES;
            q.y = (s4 + 1 < deg) ? lsrc[st + s4 + 1] : N_NODES;
            q.z = (s4 + 2 < deg) ? lsrc[st + s4 + 2] : N_NODES;
            q.w = (s4 + 3 < deg) ? lsrc[st + s4 + 3] : N_NODES;
            *(int4*)(row + s4) = q;
        }
    }
}

// ---------------- layer-0 pre-projection: ybf = bf16(x @ W1f) (no bias) ------
// 4 nodes per wave; x staged TRANSPOSED ([k][r]) so the MACs run as packed
// pairs on broadcast ds_read_b128.
__global__ void proj0(const float* __restrict__ x, const float* __restrict__ W1,
                      bf16* __restrict__ ybf) {
    __shared__ __align__(16) float xshT[4][IN_CH][4];   // 8 KB
    const int wave = threadIdx.x >> 6, lane = threadIdx.x & 63;
    const int nb = blockIdx.x * 16 + wave * 4;    // 6250 * 16 == 100000
    #pragma unroll
    for (int r = 0; r < 4; r++) {
        float2 v = ((const float2*)(x + (long)(nb + r) * IN_CH))[lane];
        xshT[wave][2 * lane][r]     = v.x;
        xshT[wave][2 * lane + 1][r] = v.y;
    }
    // per-wave LDS slice: wave-lockstep + compiler lgkmcnt; no barrier
    f32x2 aA = {0.f, 0.f}, aB = {0.f, 0.f};
    #pragma unroll 8
    for (int k = 0; k < IN_CH; k++) {
        f32x4 q = *(const f32x4*)&xshT[wave][k][0];  // broadcast read
        float w = W1[k * 64 + lane];
        f32x2 wv = {w, w};
        aA += (f32x2){q.x, q.y} * wv;
        aB += (f32x2){q.z, q.w} * wv;
    }
    ybf[(long)(nb + 0) * 64 + lane] = __float2bfloat16(aA.x);
    ybf[(long)(nb + 1) * 64 + lane] = __float2bfloat16(aA.y);
    ybf[(long)(nb + 2) * 64 + lane] = __float2bfloat16(aB.x);
    ybf[(long)(nb + 3) * 64 + lane] = __float2bfloat16(aB.y);
}

// ---------------- fused layer: b128 gather -> relu -> W2 -> pool (+W1n) ------
// Each wave owns 4 nodes. Gather: 8 edge-groups (lane>>3) x 8 channels/lane
// (lane&7 -> dwords 4j..4j+3): ONE global_load_dwordx4 fetches 8 rows' worth
// per step; 4 steps cover a 32-edge chunk. Group partials reduce through a
// conflict-free LDS exchange (stride 65). MLPs: scalar-FMA form (packed f32
// is not double-rate on CDNA4 -- round-3 lesson).
template <bool HAS_NEXT>
__global__ __launch_bounds__(256, 6)
void layer_fused(const bf16* __restrict__ ybf, const int* __restrict__ cnt,
                 const int* __restrict__ col, const int* __restrict__ batch,
                 const float* __restrict__ b1, const float* __restrict__ W2,
                 const float* __restrict__ b2, const float* __restrict__ W1n,
                 bf16* __restrict__ ynext, float* __restrict__ pooled_l) {
    __shared__ float csh[4][8][65];               // group partials (stride 65: conflict-free)
    __shared__ float tsh[4][4][HID];              // t rows, 4 KB
    __shared__ float hsh[4][4][HID];              // h rows, 4 KB
    __shared__ float psh[4][HID];                 // pooling partials, 1 KB
    const int wave = threadIdx.x >> 6, lane = threadIdx.x & 63;
    const int eg = lane >> 3;                     // edge group 0..7
    const int j  = lane & 7;                      // dword-quad index in row
    const uint32 joff = (uint32)j * 16u;
    const int nA = blockIdx.x * 16;               // 6250 blocks
    const int nW = nA + wave * 4;                 // this wave's first node
    const char* ybase = (const char*)ybf;

    // ---- phase 1: gather + t = relu(y_self + b1 + agg) for 4 nodes ----
    #pragma unroll
    for (int r = 0; r < 4; r++) {
        const int n = __builtin_amdgcn_readfirstlane(nW + r);
        const int deg32 = __builtin_amdgcn_readfirstlane((cnt[n] + 31) & ~31);
        const int s = n * CAP;                    // < 6.4M, fits int
        float acc[8] = {0.f, 0.f, 0.f, 0.f, 0.f, 0.f, 0.f, 0.f};
        for (int i = 0; i < deg32; i += 32) {
            uint4 p[4];
            #pragma unroll
            for (int t = 0; t < 4; t++) {
                int c = col[s + i + 8 * t + eg];   // 8-lane broadcast vector load
                uint32 off = ((uint32)c << 7) + joff;
                p[t] = *(const uint4*)(ybase + off);
            }
            #pragma unroll
            for (int t = 0; t < 4; t++) {
                f32x2 f0 = unpk2(p[t].x); acc[0] += f0.x; acc[1] += f0.y;
                f32x2 f1 = unpk2(p[t].y); acc[2] += f1.x; acc[3] += f1.y;
                f32x2 f2 = unpk2(p[t].z); acc[4] += f2.x; acc[5] += f2.y;
                f32x2 f3 = unpk2(p[t].w); acc[6] += f3.x; acc[7] += f3.y;
            }
        }
        #pragma unroll
        for (int d = 0; d < 8; d++) csh[wave][eg][8 * j + d] = acc[d];
        // per-wave LDS slice: lockstep + compiler lgkmcnt; no barrier
        float sumv = 0.f;
        #pragma unroll
        for (int ee = 0; ee < 8; ee++) sumv += csh[wave][ee][lane];
        float t = bf2f(ybf[(long)n * 64 + lane]) + b1[lane] + sumv;
        tsh[wave][r][lane] = fmaxf(t, 0.f);
    }

    // ---- phase 2: h = relu(t @ W2 + b2), weights loaded once per wave ----
    float hv0, hv1, hv2, hv3;
    {
        const float bb = b2[lane];
        float h0 = bb, h1 = bb, h2 = bb, h3 = bb;
        for (int k = 0; k < 64; k += 4) {
            float4 t0 = *(const float4*)&tsh[wave][0][k];
            float4 t1 = *(const float4*)&tsh[wave][1][k];
            float4 t2 = *(const float4*)&tsh[wave][2][k];
            float4 t3 = *(const float4*)&tsh[wave][3][k];
            float w0 = W2[(k + 0) * 64 + lane];
            float w1 = W2[(k + 1) * 64 + lane];
            float w2 = W2[(k + 2) * 64 + lane];
            float w3 = W2[(k + 3) * 64 + lane];
            h0 += t0.x * w0 + t0.y * w1 + t0.z * w2 + t0.w * w3;
            h1 += t1.x * w0 + t1.y * w1 + t1.z * w2 + t1.w * w3;
            h2 += t2.x * w0 + t2.y * w1 + t2.z * w2 + t2.w * w3;
            h3 += t3.x * w0 + t3.y * w1 + t3.z * w2 + t3.w * w3;
        }
        hv0 = fmaxf(h0, 0.f); hv1 = fmaxf(h1, 0.f);
        hv2 = fmaxf(h2, 0.f); hv3 = fmaxf(h3, 0.f);
    }
    hsh[wave][0][lane] = hv0;
    hsh[wave][1][lane] = hv1;
    hsh[wave][2][lane] = hv2;
    hsh[wave][3][lane] = hv3;

    // ---- phase 3: ynext = h @ W1n (next layer's first linear, no bias) ----
    if (HAS_NEXT) {               // reads only own wave's hsh slice: no barrier
        float y0 = 0.f, y1 = 0.f, y2 = 0.f, y3 = 0.f;
        for (int k = 0; k < 64; k += 4) {
            float4 g0 = *(const float4*)&hsh[wave][0][k];
            float4 g1 = *(const float4*)&hsh[wave][1][k];
            float4 g2 = *(const float4*)&hsh[wave][2][k];
            float4 g3 = *(const float4*)&hsh[wave][3][k];
            float w0 = W1n[(k + 0) * 64 + lane];
            float w1 = W1n[(k + 1) * 64 + lane];
            float w2 = W1n[(k + 2) * 64 + lane];
            float w3 = W1n[(k + 3) * 64 + lane];
            y0 += g0.x * w0 + g0.y * w1 + g0.z * w2 + g0.w * w3;
            y1 += g1.x * w0 + g1.y * w1 + g1.z * w2 + g1.w * w3;
            y2 += g2.x * w0 + g2.y * w1 + g2.z * w2 + g2.w * w3;
            y3 += g3.x * w0 + g3.y * w1 + g3.z * w2 + g3.w * w3;
        }
        ynext[(long)(nW + 0) * 64 + lane] = __float2bfloat16(y0);
        ynext[(long)(nW + 1) * 64 + lane] = __float2bfloat16(y1);
        ynext[(long)(nW + 2) * 64 + lane] = __float2bfloat16(y2);
        ynext[(long)(nW + 3) * 64 + lane] = __float2bfloat16(y3);
    }

    // ---- pooling: 16 nodes -> 1 atomic when block is graph-uniform ----
    const int gA = __builtin_amdgcn_readfirstlane(batch[nA]);
    const int gZ = __builtin_amdgcn_readfirstlane(batch[nA + 15]);
    float* rep = pooled_l + (long)(blockIdx.x & (NREP - 1)) * NUM_GRAPHS * HID;
    if (gA == gZ) {               // ~98% of blocks: whole block same graph
        psh[wave][lane] = (hv0 + hv1) + (hv2 + hv3);
        __syncthreads();
        if (wave == 0) {
            float ssum = (psh[0][lane] + psh[1][lane]) + (psh[2][lane] + psh[3][lane]);
            atomicAdd(&rep[gA * 64 + lane], ssum);
        }
    } else {                      // graph boundary inside block: per-node atomics
        const int g0 = __builtin_amdgcn_readfirstlane(batch[nW + 0]);
        atomicAdd(&rep[g0 * 64 + lane], hv0);
        const int g1 = __builtin_amdgcn_readfirstlane(batch[nW + 1]);
        atomicAdd(&rep[g1 * 64 + lane], hv1);
        const int g2 = __builtin_amdgcn_readfirstlane(batch[nW + 2]);
        atomicAdd(&rep[g2 * 64 + lane], hv2);
        const int g3 = __builtin_amdgcn_readfirstlane(batch[nW + 3]);
        atomicAdd(&rep[g3 * 64 + lane], hv3);
    }
}

// ---------------- JK proj + classifier Linear1 + BN-stat atomics -------------
__global__ void jk_cls1(const float* __restrict__ pooled, const int* __restrict__ cntg,
                        const float* __restrict__ Wjk, const float* __restrict__ bjk,
                        const float* __restrict__ Wc1, const float* __restrict__ bc1,
                        float* __restrict__ Z, float* __restrict__ zstats) {
    __shared__ __align__(16) float sh[4][HID];    // per-layer summed pooled rows
    __shared__ float pacc[4][HID];                // per-wave partial pjk
    __shared__ __align__(16) float pj[HID];       // full pjk row
    __shared__ float zacc[4][HID];                // per-wave partial Z
    const int g = blockIdx.x;                     // 128 blocks
    const int wave = threadIdx.x >> 6, j = threadIdx.x & 63;

    // stage 1: wave w = layer w. Sum NREP replicas, then partial JK matmul.
    float s = 0.f;
    for (int r = 0; r < NREP; r++)
        s += pooled[((long)(wave * NREP + r) * NUM_GRAPHS + g) * 64 + j];
    sh[wave][j] = s;                              // own-wave slice: lockstep, no barrier
    const float* W = Wjk + (long)wave * HID * 64;
    float a = 0.f;
    for (int k = 0; k < 64; k += 4) {
        f32x4 sv = *(const f32x4*)&sh[wave][k];
        a += sv.x * W[(k + 0) * 64 + j];
        a += sv.y * W[(k + 1) * 64 + j];
        a += sv.z * W[(k + 2) * 64 + j];
        a += sv.w * W[(k + 3) * 64 + j];
    }
    pacc[wave][j] = a;
    __syncthreads();

    // full pjk row (every thread computes same value for its j)
    if (wave == 0)
        pj[j] = (float)cntg[g] * bjk[j]
              + (pacc[0][j] + pacc[1][j]) + (pacc[2][j] + pacc[3][j]);
    __syncthreads();

    // stage 2: wave w handles k in [16w, 16w+16) of Z = pjk @ Wc1
    float z = 0.f;
    for (int k = 16 * wave; k < 16 * wave + 16; k += 4) {
        f32x4 pv = *(const f32x4*)&pj[k];
        z += pv.x * Wc1[(k + 0) * 64 + j];
        z += pv.y * Wc1[(k + 1) * 64 + j];
        z += pv.z * Wc1[(k + 2) * 64 + j];
        z += pv.w * Wc1[(k + 3) * 64 + j];
    }
    zacc[wave][j] = z;
    __syncthreads();
    if (wave == 0) {
        float zv = bc1[j] + (zacc[0][j] + zacc[1][j]) + (zacc[2][j] + zacc[3][j]);
        Z[g * 64 + j] = zv;
        atomicAdd(&zstats[j], zv);
        atomicAdd(&zstats[HID + j], zv * zv);
    }
}

// ---------------- classifier tail: BN(batch stats) -> ReLU -> Linear ---------
__global__ void cls2(const float* __restrict__ Z, const float* __restrict__ zstats,
                     const float* __restrict__ gamma, const float* __restrict__ beta,
                     const float* __restrict__ Wc2, const float* __restrict__ bc2,
                     float* __restrict__ out) {
    __shared__ float v[HID];
    const int g = blockIdx.x, j = threadIdx.x;    // 128 blocks x 64 threads
    float mu = zstats[j] * (1.f / NUM_GRAPHS);
    float var = zstats[HID + j] * (1.f / NUM_GRAPHS) - mu * mu;
    float rs = rsqrtf(var + BN_EPS);
    float zv = Z[g * 64 + j];
    v[j] = fmaxf(gamma[j] * (zv - mu) * rs + beta[j], 0.f);
    // single wave: lockstep + compiler lgkmcnt; no barrier
    if (j < OUT_CH) {
        float acc = bc2[j];
        for (int k = 0; k < 64; k++) acc += v[k] * Wc2[k * OUT_CH + j];
        out[g * OUT_CH + j] = acc;
    }
}

// -----------------------------------------------------------------------------
extern "C" void kernel_launch(void* const* d_in, const int* in_sizes, int n_in,
                              void* d_out, int out_size, void* d_ws, size_t ws_size,
                              hipStream_t stream) {
    const float* x     = (const float*)d_in[0];
    const int*   ei    = (const int*)d_in[1];
    const int*   batch = (const int*)d_in[2];
    const float* W1f   = (const float*)d_in[3];
    const float* b1f   = (const float*)d_in[4];
    const float* W2f   = (const float*)d_in[5];
    const float* b2f   = (const float*)d_in[6];
    const float* W1r   = (const float*)d_in[7];
    const float* b1r   = (const float*)d_in[8];
    const float* W2r   = (const float*)d_in[9];
    const float* b2r   = (const float*)d_in[10];
    const float* Wjk   = (const float*)d_in[11];
    const float* bjk   = (const float*)d_in[12];
    const float* Wc1   = (const float*)d_in[13];
    const float* bc1   = (const float*)d_in[14];
    const float* gamma = (const float*)d_in[15];
    const float* beta  = (const float*)d_in[16];
    const float* Wc2   = (const float*)d_in[17];
    const float* bc2   = (const float*)d_in[18];

    const int* src = ei;
    const int* dst = ei + N_EDGES;

    // workspace layout (all segments 8-B aligned)
    float* ws        = (float*)d_ws;
    float* Z         = ws;                                      // 8192 floats (cls Z)
    bf16*  ybfA      = (bf16*)(Z + NUM_GRAPHS * HID);           // (N+1)*64 bf16
    bf16*  ybfB      = ybfA + (long)(N_NODES + 1) * HID;        // (N+1)*64 bf16
    int*   cnt       = (int*)(ybfB + (long)(N_NODES + 1) * HID);// 100000 (written by bfill)
    float* pooled    = (float*)(cnt + N_NODES);                 // 4*8*8192 floats
    int*   ghist     = (int*)(pooled + (long)N_LAYERS * NREP * NUM_GRAPHS * HID); // 256
    int*   gcursor   = ghist + NBKT;                            // 256 (bpart cursor)
    int*   gbase     = gcursor + NBKT;                          // 256 (immutable base)
    int*   cntg      = gbase + NBKT;                            // 128
    float* zstats    = (float*)(cntg + NUM_GRAPHS);             // 128 (sum | sumsq)
    int*   col       = (int*)(zstats + 2 * HID);                // 6.4M ints
    int*   epart     = col + (long)N_NODES * CAP;               // 1.6M packed ints
    // zeroed span: pooled .. zstats (+gbase/gcursor/cntg harmlessly; cnt NOT needed)
    const int ZN = N_LAYERS * NREP * NUM_GRAPHS * HID
                 + 3 * NBKT + NUM_GRAPHS + 2 * HID;

    // ---- CSR build: zero -> hist -> scan -> partition -> bucket-sort fill ---
    zero_i<<<360, 256, 0, stream>>>((int*)pooled, ZN);
    bhist<<<PNB, 256, 0, stream>>>(dst, ghist);
    bscan<<<1, 256, 0, stream>>>(ghist, gcursor, gbase, batch, cntg, ybfA, ybfB);
    bpart<<<PNB, 256, 0, stream>>>(src, dst, gcursor, epart);
    bfill<<<NBUCK, 256, 0, stream>>>(epart, gbase, ghist, cnt, col);

    // ---- layer-0 pre-projection (dense, streaming; 4 nodes/wave) ----
    proj0<<<N_NODES / 16, 256, 0, stream>>>(x, W1f, ybfA);

    // ---- 4 fused layers (16 nodes per block: 4 waves x 4 nodes/wave) ----
    const int NB = N_NODES / 16;                                // 6250
    const long PL = (long)NREP * NUM_GRAPHS * HID;
    layer_fused<true><<<NB, 256, 0, stream>>>(
        ybfA, cnt, col, batch, b1f, W2f, b2f,
        W1r, ybfB, pooled);
    layer_fused<true><<<NB, 256, 0, stream>>>(
        ybfB, cnt, col, batch, b1r, W2r, b2r,
        W1r + (long)1 * HID * HID, ybfA, pooled + 1 * PL);
    layer_fused<true><<<NB, 256, 0, stream>>>(
        ybfA, cnt, col, batch, b1r + HID, W2r + (long)1 * HID * HID, b2r + HID,
        W1r + (long)2 * HID * HID, ybfB, pooled + 2 * PL);
    layer_fused<false><<<NB, 256, 0, stream>>>(
        ybfB, cnt, col, batch, b1r + 2 * HID, W2r + (long)2 * HID * HID, b2r + 2 * HID,
        nullptr, nullptr, pooled + 3 * PL);

    // ---- JK + classifier: wide tail (128 blocks each) ----
    jk_cls1<<<NUM_GRAPHS, 256, 0, stream>>>(pooled, cntg, Wjk, bjk, Wc1, bc1,
                                            Z, zstats);
    cls2<<<NUM_GRAPHS, 64, 0, stream>>>(Z, zstats, gamma, beta, Wc2, bc2,
                                        (float*)d_out);
}

// Round 8
// 422.744 us; speedup vs baseline: 1.7314x; 1.0120x over previous
//
#include <hip/hip_runtime.h>
#include <hip/hip_bf16.h>

#define N_NODES    100000
#define N_EDGES    1600000
#define IN_CH      128
#define HID        64
#define N_LAYERS   4
#define OUT_CH     10
#define NUM_GRAPHS 128
#define BN_EPS     1e-5f
#define CAP        64             // padded CSR row capacity; P(deg>64) ~ 1e-19 at Poisson(16)
#define NREP       8              // pooled replicas (cuts per-address atomic chains 8x)
#define NBKT       256            // dst>>9 -> buckets 0..195 (256 slots for pow2 LDS)
#define NBUCK      196            // ceil(100000 / 512) actual buckets
#define EPB        2048           // edges per block in partition kernels
#define PNB        782            // ceil(1.6M / 2048)
#define SUBCAP     2688           // per-128-node-slice edge capacity (mean 2048, sd 45: 14 sigma)
#define ZB         360            // zero blocks inside stage1
#define P0B        6250           // proj0 blocks inside stage1

typedef __hip_bfloat16 bf16;
typedef unsigned int uint32;
typedef float f32x2 __attribute__((ext_vector_type(2)));
typedef float f32x4 __attribute__((ext_vector_type(4)));

__device__ __forceinline__ float bf2f(bf16 v) { return __bfloat162float(v); }
// unpack packed bf16x2 dword -> f32x2 pair (bf16 -> f32 is <<16)
__device__ __forceinline__ f32x2 unpk2(uint32 p) {
    f32x2 r;
    r.x = __uint_as_float(p << 16);
    r.y = __uint_as_float(p & 0xffff0000u);
    return r;
}

// ---------------- zero helper (also used for ghist pre-clear) ----------------
__global__ void zero_i(int* __restrict__ p, int n) {
    int i = blockIdx.x * 256 + threadIdx.x;
    int st = gridDim.x * 256;
    for (; i < n; i += st) p[i] = 0;
}

// ---------------- stage1: fused bhist | zero | proj0 (independent parts) -----
// blocks [0,782): edge-bucket histogram; [782,1142): zero accum region;
// [1142,7392): layer-0 pre-projection ybf = bf16(x @ W1f). ghist is zeroed by
// a preceding zero_i launch (it can't share the zero span with its own
// atomics).
__global__ void stage1(const int* __restrict__ dst, int* __restrict__ ghist,
                       int* __restrict__ zp, int zn,
                       const float* __restrict__ x, const float* __restrict__ W1,
                       bf16* __restrict__ ybf) {
    const int bid = blockIdx.x;
    const int t = threadIdx.x;
    if (bid < PNB) {
        // ---- bhist ----
        __shared__ int h[NBKT];
        h[t] = 0;
        __syncthreads();
        long base = (long)bid * EPB;
        for (int u = 0; u < 8; u++) {
            long e = base + u * 256 + t;
            if (e < N_EDGES) atomicAdd(&h[dst[e] >> 9], 1);
        }
        __syncthreads();
        if (h[t]) atomicAdd(&ghist[t], h[t]);
    } else if (bid < PNB + ZB) {
        // ---- zero accumulators (pooled .. zstats; ghist excluded) ----
        int i = (bid - PNB) * 256 + t;
        const int st = ZB * 256;
        for (; i < zn; i += st) zp[i] = 0;
    } else {
        // ---- proj0: 4 nodes per wave, x staged transposed [k][r] ----
        __shared__ __align__(16) float xshT[4][IN_CH][4];   // 8 KB
        const int wave = t >> 6, lane = t & 63;
        const int nb = (bid - PNB - ZB) * 16 + wave * 4;    // 6250*16 == 100000
        #pragma unroll
        for (int r = 0; r < 4; r++) {
            float2 v = ((const float2*)(x + (long)(nb + r) * IN_CH))[lane];
            xshT[wave][2 * lane][r]     = v.x;
            xshT[wave][2 * lane + 1][r] = v.y;
        }
        // per-wave LDS slice: wave-lockstep + compiler lgkmcnt; no barrier
        f32x2 aA = {0.f, 0.f}, aB = {0.f, 0.f};
        #pragma unroll 8
        for (int k = 0; k < IN_CH; k++) {
            f32x4 q = *(const f32x4*)&xshT[wave][k][0];  // broadcast read
            float w = W1[k * 64 + lane];
            f32x2 wv = {w, w};
            aA += (f32x2){q.x, q.y} * wv;
            aB += (f32x2){q.z, q.w} * wv;
        }
        ybf[(long)(nb + 0) * 64 + lane] = __float2bfloat16(aA.x);
        ybf[(long)(nb + 1) * 64 + lane] = __float2bfloat16(aA.y);
        ybf[(long)(nb + 2) * 64 + lane] = __float2bfloat16(aB.x);
        ybf[(long)(nb + 3) * 64 + lane] = __float2bfloat16(aB.y);
    }
}

// ---------------- bucket scan + cntg (binary search) + ybf pad-row zero ------
__global__ void bscan(const int* __restrict__ ghist, int* __restrict__ gcursor,
                      int* __restrict__ gbase,
                      const int* __restrict__ batch, int* __restrict__ cntg,
                      bf16* __restrict__ ybfA, bf16* __restrict__ ybfB) {
    __shared__ int sh[NBKT];
    int t = threadIdx.x;                          // 256 threads
    int v = ghist[t];
    sh[t] = v;
    __syncthreads();
    for (int off = 1; off < NBKT; off <<= 1) {
        int a = (t >= off) ? sh[t - off] : 0;
        __syncthreads();
        sh[t] += a;
        __syncthreads();
    }
    gcursor[t] = sh[t] - v;                       // exclusive bucket base (bpart cursor)
    gbase[t]   = sh[t] - v;                       // immutable copy for bfill
    if (t < NUM_GRAPHS) {                         // per-graph node counts
        int g = t, lo = 0, hi = N_NODES;
        while (lo < hi) { int m = (lo + hi) >> 1; if (batch[m] < g) lo = m + 1; else hi = m; }
        int lb = lo;
        lo = 0; hi = N_NODES;
        while (lo < hi) { int m = (lo + hi) >> 1; if (batch[m] < g + 1) lo = m + 1; else hi = m; }
        cntg[g] = lo - lb;
    }
    if (t < HID) {                                // sentinel zero-row for tail-free gather
        ybfA[(long)N_NODES * HID + t] = __float2bfloat16(0.f);
        ybfB[(long)N_NODES * HID + t] = __float2bfloat16(0.f);
    }
}

// ---------------- partition edges into bucket order (packed 4-B records) -----
// record = src | (dst&511)<<17  (src < 2^17, local dst < 2^9)
__global__ void bpart(const int* __restrict__ src, const int* __restrict__ dst,
                      int* __restrict__ gcursor, int* __restrict__ epart) {
    __shared__ int h[NBKT];
    __shared__ int cur[NBKT];
    int t = threadIdx.x;
    h[t] = 0;
    __syncthreads();
    long base = (long)blockIdx.x * EPB;
    int myd[8], mys[8];
    for (int u = 0; u < 8; u++) {
        long e = base + u * 256 + t;
        if (e < N_EDGES) {
            myd[u] = dst[e];
            mys[u] = src[e];
            atomicAdd(&h[myd[u] >> 9], 1);
        } else myd[u] = -1;
    }
    __syncthreads();
    if (h[t]) cur[t] = atomicAdd(&gcursor[t], h[t]);
    __syncthreads();
    for (int u = 0; u < 8; u++) {
        if (myd[u] >= 0) {
            int pos = atomicAdd(&cur[myd[u] >> 9], 1);
            epart[pos] = mys[u] | ((myd[u] & 511) << 17);
        }
    }
}

// ---------------- per-slice LDS counting sort -> coalesced CSR fill ----------
// 4 sub-blocks per 512-node bucket (784 blocks total, ~3/CU): each handles a
// 128-node slice, scanning the bucket's records (~8.2K, L1/L2-resident) and
// filtering its slice. Fixes round-6 bfill's parallelism starvation (196
// blocks, 46KB LDS, no TLP). Row writes are full 128B lines (deg32 ints,
// 256B-aligned rows) -> no write-allocate amplification.
__global__ __launch_bounds__(256)
void bfill(const int* __restrict__ epart, const int* __restrict__ gbase,
           const int* __restrict__ ghist, int* __restrict__ cnt,
           int* __restrict__ col) {
    __shared__ int lcnt[128];
    __shared__ int loff[128];
    __shared__ int lsrc[SUBCAP];
    const int b = blockIdx.x >> 2;                // 512-node bucket 0..195
    const int q = blockIdx.x & 3;                 // 128-node slice 0..3
    const int t = threadIdx.x;                    // 256 threads
    const int n0 = (b << 9) + (q << 7);
    if (n0 >= N_NODES) return;                    // uniform: whole block exits
    const int nN = min(128, N_NODES - n0);
    const int base = gbase[b];
    const int m = ghist[b];
    const int lo = q << 7;                        // local9 range [lo, lo+128)

    if (t < 128) lcnt[t] = 0;
    __syncthreads();
    // pass 1: per-node degree (slice filter)
    for (int e = t; e < m; e += 256) {
        int ln = (int)((uint32)epart[base + e] >> 17) - lo;
        if ((uint32)ln < 128u) atomicAdd(&lcnt[ln], 1);
    }
    __syncthreads();
    // inclusive Hillis-Steele scan over 128 counts
    if (t < 128) loff[t] = lcnt[t];
    __syncthreads();
    for (int off = 1; off < 128; off <<= 1) {
        int a = (t < 128 && t >= off) ? loff[t - off] : 0;
        __syncthreads();
        if (t < 128) loff[t] += a;
        __syncthreads();
    }
    int ex = 0;
    if (t < 128) ex = loff[t] - lcnt[t];          // exclusive offset
    __syncthreads();
    if (t < 128) { loff[t] = ex; lcnt[t] = 0; }   // lcnt reused as cursor
    __syncthreads();
    // pass 2: scatter srcs into per-node runs
    for (int e = t; e < m; e += 256) {
        uint32 v = (uint32)epart[base + e];
        int ln = (int)(v >> 17) - lo;
        if ((uint32)ln < 128u) {
            int slot = atomicAdd(&lcnt[ln], 1);
            lsrc[loff[ln] + slot] = (int)(v & 0x1FFFFu);
        }
    }
    __syncthreads();
    // write rows: data + sentinel pad to deg32, int4 stores; plus cnt
    if (t < nN) {
        int deg = lcnt[t];
        int st  = loff[t];
        int n   = n0 + t;
        cnt[n] = deg;
        int d32 = (deg + 31) & ~31;
        int* row = col + n * CAP;
        for (int s4 = 0; s4 < d32; s4 += 4) {
            int4 qv;
            qv.x = (s4 + 0 < deg) ? lsrc[st + s4 + 0] : N_NODES;
            qv.y = (s4 + 1 < deg) ? lsrc[st + s4 + 1] : N_NODES;
            qv.z = (s4 + 2 < deg) ? lsrc[st + s4 + 2] : N_NODES;
            qv.w = (s4 + 3 < deg) ? lsrc[st + s4 + 3] : N_NODES;
            *(int4*)(row + s4) = qv;
        }
    }
}

// ---------------- fused layer: b128 gather -> relu -> W2 -> pool (+W1n) ------
// FROZEN from round 5 (control). Each wave owns 4 nodes. Gather: 8 edge-groups
// (lane>>3) x 8 channels/lane; one global_load_dwordx4 per 8 rows per step.
// Group partials reduce via conflict-free LDS exchange (stride 65). MLPs:
// scalar-FMA form (packed f32 not double-rate on CDNA4 -- round-3 lesson).
template <bool HAS_NEXT>
__global__ __launch_bounds__(256, 6)
void layer_fused(const bf16* __restrict__ ybf, const int* __restrict__ cnt,
                 const int* __restrict__ col, const int* __restrict__ batch,
                 const float* __restrict__ b1, const float* __restrict__ W2,
                 const float* __restrict__ b2, const float* __restrict__ W1n,
                 bf16* __restrict__ ynext, float* __restrict__ pooled_l) {
    __shared__ float csh[4][8][65];               // group partials (stride 65: conflict-free)
    __shared__ float tsh[4][4][HID];              // t rows, 4 KB
    __shared__ float hsh[4][4][HID];              // h rows, 4 KB
    __shared__ float psh[4][HID];                 // pooling partials, 1 KB
    const int wave = threadIdx.x >> 6, lane = threadIdx.x & 63;
    const int eg = lane >> 3;                     // edge group 0..7
    const int j  = lane & 7;                      // dword-quad index in row
    const uint32 joff = (uint32)j * 16u;
    const int nA = blockIdx.x * 16;               // 6250 blocks
    const int nW = nA + wave * 4;                 // this wave's first node
    const char* ybase = (const char*)ybf;

    // ---- phase 1: gather + t = relu(y_self + b1 + agg) for 4 nodes ----
    #pragma unroll
    for (int r = 0; r < 4; r++) {
        const int n = __builtin_amdgcn_readfirstlane(nW + r);
        const int deg32 = __builtin_amdgcn_readfirstlane((cnt[n] + 31) & ~31);
        const int s = n * CAP;                    // < 6.4M, fits int
        float acc[8] = {0.f, 0.f, 0.f, 0.f, 0.f, 0.f, 0.f, 0.f};
        for (int i = 0; i < deg32; i += 32) {
            uint4 p[4];
            #pragma unroll
            for (int t = 0; t < 4; t++) {
                int c = col[s + i + 8 * t + eg];   // 8-lane broadcast vector load
                uint32 off = ((uint32)c << 7) + joff;
                p[t] = *(const uint4*)(ybase + off);
            }
            #pragma unroll
            for (int t = 0; t < 4; t++) {
                f32x2 f0 = unpk2(p[t].x); acc[0] += f0.x; acc[1] += f0.y;
                f32x2 f1 = unpk2(p[t].y); acc[2] += f1.x; acc[3] += f1.y;
                f32x2 f2 = unpk2(p[t].z); acc[4] += f2.x; acc[5] += f2.y;
                f32x2 f3 = unpk2(p[t].w); acc[6] += f3.x; acc[7] += f3.y;
            }
        }
        #pragma unroll
        for (int d = 0; d < 8; d++) csh[wave][eg][8 * j + d] = acc[d];
        // per-wave LDS slice: lockstep + compiler lgkmcnt; no barrier
        float sumv = 0.f;
        #pragma unroll
        for (int ee = 0; ee < 8; ee++) sumv += csh[wave][ee][lane];
        float t = bf2f(ybf[(long)n * 64 + lane]) + b1[lane] + sumv;
        tsh[wave][r][lane] = fmaxf(t, 0.f);
    }

    // ---- phase 2: h = relu(t @ W2 + b2), weights loaded once per wave ----
    float hv0, hv1, hv2, hv3;
    {
        const float bb = b2[lane];
        float h0 = bb, h1 = bb, h2 = bb, h3 = bb;
        for (int k = 0; k < 64; k += 4) {
            float4 t0 = *(const float4*)&tsh[wave][0][k];
            float4 t1 = *(const float4*)&tsh[wave][1][k];
            float4 t2 = *(const float4*)&tsh[wave][2][k];
            float4 t3 = *(const float4*)&tsh[wave][3][k];
            float w0 = W2[(k + 0) * 64 + lane];
            float w1 = W2[(k + 1) * 64 + lane];
            float w2 = W2[(k + 2) * 64 + lane];
            float w3 = W2[(k + 3) * 64 + lane];
            h0 += t0.x * w0 + t0.y * w1 + t0.z * w2 + t0.w * w3;
            h1 += t1.x * w0 + t1.y * w1 + t1.z * w2 + t1.w * w3;
            h2 += t2.x * w0 + t2.y * w1 + t2.z * w2 + t2.w * w3;
            h3 += t3.x * w0 + t3.y * w1 + t3.z * w2 + t3.w * w3;
        }
        hv0 = fmaxf(h0, 0.f); hv1 = fmaxf(h1, 0.f);
        hv2 = fmaxf(h2, 0.f); hv3 = fmaxf(h3, 0.f);
    }
    hsh[wave][0][lane] = hv0;
    hsh[wave][1][lane] = hv1;
    hsh[wave][2][lane] = hv2;
    hsh[wave][3][lane] = hv3;

    // ---- phase 3: ynext = h @ W1n (next layer's first linear, no bias) ----
    if (HAS_NEXT) {               // reads only own wave's hsh slice: no barrier
        float y0 = 0.f, y1 = 0.f, y2 = 0.f, y3 = 0.f;
        for (int k = 0; k < 64; k += 4) {
            float4 g0 = *(const float4*)&hsh[wave][0][k];
            float4 g1 = *(const float4*)&hsh[wave][1][k];
            float4 g2 = *(const float4*)&hsh[wave][2][k];
            float4 g3 = *(const float4*)&hsh[wave][3][k];
            float w0 = W1n[(k + 0) * 64 + lane];
            float w1 = W1n[(k + 1) * 64 + lane];
            float w2 = W1n[(k + 2) * 64 + lane];
            float w3 = W1n[(k + 3) * 64 + lane];
            y0 += g0.x * w0 + g0.y * w1 + g0.z * w2 + g0.w * w3;
            y1 += g1.x * w0 + g1.y * w1 + g1.z * w2 + g1.w * w3;
            y2 += g2.x * w0 + g2.y * w1 + g2.z * w2 + g2.w * w3;
            y3 += g3.x * w0 + g3.y * w1 + g3.z * w2 + g3.w * w3;
        }
        ynext[(long)(nW + 0) * 64 + lane] = __float2bfloat16(y0);
        ynext[(long)(nW + 1) * 64 + lane] = __float2bfloat16(y1);
        ynext[(long)(nW + 2) * 64 + lane] = __float2bfloat16(y2);
        ynext[(long)(nW + 3) * 64 + lane] = __float2bfloat16(y3);
    }

    // ---- pooling: 16 nodes -> 1 atomic when block is graph-uniform ----
    const int gA = __builtin_amdgcn_readfirstlane(batch[nA]);
    const int gZ = __builtin_amdgcn_readfirstlane(batch[nA + 15]);
    float* rep = pooled_l + (long)(blockIdx.x & (NREP - 1)) * NUM_GRAPHS * HID;
    if (gA == gZ) {               // ~98% of blocks: whole block same graph
        psh[wave][lane] = (hv0 + hv1) + (hv2 + hv3);
        __syncthreads();
        if (wave == 0) {
            float ssum = (psh[0][lane] + psh[1][lane]) + (psh[2][lane] + psh[3][lane]);
            atomicAdd(&rep[gA * 64 + lane], ssum);
        }
    } else {                      // graph boundary inside block: per-node atomics
        const int g0 = __builtin_amdgcn_readfirstlane(batch[nW + 0]);
        atomicAdd(&rep[g0 * 64 + lane], hv0);
        const int g1 = __builtin_amdgcn_readfirstlane(batch[nW + 1]);
        atomicAdd(&rep[g1 * 64 + lane], hv1);
        const int g2 = __builtin_amdgcn_readfirstlane(batch[nW + 2]);
        atomicAdd(&rep[g2 * 64 + lane], hv2);
        const int g3 = __builtin_amdgcn_readfirstlane(batch[nW + 3]);
        atomicAdd(&rep[g3 * 64 + lane], hv3);
    }
}

// ---------------- JK proj + classifier Linear1 + BN-stat atomics -------------
__global__ void jk_cls1(const float* __restrict__ pooled, const int* __restrict__ cntg,
                        const float* __restrict__ Wjk, const float* __restrict__ bjk,
                        const float* __restrict__ Wc1, const float* __restrict__ bc1,
                        float* __restrict__ Z, float* __restrict__ zstats) {
    __shared__ __align__(16) float sh[4][HID];    // per-layer summed pooled rows
    __shared__ float pacc[4][HID];                // per-wave partial pjk
    __shared__ __align__(16) float pj[HID];       // full pjk row
    __shared__ float zacc[4][HID];                // per-wave partial Z
    const int g = blockIdx.x;                     // 128 blocks
    const int wave = threadIdx.x >> 6, j = threadIdx.x & 63;

    // stage 1: wave w = layer w. Sum NREP replicas, then partial JK matmul.
    float s = 0.f;
    for (int r = 0; r < NREP; r++)
        s += pooled[((long)(wave * NREP + r) * NUM_GRAPHS + g) * 64 + j];
    sh[wave][j] = s;                              // own-wave slice: lockstep, no barrier
    const float* W = Wjk + (long)wave * HID * 64;
    float a = 0.f;
    for (int k = 0; k < 64; k += 4) {
        f32x4 sv = *(const f32x4*)&sh[wave][k];
        a += sv.x * W[(k + 0) * 64 + j];
        a += sv.y * W[(k + 1) * 64 + j];
        a += sv.z * W[(k + 2) * 64 + j];
        a += sv.w * W[(k + 3) * 64 + j];
    }
    pacc[wave][j] = a;
    __syncthreads();

    // full pjk row (every thread computes same value for its j)
    if (wave == 0)
        pj[j] = (float)cntg[g] * bjk[j]
              + (pacc[0][j] + pacc[1][j]) + (pacc[2][j] + pacc[3][j]);
    __syncthreads();

    // stage 2: wave w handles k in [16w, 16w+16) of Z = pjk @ Wc1
    float z = 0.f;
    for (int k = 16 * wave; k < 16 * wave + 16; k += 4) {
        f32x4 pv = *(const f32x4*)&pj[k];
        z += pv.x * Wc1[(k + 0) * 64 + j];
        z += pv.y * Wc1[(k + 1) * 64 + j];
        z += pv.z * Wc1[(k + 2) * 64 + j];
        z += pv.w * Wc1[(k + 3) * 64 + j];
    }
    zacc[wave][j] = z;
    __syncthreads();
    if (wave == 0) {
        float zv = bc1[j] + (zacc[0][j] + zacc[1][j]) + (zacc[2][j] + zacc[3][j]);
        Z[g * 64 + j] = zv;
        atomicAdd(&zstats[j], zv);
        atomicAdd(&zstats[HID + j], zv * zv);
    }
}

// ---------------- classifier tail: BN(batch stats) -> ReLU -> Linear ---------
__global__ void cls2(const float* __restrict__ Z, const float* __restrict__ zstats,
                     const float* __restrict__ gamma, const float* __restrict__ beta,
                     const float* __restrict__ Wc2, const float* __restrict__ bc2,
                     float* __restrict__ out) {
    __shared__ float v[HID];
    const int g = blockIdx.x, j = threadIdx.x;    // 128 blocks x 64 threads
    float mu = zstats[j] * (1.f / NUM_GRAPHS);
    float var = zstats[HID + j] * (1.f / NUM_GRAPHS) - mu * mu;
    float rs = rsqrtf(var + BN_EPS);
    float zv = Z[g * 64 + j];
    v[j] = fmaxf(gamma[j] * (zv - mu) * rs + beta[j], 0.f);
    // single wave: lockstep + compiler lgkmcnt; no barrier
    if (j < OUT_CH) {
        float acc = bc2[j];
        for (int k = 0; k < 64; k++) acc += v[k] * Wc2[k * OUT_CH + j];
        out[g * OUT_CH + j] = acc;
    }
}

// -----------------------------------------------------------------------------
extern "C" void kernel_launch(void* const* d_in, const int* in_sizes, int n_in,
                              void* d_out, int out_size, void* d_ws, size_t ws_size,
                              hipStream_t stream) {
    const float* x     = (const float*)d_in[0];
    const int*   ei    = (const int*)d_in[1];
    const int*   batch = (const int*)d_in[2];
    const float* W1f   = (const float*)d_in[3];
    const float* b1f   = (const float*)d_in[4];
    const float* W2f   = (const float*)d_in[5];
    const float* b2f   = (const float*)d_in[6];
    const float* W1r   = (const float*)d_in[7];
    const float* b1r   = (const float*)d_in[8];
    const float* W2r   = (const float*)d_in[9];
    const float* b2r   = (const float*)d_in[10];
    const float* Wjk   = (const float*)d_in[11];
    const float* bjk   = (const float*)d_in[12];
    const float* Wc1   = (const float*)d_in[13];
    const float* bc1   = (const float*)d_in[14];
    const float* gamma = (const float*)d_in[15];
    const float* beta  = (const float*)d_in[16];
    const float* Wc2   = (const float*)d_in[17];
    const float* bc2   = (const float*)d_in[18];

    const int* src = ei;
    const int* dst = ei + N_EDGES;

    // workspace layout (all segments 8-B aligned). ghist sits OUTSIDE the
    // zeroed span (stage1 zeroes concurrently with bhist atomics on ghist).
    float* ws        = (float*)d_ws;
    float* Z         = ws;                                      // 8192 floats (cls Z)
    bf16*  ybfA      = (bf16*)(Z + NUM_GRAPHS * HID);           // (N+1)*64 bf16
    bf16*  ybfB      = ybfA + (long)(N_NODES + 1) * HID;        // (N+1)*64 bf16
    int*   cnt       = (int*)(ybfB + (long)(N_NODES + 1) * HID);// 100000 (written by bfill)
    float* pooled    = (float*)(cnt + N_NODES);                 // 4*8*8192 floats
    int*   gcursor   = (int*)(pooled + (long)N_LAYERS * NREP * NUM_GRAPHS * HID); // 256
    int*   gbase     = gcursor + NBKT;                          // 256
    int*   cntg      = gbase + NBKT;                            // 128
    float* zstats    = (float*)(cntg + NUM_GRAPHS);             // 128 (sum | sumsq)
    int*   ghist     = (int*)(zstats + 2 * HID);                // 256 (zeroed separately)
    int*   col       = ghist + NBKT;                            // 6.4M ints
    int*   epart     = col + (long)N_NODES * CAP;               // 1.6M packed ints
    // zeroed span: pooled .. zstats (gcursor/gbase/cntg rewritten by bscan)
    const int ZN = N_LAYERS * NREP * NUM_GRAPHS * HID
                 + 2 * NBKT + NUM_GRAPHS + 2 * HID;

    // ---- ghist pre-clear (kernel, not memset: graph-capture-safe) ----
    zero_i<<<1, 256, 0, stream>>>(ghist, NBKT);

    // ---- stage1: bhist | zero | proj0 fused (all independent) ----
    stage1<<<PNB + ZB + P0B, 256, 0, stream>>>(dst, ghist, (int*)pooled, ZN,
                                               x, W1f, ybfA);
    bscan<<<1, 256, 0, stream>>>(ghist, gcursor, gbase, batch, cntg, ybfA, ybfB);
    bpart<<<PNB, 256, 0, stream>>>(src, dst, gcursor, epart);
    bfill<<<NBUCK * 4, 256, 0, stream>>>(epart, gbase, ghist, cnt, col);

    // ---- 4 fused layers (16 nodes per block: 4 waves x 4 nodes/wave) ----
    const int NB = N_NODES / 16;                                // 6250
    const long PL = (long)NREP * NUM_GRAPHS * HID;
    layer_fused<true><<<NB, 256, 0, stream>>>(
        ybfA, cnt, col, batch, b1f, W2f, b2f,
        W1r, ybfB, pooled);
    layer_fused<true><<<NB, 256, 0, stream>>>(
        ybfB, cnt, col, batch, b1r, W2r, b2r,
        W1r + (long)1 * HID * HID, ybfA, pooled + 1 * PL);
    layer_fused<true><<<NB, 256, 0, stream>>>(
        ybfA, cnt, col, batch, b1r + HID, W2r + (long)1 * HID * HID, b2r + HID,
        W1r + (long)2 * HID * HID, ybfB, pooled + 2 * PL);
    layer_fused<false><<<NB, 256, 0, stream>>>(
        ybfB, cnt, col, batch, b1r + 2 * HID, W2r + (long)2 * HID * HID, b2r + 2 * HID,
        nullptr, nullptr, pooled + 3 * PL);

    // ---- JK + classifier: wide tail (128 blocks each) ----
    jk_cls1<<<NUM_GRAPHS, 256, 0, stream>>>(pooled, cntg, Wjk, bjk, Wc1, bc1,
                                            Z, zstats);
    cls2<<<NUM_GRAPHS, 64, 0, stream>>>(Z, zstats, gamma, beta, Wc2, bc2,
                                        (float*)d_out);
}

// Round 9
// 378.398 us; speedup vs baseline: 1.9343x; 1.1172x over previous
//
#include <hip/hip_runtime.h>
#include <hip/hip_bf16.h>

#define N_NODES    100000
#define N_EDGES    1600000
#define IN_CH      128
#define HID        64
#define N_LAYERS   4
#define OUT_CH     10
#define NUM_GRAPHS 128
#define BN_EPS     1e-5f
#define CAP        64             // padded CSR row capacity; P(deg>64) ~ 1e-19 at Poisson(16)
#define NREP       8              // pooled replicas (cuts per-address atomic chains 8x)
#define NBKT       256            // dst>>9 -> buckets 0..195 (256 slots for pow2 LDS)
#define NBUCK      196            // ceil(100000 / 512) actual buckets
#define EPB        2048           // edges per block in partition kernels
#define PNB        782            // ceil(1.6M / 2048)
#define SUBCAP     2688           // per-128-node-slice edge capacity (mean 2048, sd 45: 14 sigma)
#define ZB         360            // zero blocks inside stage1
#define P0B        6250           // proj0 blocks inside stage1
#define NWMAT      7              // fragment-ordered weight matrices (4 W2 + 3 W1n)

typedef __hip_bfloat16 bf16;
typedef unsigned int uint32;
typedef float f32x2 __attribute__((ext_vector_type(2)));
typedef float f32x4 __attribute__((ext_vector_type(4)));
typedef short s16x8 __attribute__((ext_vector_type(8)));   // 8 bf16 (4 VGPRs)

__device__ __forceinline__ float bf2f(bf16 v) { return __bfloat162float(v); }
// unpack packed bf16x2 dword -> f32x2 pair (bf16 -> f32 is <<16)
__device__ __forceinline__ f32x2 unpk2(uint32 p) {
    f32x2 r;
    r.x = __uint_as_float(p << 16);
    r.y = __uint_as_float(p & 0xffff0000u);
    return r;
}
__device__ __forceinline__ short f2bs(float f) {
    bf16 b = __float2bfloat16(f);
    return *reinterpret_cast<short*>(&b);
}

// ---------------- zero helper (also used for ghist pre-clear) ----------------
__global__ void zero_i(int* __restrict__ p, int n) {
    int i = blockIdx.x * 256 + threadIdx.x;
    int st = gridDim.x * 256;
    for (; i < n; i += st) p[i] = 0;
}

// ---------------- stage1: fused bhist | zero | proj0 | wprep -----------------
// blocks [0,782): edge-bucket histogram; [782,1142): zero accum region;
// [1142,7392): layer-0 pre-projection; [7392,7399): MFMA weight-fragment prep.
__global__ void stage1(const int* __restrict__ dst, int* __restrict__ ghist,
                       int* __restrict__ zp, int zn,
                       const float* __restrict__ x, const float* __restrict__ W1,
                       bf16* __restrict__ ybf,
                       const float* __restrict__ W2f, const float* __restrict__ W2r,
                       const float* __restrict__ W1r, bf16* __restrict__ wfrag) {
    const int bid = blockIdx.x;
    const int t = threadIdx.x;
    if (bid < PNB) {
        // ---- bhist ----
        __shared__ int h[NBKT];
        h[t] = 0;
        __syncthreads();
        long base = (long)bid * EPB;
        for (int u = 0; u < 8; u++) {
            long e = base + u * 256 + t;
            if (e < N_EDGES) atomicAdd(&h[dst[e] >> 9], 1);
        }
        __syncthreads();
        if (h[t]) atomicAdd(&ghist[t], h[t]);
    } else if (bid < PNB + ZB) {
        // ---- zero accumulators (pooled .. zstats; ghist excluded) ----
        int i = (bid - PNB) * 256 + t;
        const int st = ZB * 256;
        for (; i < zn; i += st) zp[i] = 0;
    } else if (bid < PNB + ZB + P0B) {
        // ---- proj0: 4 nodes per wave, x staged transposed [k][r] ----
        __shared__ __align__(16) float xshT[4][IN_CH][4];   // 8 KB
        const int wave = t >> 6, lane = t & 63;
        const int nb = (bid - PNB - ZB) * 16 + wave * 4;    // 6250*16 == 100000
        #pragma unroll
        for (int r = 0; r < 4; r++) {
            float2 v = ((const float2*)(x + (long)(nb + r) * IN_CH))[lane];
            xshT[wave][2 * lane][r]     = v.x;
            xshT[wave][2 * lane + 1][r] = v.y;
        }
        // per-wave LDS slice: wave-lockstep + compiler lgkmcnt; no barrier
        f32x2 aA = {0.f, 0.f}, aB = {0.f, 0.f};
        #pragma unroll 8
        for (int k = 0; k < IN_CH; k++) {
            f32x4 q = *(const f32x4*)&xshT[wave][k][0];  // broadcast read
            float w = W1[k * 64 + lane];
            f32x2 wv = {w, w};
            aA += (f32x2){q.x, q.y} * wv;
            aB += (f32x2){q.z, q.w} * wv;
        }
        ybf[(long)(nb + 0) * 64 + lane] = __float2bfloat16(aA.x);
        ybf[(long)(nb + 1) * 64 + lane] = __float2bfloat16(aA.y);
        ybf[(long)(nb + 2) * 64 + lane] = __float2bfloat16(aB.x);
        ybf[(long)(nb + 3) * 64 + lane] = __float2bfloat16(aB.y);
    } else {
        // ---- wprep: B-operand fragment-ordered bf16 weights (mfma 16x16x32)
        // frag[(tile*2+ks)*64 + lane][j] = W[ks*32 + 8*(lane>>4) + j][16*tile + (lane&15)]
        int mi = bid - (PNB + ZB + P0B);              // 0..6
        const float* W = (mi == 0) ? W2f
                       : (mi <= 3) ? W2r + (long)(mi - 1) * HID * HID
                                   : W1r + (long)(mi - 4) * HID * HID;
        bf16* out = wfrag + mi * HID * HID;
        for (int u = 0; u < 2; u++) {
            int idx = u * 256 + t;                    // (tile*2+ks)*64 + lane
            int lane = idx & 63, tk = idx >> 6;
            int kbase = (tk & 1) * 32 + 8 * (lane >> 4);
            int c = (tk >> 1) * 16 + (lane & 15);
            #pragma unroll
            for (int j = 0; j < 8; j++)
                out[idx * 8 + j] = __float2bfloat16(W[(kbase + j) * 64 + c]);
        }
    }
}

// ---------------- bucket scan + cntg (binary search) + ybf pad-row zero ------
__global__ void bscan(const int* __restrict__ ghist, int* __restrict__ gcursor,
                      int* __restrict__ gbase,
                      const int* __restrict__ batch, int* __restrict__ cntg,
                      bf16* __restrict__ ybfA, bf16* __restrict__ ybfB) {
    __shared__ int sh[NBKT];
    int t = threadIdx.x;                          // 256 threads
    int v = ghist[t];
    sh[t] = v;
    __syncthreads();
    for (int off = 1; off < NBKT; off <<= 1) {
        int a = (t >= off) ? sh[t - off] : 0;
        __syncthreads();
        sh[t] += a;
        __syncthreads();
    }
    gcursor[t] = sh[t] - v;                       // exclusive bucket base (bpart cursor)
    gbase[t]   = sh[t] - v;                       // immutable copy for bfill
    if (t < NUM_GRAPHS) {                         // per-graph node counts
        int g = t, lo = 0, hi = N_NODES;
        while (lo < hi) { int m = (lo + hi) >> 1; if (batch[m] < g) lo = m + 1; else hi = m; }
        int lb = lo;
        lo = 0; hi = N_NODES;
        while (lo < hi) { int m = (lo + hi) >> 1; if (batch[m] < g + 1) lo = m + 1; else hi = m; }
        cntg[g] = lo - lb;
    }
    if (t < HID) {                                // sentinel zero-row for tail-free gather
        ybfA[(long)N_NODES * HID + t] = __float2bfloat16(0.f);
        ybfB[(long)N_NODES * HID + t] = __float2bfloat16(0.f);
    }
}

// ---------------- partition edges into bucket order (packed 4-B records) -----
// record = src | (dst&511)<<17  (src < 2^17, local dst < 2^9)
__global__ void bpart(const int* __restrict__ src, const int* __restrict__ dst,
                      int* __restrict__ gcursor, int* __restrict__ epart) {
    __shared__ int h[NBKT];
    __shared__ int cur[NBKT];
    int t = threadIdx.x;
    h[t] = 0;
    __syncthreads();
    long base = (long)blockIdx.x * EPB;
    int myd[8], mys[8];
    for (int u = 0; u < 8; u++) {
        long e = base + u * 256 + t;
        if (e < N_EDGES) {
            myd[u] = dst[e];
            mys[u] = src[e];
            atomicAdd(&h[myd[u] >> 9], 1);
        } else myd[u] = -1;
    }
    __syncthreads();
    if (h[t]) cur[t] = atomicAdd(&gcursor[t], h[t]);
    __syncthreads();
    for (int u = 0; u < 8; u++) {
        if (myd[u] >= 0) {
            int pos = atomicAdd(&cur[myd[u] >> 9], 1);
            epart[pos] = mys[u] | ((myd[u] & 511) << 17);
        }
    }
}

// ---------------- per-slice LDS counting sort -> coalesced CSR fill ----------
__global__ __launch_bounds__(256)
void bfill(const int* __restrict__ epart, const int* __restrict__ gbase,
           const int* __restrict__ ghist, int* __restrict__ cnt,
           int* __restrict__ col) {
    __shared__ int lcnt[128];
    __shared__ int loff[128];
    __shared__ int lsrc[SUBCAP];
    const int b = blockIdx.x >> 2;                // 512-node bucket 0..195
    const int q = blockIdx.x & 3;                 // 128-node slice 0..3
    const int t = threadIdx.x;                    // 256 threads
    const int n0 = (b << 9) + (q << 7);
    if (n0 >= N_NODES) return;                    // uniform: whole block exits
    const int nN = min(128, N_NODES - n0);
    const int base = gbase[b];
    const int m = ghist[b];
    const int lo = q << 7;                        // local9 range [lo, lo+128)

    if (t < 128) lcnt[t] = 0;
    __syncthreads();
    // pass 1: per-node degree (slice filter)
    for (int e = t; e < m; e += 256) {
        int ln = (int)((uint32)epart[base + e] >> 17) - lo;
        if ((uint32)ln < 128u) atomicAdd(&lcnt[ln], 1);
    }
    __syncthreads();
    // inclusive Hillis-Steele scan over 128 counts
    if (t < 128) loff[t] = lcnt[t];
    __syncthreads();
    for (int off = 1; off < 128; off <<= 1) {
        int a = (t < 128 && t >= off) ? loff[t - off] : 0;
        __syncthreads();
        if (t < 128) loff[t] += a;
        __syncthreads();
    }
    int ex = 0;
    if (t < 128) ex = loff[t] - lcnt[t];          // exclusive offset
    __syncthreads();
    if (t < 128) { loff[t] = ex; lcnt[t] = 0; }   // lcnt reused as cursor
    __syncthreads();
    // pass 2: scatter srcs into per-node runs
    for (int e = t; e < m; e += 256) {
        uint32 v = (uint32)epart[base + e];
        int ln = (int)(v >> 17) - lo;
        if ((uint32)ln < 128u) {
            int slot = atomicAdd(&lcnt[ln], 1);
            lsrc[loff[ln] + slot] = (int)(v & 0x1FFFFu);
        }
    }
    __syncthreads();
    // write rows: data + sentinel pad to deg32, int4 stores; plus cnt
    if (t < nN) {
        int deg = lcnt[t];
        int st  = loff[t];
        int n   = n0 + t;
        cnt[n] = deg;
        int d32 = (deg + 31) & ~31;
        int* row = col + n * CAP;
        for (int s4 = 0; s4 < d32; s4 += 4) {
            int4 qv;
            qv.x = (s4 + 0 < deg) ? lsrc[st + s4 + 0] : N_NODES;
            qv.y = (s4 + 1 < deg) ? lsrc[st + s4 + 1] : N_NODES;
            qv.z = (s4 + 2 < deg) ? lsrc[st + s4 + 2] : N_NODES;
            qv.w = (s4 + 3 < deg) ? lsrc[st + s4 + 3] : N_NODES;
            *(int4*)(row + s4) = qv;
        }
    }
}

// ---------------- fused layer: b128 gather -> MFMA MLP -> pool (+W1n) --------
// Gather unchanged (round-5 form). MLPs now on matrix cores: block computes
// T[16][64] bf16 in LDS (144-B rows: 2-way bank alias, free), each wave owns
// one 16-col output tile; H = relu(T@W2+b2) and Y = H@W1n are 2 mfma
// 16x16x32_bf16 each, weights loaded from fragment-ordered global (1 dwordx4
// per lane per mfma). D-layout: col=lane&15, row=4*(lane>>4)+reg [m89].
template <bool HAS_NEXT>
__global__ __launch_bounds__(256, 6)
void layer_fused(const bf16* __restrict__ ybf, const int* __restrict__ cnt,
                 const int* __restrict__ col, const int* __restrict__ batch,
                 const float* __restrict__ b1, const bf16* __restrict__ w2frag,
                 const float* __restrict__ b2, const bf16* __restrict__ w1nfrag,
                 bf16* __restrict__ ynext, float* __restrict__ pooled_l) {
    __shared__ float csh[4][8][65];               // group partials (stride 65: conflict-free)
    __shared__ __align__(16) short Tsh[16][72];   // t rows bf16, 144-B stride
    __shared__ __align__(16) short Hsh[16][72];   // h rows bf16
    const int wave = threadIdx.x >> 6, lane = threadIdx.x & 63;
    const int eg = lane >> 3;                     // edge group 0..7
    const int j  = lane & 7;                      // dword-quad index in row
    const uint32 joff = (uint32)j * 16u;
    const int nA = blockIdx.x * 16;               // 6250 blocks
    const int nW = nA + wave * 4;                 // this wave's first node
    const char* ybase = (const char*)ybf;

    // ---- phase 1: gather + t = relu(y_self + b1 + agg) for 4 nodes ----
    #pragma unroll
    for (int r = 0; r < 4; r++) {
        const int n = __builtin_amdgcn_readfirstlane(nW + r);
        const int deg32 = __builtin_amdgcn_readfirstlane((cnt[n] + 31) & ~31);
        const int s = n * CAP;                    // < 6.4M, fits int
        float acc[8] = {0.f, 0.f, 0.f, 0.f, 0.f, 0.f, 0.f, 0.f};
        for (int i = 0; i < deg32; i += 32) {
            uint4 p[4];
            #pragma unroll
            for (int t = 0; t < 4; t++) {
                int c = col[s + i + 8 * t + eg];   // 8-lane broadcast vector load
                uint32 off = ((uint32)c << 7) + joff;
                p[t] = *(const uint4*)(ybase + off);
            }
            #pragma unroll
            for (int t = 0; t < 4; t++) {
                f32x2 f0 = unpk2(p[t].x); acc[0] += f0.x; acc[1] += f0.y;
                f32x2 f1 = unpk2(p[t].y); acc[2] += f1.x; acc[3] += f1.y;
                f32x2 f2 = unpk2(p[t].z); acc[4] += f2.x; acc[5] += f2.y;
                f32x2 f3 = unpk2(p[t].w); acc[6] += f3.x; acc[7] += f3.y;
            }
        }
        #pragma unroll
        for (int d = 0; d < 8; d++) csh[wave][eg][8 * j + d] = acc[d];
        // per-wave LDS slice: lockstep + compiler lgkmcnt; no barrier
        float sumv = 0.f;
        #pragma unroll
        for (int ee = 0; ee < 8; ee++) sumv += csh[wave][ee][lane];
        float tv = bf2f(ybf[(long)n * 64 + lane]) + b1[lane] + sumv;
        Tsh[4 * wave + r][lane] = f2bs(fmaxf(tv, 0.f));
    }
    __syncthreads();                              // T complete (A spans all 16 rows)

    // ---- phase 2: H = relu(T @ W2 + b2), 2x mfma_f32_16x16x32_bf16 ----
    const int c15 = lane & 15, g16 = lane >> 4;
    s16x8 a0 = *(const s16x8*)((const char*)Tsh + c15 * 144 + g16 * 16);
    s16x8 a1 = *(const s16x8*)((const char*)Tsh + c15 * 144 + g16 * 16 + 64);
    const s16x8* w2q = (const s16x8*)w2frag;
    f32x4 hacc = {0.f, 0.f, 0.f, 0.f};
    hacc = __builtin_amdgcn_mfma_f32_16x16x32_bf16(a0, w2q[(wave * 2 + 0) * 64 + lane], hacc, 0, 0, 0);
    hacc = __builtin_amdgcn_mfma_f32_16x16x32_bf16(a1, w2q[(wave * 2 + 1) * 64 + lane], hacc, 0, 0, 0);
    const float bb = b2[16 * wave + c15];
    float hv[4];
    #pragma unroll
    for (int i = 0; i < 4; i++) hv[i] = fmaxf(hacc[i] + bb, 0.f);

    // ---- phase 3: Y = H @ W1n (no bias), same MFMA structure ----
    if (HAS_NEXT) {
        #pragma unroll
        for (int i = 0; i < 4; i++)                // lane holds H[4*g16+i][16w+c15]
            Hsh[4 * g16 + i][16 * wave + c15] = f2bs(hv[i]);
        __syncthreads();                           // H complete
        s16x8 h0 = *(const s16x8*)((const char*)Hsh + c15 * 144 + g16 * 16);
        s16x8 h1 = *(const s16x8*)((const char*)Hsh + c15 * 144 + g16 * 16 + 64);
        const s16x8* w1q = (const s16x8*)w1nfrag;
        f32x4 yac = {0.f, 0.f, 0.f, 0.f};
        yac = __builtin_amdgcn_mfma_f32_16x16x32_bf16(h0, w1q[(wave * 2 + 0) * 64 + lane], yac, 0, 0, 0);
        yac = __builtin_amdgcn_mfma_f32_16x16x32_bf16(h1, w1q[(wave * 2 + 1) * 64 + lane], yac, 0, 0, 0);
        #pragma unroll
        for (int i = 0; i < 4; i++)
            ynext[(long)(nA + 4 * g16 + i) * 64 + 16 * wave + c15] = __float2bfloat16(yac[i]);
    }

    // ---- pooling from D-layout regs: shfl_xor over the 4 row-groups ----
    const int gA = __builtin_amdgcn_readfirstlane(batch[nA]);
    const int gZ = __builtin_amdgcn_readfirstlane(batch[nA + 15]);
    float* rep = pooled_l + (long)(blockIdx.x & (NREP - 1)) * NUM_GRAPHS * HID;
    if (gA == gZ) {               // ~98% of blocks: whole block same graph
        float ps = (hv[0] + hv[1]) + (hv[2] + hv[3]);
        ps += __shfl_xor(ps, 32);
        ps += __shfl_xor(ps, 16);
        if (g16 == 0)             // lanes 0-15: full col sums for this wave's tile
            atomicAdd(&rep[gA * 64 + 16 * wave + c15], ps);
    } else {                      // graph boundary inside block: per-node atomics
        #pragma unroll
        for (int i = 0; i < 4; i++) {
            int gb = batch[nA + 4 * g16 + i];
            atomicAdd(&rep[gb * 64 + 16 * wave + c15], hv[i]);
        }
    }
}

// ---------------- JK proj + classifier Linear1 + BN-stat atomics -------------
__global__ void jk_cls1(const float* __restrict__ pooled, const int* __restrict__ cntg,
                        const float* __restrict__ Wjk, const float* __restrict__ bjk,
                        const float* __restrict__ Wc1, const float* __restrict__ bc1,
                        float* __restrict__ Z, float* __restrict__ zstats) {
    __shared__ __align__(16) float sh[4][HID];    // per-layer summed pooled rows
    __shared__ float pacc[4][HID];                // per-wave partial pjk
    __shared__ __align__(16) float pj[HID];       // full pjk row
    __shared__ float zacc[4][HID];                // per-wave partial Z
    const int g = blockIdx.x;                     // 128 blocks
    const int wave = threadIdx.x >> 6, j = threadIdx.x & 63;

    // stage 1: wave w = layer w. Sum NREP replicas, then partial JK matmul.
    float s = 0.f;
    for (int r = 0; r < NREP; r++)
        s += pooled[((long)(wave * NREP + r) * NUM_GRAPHS + g) * 64 + j];
    sh[wave][j] = s;                              // own-wave slice: lockstep, no barrier
    const float* W = Wjk + (long)wave * HID * 64;
    float a = 0.f;
    for (int k = 0; k < 64; k += 4) {
        f32x4 sv = *(const f32x4*)&sh[wave][k];
        a += sv.x * W[(k + 0) * 64 + j];
        a += sv.y * W[(k + 1) * 64 + j];
        a += sv.z * W[(k + 2) * 64 + j];
        a += sv.w * W[(k + 3) * 64 + j];
    }
    pacc[wave][j] = a;
    __syncthreads();

    // full pjk row (every thread computes same value for its j)
    if (wave == 0)
        pj[j] = (float)cntg[g] * bjk[j]
              + (pacc[0][j] + pacc[1][j]) + (pacc[2][j] + pacc[3][j]);
    __syncthreads();

    // stage 2: wave w handles k in [16w, 16w+16) of Z = pjk @ Wc1
    float z = 0.f;
    for (int k = 16 * wave; k < 16 * wave + 16; k += 4) {
        f32x4 pv = *(const f32x4*)&pj[k];
        z += pv.x * Wc1[(k + 0) * 64 + j];
        z += pv.y * Wc1[(k + 1) * 64 + j];
        z += pv.z * Wc1[(k + 2) * 64 + j];
        z += pv.w * Wc1[(k + 3) * 64 + j];
    }
    zacc[wave][j] = z;
    __syncthreads();
    if (wave == 0) {
        float zv = bc1[j] + (zacc[0][j] + zacc[1][j]) + (zacc[2][j] + zacc[3][j]);
        Z[g * 64 + j] = zv;
        atomicAdd(&zstats[j], zv);
        atomicAdd(&zstats[HID + j], zv * zv);
    }
}

// ---------------- classifier tail: BN(batch stats) -> ReLU -> Linear ---------
__global__ void cls2(const float* __restrict__ Z, const float* __restrict__ zstats,
                     const float* __restrict__ gamma, const float* __restrict__ beta,
                     const float* __restrict__ Wc2, const float* __restrict__ bc2,
                     float* __restrict__ out) {
    __shared__ float v[HID];
    const int g = blockIdx.x, j = threadIdx.x;    // 128 blocks x 64 threads
    float mu = zstats[j] * (1.f / NUM_GRAPHS);
    float var = zstats[HID + j] * (1.f / NUM_GRAPHS) - mu * mu;
    float rs = rsqrtf(var + BN_EPS);
    float zv = Z[g * 64 + j];
    v[j] = fmaxf(gamma[j] * (zv - mu) * rs + beta[j], 0.f);
    // single wave: lockstep + compiler lgkmcnt; no barrier
    if (j < OUT_CH) {
        float acc = bc2[j];
        for (int k = 0; k < 64; k++) acc += v[k] * Wc2[k * OUT_CH + j];
        out[g * OUT_CH + j] = acc;
    }
}

// -----------------------------------------------------------------------------
extern "C" void kernel_launch(void* const* d_in, const int* in_sizes, int n_in,
                              void* d_out, int out_size, void* d_ws, size_t ws_size,
                              hipStream_t stream) {
    const float* x     = (const float*)d_in[0];
    const int*   ei    = (const int*)d_in[1];
    const int*   batch = (const int*)d_in[2];
    const float* W1f   = (const float*)d_in[3];
    const float* b1f   = (const float*)d_in[4];
    const float* W2f   = (const float*)d_in[5];
    const float* b2f   = (const float*)d_in[6];
    const float* W1r   = (const float*)d_in[7];
    const float* b1r   = (const float*)d_in[8];
    const float* W2r   = (const float*)d_in[9];
    const float* b2r   = (const float*)d_in[10];
    const float* Wjk   = (const float*)d_in[11];
    const float* bjk   = (const float*)d_in[12];
    const float* Wc1   = (const float*)d_in[13];
    const float* bc1   = (const float*)d_in[14];
    const float* gamma = (const float*)d_in[15];
    const float* beta  = (const float*)d_in[16];
    const float* Wc2   = (const float*)d_in[17];
    const float* bc2   = (const float*)d_in[18];

    const int* src = ei;
    const int* dst = ei + N_EDGES;

    // workspace layout (all segments 8-B aligned). ghist sits OUTSIDE the
    // zeroed span (stage1 zeroes concurrently with bhist atomics on ghist).
    float* ws        = (float*)d_ws;
    float* Z         = ws;                                      // 8192 floats (cls Z)
    bf16*  ybfA      = (bf16*)(Z + NUM_GRAPHS * HID);           // (N+1)*64 bf16
    bf16*  ybfB      = ybfA + (long)(N_NODES + 1) * HID;        // (N+1)*64 bf16
    int*   cnt       = (int*)(ybfB + (long)(N_NODES + 1) * HID);// 100000 (written by bfill)
    float* pooled    = (float*)(cnt + N_NODES);                 // 4*8*8192 floats
    int*   gcursor   = (int*)(pooled + (long)N_LAYERS * NREP * NUM_GRAPHS * HID); // 256
    int*   gbase     = gcursor + NBKT;                          // 256
    int*   cntg      = gbase + NBKT;                            // 128
    float* zstats    = (float*)(cntg + NUM_GRAPHS);             // 128 (sum | sumsq)
    int*   ghist     = (int*)(zstats + 2 * HID);                // 256 (zeroed separately)
    int*   col       = ghist + NBKT;                            // 6.4M ints
    int*   epart     = col + (long)N_NODES * CAP;               // 1.6M packed ints
    bf16*  wfrag     = (bf16*)(epart + N_EDGES);                // 7*4096 bf16 (56 KB)
    // zeroed span: pooled .. zstats (gcursor/gbase/cntg rewritten by bscan)
    const int ZN = N_LAYERS * NREP * NUM_GRAPHS * HID
                 + 2 * NBKT + NUM_GRAPHS + 2 * HID;

    // ---- ghist pre-clear (kernel, not memset: graph-capture-safe) ----
    zero_i<<<1, 256, 0, stream>>>(ghist, NBKT);

    // ---- stage1: bhist | zero | proj0 | wprep fused (all independent) ----
    stage1<<<PNB + ZB + P0B + NWMAT, 256, 0, stream>>>(
        dst, ghist, (int*)pooled, ZN, x, W1f, ybfA, W2f, W2r, W1r, wfrag);
    bscan<<<1, 256, 0, stream>>>(ghist, gcursor, gbase, batch, cntg, ybfA, ybfB);
    bpart<<<PNB, 256, 0, stream>>>(src, dst, gcursor, epart);
    bfill<<<NBUCK * 4, 256, 0, stream>>>(epart, gbase, ghist, cnt, col);

    // ---- 4 fused layers (16 nodes per block; MFMA MLP) ----
    const int NB = N_NODES / 16;                                // 6250
    const long PL = (long)NREP * NUM_GRAPHS * HID;
    const int WM = HID * HID;                                   // 4096 elems / matrix
    layer_fused<true><<<NB, 256, 0, stream>>>(
        ybfA, cnt, col, batch, b1f, wfrag + 0 * WM, b2f,
        wfrag + 4 * WM, ybfB, pooled);
    layer_fused<true><<<NB, 256, 0, stream>>>(
        ybfB, cnt, col, batch, b1r, wfrag + 1 * WM, b2r,
        wfrag + 5 * WM, ybfA, pooled + 1 * PL);
    layer_fused<true><<<NB, 256, 0, stream>>>(
        ybfA, cnt, col, batch, b1r + HID, wfrag + 2 * WM, b2r + HID,
        wfrag + 6 * WM, ybfB, pooled + 2 * PL);
    layer_fused<false><<<NB, 256, 0, stream>>>(
        ybfB, cnt, col, batch, b1r + 2 * HID, wfrag + 3 * WM, b2r + 2 * HID,
        nullptr, nullptr, pooled + 3 * PL);

    // ---- JK + classifier: wide tail (128 blocks each) ----
    jk_cls1<<<NUM_GRAPHS, 256, 0, stream>>>(pooled, cntg, Wjk, bjk, Wc1, bc1,
                                            Z, zstats);
    cls2<<<NUM_GRAPHS, 64, 0, stream>>>(Z, zstats, gamma, beta, Wc2, bc2,
                                        (float*)d_out);
}

// Round 10
// 357.303 us; speedup vs baseline: 2.0485x; 1.0590x over previous
//
#include <hip/hip_runtime.h>
#include <hip/hip_bf16.h>

#define N_NODES    100000
#define N_EDGES    1600000
#define IN_CH      128
#define HID        64
#define N_LAYERS   4
#define OUT_CH     10
#define NUM_GRAPHS 128
#define BN_EPS     1e-5f
#define CAP        64             // padded CSR row capacity; P(deg>64) ~ 1e-19 at Poisson(16)
#define NREP       8              // pooled replicas (cuts per-address atomic chains 8x)
#define NBKT       256            // dst>>9 -> buckets 0..195 (256 slots for pow2 LDS)
#define NBUCK      196            // ceil(100000 / 512) actual buckets
#define EPB        2048           // edges per block in partition kernels
#define PNB        782            // ceil(1.6M / 2048)
#define SUBCAP     2688           // per-128-node-slice edge capacity (mean 2048, sd 45: 14 sigma)
#define ZB         360            // zero blocks inside stage1
#define P0B        6250           // proj0 blocks inside stage1
#define NWMAT      8              // fragment matrices: 4 W2 + 3 W1n + W1f(K=128)

typedef __hip_bfloat16 bf16;
typedef unsigned int uint32;
typedef float f32x2 __attribute__((ext_vector_type(2)));
typedef float f32x4 __attribute__((ext_vector_type(4)));
typedef short s16x8 __attribute__((ext_vector_type(8)));   // 8 bf16 (4 VGPRs)

__device__ __forceinline__ float bf2f(bf16 v) { return __bfloat162float(v); }
// unpack packed bf16x2 dword -> f32x2 pair (bf16 -> f32 is <<16)
__device__ __forceinline__ f32x2 unpk2(uint32 p) {
    f32x2 r;
    r.x = __uint_as_float(p << 16);
    r.y = __uint_as_float(p & 0xffff0000u);
    return r;
}
__device__ __forceinline__ short f2bs(float f) {
    bf16 b = __float2bfloat16(f);
    return *reinterpret_cast<short*>(&b);
}

// ---------------- prep: ghist zero + weight fragment conversion --------------
// block 0: zero ghist. blocks 1..8: convert one weight matrix to MFMA B-frag
// order (bf16). mi 0..6: 64x64 (4 W2, 3 W1n), K=64 (2 k-slices x 4 tiles).
// mi 7: W1f 128x64, K=128 (4 k-slices x 4 tiles). Runs BEFORE stage1 because
// stage1's proj0 blocks consume the W1f fragments (no same-kernel ordering).
__global__ void prep(int* __restrict__ ghist,
                     const float* __restrict__ W1f, const float* __restrict__ W2f,
                     const float* __restrict__ W2r, const float* __restrict__ W1r,
                     bf16* __restrict__ wfrag) {
    const int bid = blockIdx.x, t = threadIdx.x;  // 9 blocks x 256 threads
    if (bid == 0) { ghist[t] = 0; return; }
    const int mi = bid - 1;                       // 0..7
    if (mi < 7) {
        const float* W = (mi == 0) ? W2f
                       : (mi <= 3) ? W2r + (long)(mi - 1) * HID * HID
                                   : W1r + (long)(mi - 4) * HID * HID;
        bf16* out = wfrag + mi * HID * HID;
        for (int u = 0; u < 2; u++) {
            int idx = u * 256 + t;                // (tile*2+ks)*64 + lane
            int lane = idx & 63, tk = idx >> 6;
            int kbase = (tk & 1) * 32 + 8 * (lane >> 4);
            int c = (tk >> 1) * 16 + (lane & 15);
            #pragma unroll
            for (int j = 0; j < 8; j++)
                out[idx * 8 + j] = __float2bfloat16(W[(kbase + j) * 64 + c]);
        }
    } else {
        bf16* out = wfrag + 7 * HID * HID;        // W1f: 1024 frag groups
        for (int u = 0; u < 4; u++) {
            int idx = u * 256 + t;                // (tile*4+ks)*64 + lane
            int lane = idx & 63, tk = idx >> 6;   // 0..15
            int kbase = (tk & 3) * 32 + 8 * (lane >> 4);
            int c = (tk >> 2) * 16 + (lane & 15);
            #pragma unroll
            for (int j = 0; j < 8; j++)
                out[idx * 8 + j] = __float2bfloat16(W1f[(kbase + j) * 64 + c]);
        }
    }
}

// ---------------- stage1: fused bhist | zero | proj0(MFMA) -------------------
// blocks [0,782): edge-bucket histogram; [782,1142): zero accum region;
// [1142,7392): layer-0 projection ybf = bf16(x @ W1f) on matrix cores:
// 16 nodes/block, x cast to bf16 in LDS, 4 mfma_16x16x32 per wave (K=128).
__global__ void stage1(const int* __restrict__ dst, int* __restrict__ ghist,
                       int* __restrict__ zp, int zn,
                       const float* __restrict__ x, const bf16* __restrict__ w1ffrag,
                       bf16* __restrict__ ybf) {
    const int bid = blockIdx.x;
    const int t = threadIdx.x;
    if (bid < PNB) {
        // ---- bhist ----
        __shared__ int h[NBKT];
        h[t] = 0;
        __syncthreads();
        long base = (long)bid * EPB;
        for (int u = 0; u < 8; u++) {
            long e = base + u * 256 + t;
            if (e < N_EDGES) atomicAdd(&h[dst[e] >> 9], 1);
        }
        __syncthreads();
        if (h[t]) atomicAdd(&ghist[t], h[t]);
    } else if (bid < PNB + ZB) {
        // ---- zero accumulators (pooled .. zstats; ghist excluded) ----
        int i = (bid - PNB) * 256 + t;
        const int st = ZB * 256;
        for (; i < zn; i += st) zp[i] = 0;
    } else {
        // ---- proj0 via MFMA: 16 nodes per block ----
        __shared__ __align__(16) short Xsh[16][136];  // 4352 B; 272-B row stride
        const int wave = t >> 6, lane = t & 63;
        const int nb = (bid - PNB - ZB) * 16;         // 6250*16 == 100000
        {   // stage x -> bf16 LDS: thread = (row: t>>4, cols: 8*(t&15)..+8)
            int row = t >> 4, c0 = (t & 15) * 8;
            const float* xr = x + (long)(nb + row) * IN_CH + c0;
            f32x4 v0 = *(const f32x4*)(xr);
            f32x4 v1 = *(const f32x4*)(xr + 4);
            s16x8 b;
            b[0] = f2bs(v0.x); b[1] = f2bs(v0.y); b[2] = f2bs(v0.z); b[3] = f2bs(v0.w);
            b[4] = f2bs(v1.x); b[5] = f2bs(v1.y); b[6] = f2bs(v1.z); b[7] = f2bs(v1.w);
            *(s16x8*)&Xsh[row][c0] = b;
        }
        __syncthreads();
        const int c15 = lane & 15, g16 = lane >> 4;
        const s16x8* wq = (const s16x8*)w1ffrag;
        f32x4 yac = {0.f, 0.f, 0.f, 0.f};
        #pragma unroll
        for (int ks = 0; ks < 4; ks++) {
            s16x8 a = *(const s16x8*)((const char*)Xsh + c15 * 272 + ks * 64 + g16 * 16);
            yac = __builtin_amdgcn_mfma_f32_16x16x32_bf16(
                a, wq[(wave * 4 + ks) * 64 + lane], yac, 0, 0, 0);
        }
        #pragma unroll
        for (int i = 0; i < 4; i++)               // D: col=lane&15, row=4*(lane>>4)+i
            ybf[(long)(nb + 4 * g16 + i) * 64 + 16 * wave + c15] = __float2bfloat16(yac[i]);
    }
}

// ---------------- bucket scan + cntg (binary search) + ybf pad-row zero ------
__global__ void bscan(const int* __restrict__ ghist, int* __restrict__ gcursor,
                      int* __restrict__ gbase,
                      const int* __restrict__ batch, int* __restrict__ cntg,
                      bf16* __restrict__ ybfA, bf16* __restrict__ ybfB) {
    __shared__ int sh[NBKT];
    int t = threadIdx.x;                          // 256 threads
    int v = ghist[t];
    sh[t] = v;
    __syncthreads();
    for (int off = 1; off < NBKT; off <<= 1) {
        int a = (t >= off) ? sh[t - off] : 0;
        __syncthreads();
        sh[t] += a;
        __syncthreads();
    }
    gcursor[t] = sh[t] - v;                       // exclusive bucket base (bpart cursor)
    gbase[t]   = sh[t] - v;                       // immutable copy for bfill
    if (t < NUM_GRAPHS) {                         // per-graph node counts
        int g = t, lo = 0, hi = N_NODES;
        while (lo < hi) { int m = (lo + hi) >> 1; if (batch[m] < g) lo = m + 1; else hi = m; }
        int lb = lo;
        lo = 0; hi = N_NODES;
        while (lo < hi) { int m = (lo + hi) >> 1; if (batch[m] < g + 1) lo = m + 1; else hi = m; }
        cntg[g] = lo - lb;
    }
    if (t < HID) {                                // sentinel zero-row for tail-free gather
        ybfA[(long)N_NODES * HID + t] = __float2bfloat16(0.f);
        ybfB[(long)N_NODES * HID + t] = __float2bfloat16(0.f);
    }
}

// ---------------- partition edges into bucket order (packed 4-B records) -----
// record = src | (dst&511)<<17  (src < 2^17, local dst < 2^9)
__global__ void bpart(const int* __restrict__ src, const int* __restrict__ dst,
                      int* __restrict__ gcursor, int* __restrict__ epart) {
    __shared__ int h[NBKT];
    __shared__ int cur[NBKT];
    int t = threadIdx.x;
    h[t] = 0;
    __syncthreads();
    long base = (long)blockIdx.x * EPB;
    int myd[8], mys[8];
    for (int u = 0; u < 8; u++) {
        long e = base + u * 256 + t;
        if (e < N_EDGES) {
            myd[u] = dst[e];
            mys[u] = src[e];
            atomicAdd(&h[myd[u] >> 9], 1);
        } else myd[u] = -1;
    }
    __syncthreads();
    if (h[t]) cur[t] = atomicAdd(&gcursor[t], h[t]);
    __syncthreads();
    for (int u = 0; u < 8; u++) {
        if (myd[u] >= 0) {
            int pos = atomicAdd(&cur[myd[u] >> 9], 1);
            epart[pos] = mys[u] | ((myd[u] & 511) << 17);
        }
    }
}

// ---------------- per-slice LDS counting sort -> coalesced CSR fill ----------
__global__ __launch_bounds__(256)
void bfill(const int* __restrict__ epart, const int* __restrict__ gbase,
           const int* __restrict__ ghist, int* __restrict__ cnt,
           int* __restrict__ col) {
    __shared__ int lcnt[128];
    __shared__ int loff[128];
    __shared__ int lsrc[SUBCAP];
    const int b = blockIdx.x >> 2;                // 512-node bucket 0..195
    const int q = blockIdx.x & 3;                 // 128-node slice 0..3
    const int t = threadIdx.x;                    // 256 threads
    const int n0 = (b << 9) + (q << 7);
    if (n0 >= N_NODES) return;                    // uniform: whole block exits
    const int nN = min(128, N_NODES - n0);
    const int base = gbase[b];
    const int m = ghist[b];
    const int lo = q << 7;                        // local9 range [lo, lo+128)

    if (t < 128) lcnt[t] = 0;
    __syncthreads();
    // pass 1: per-node degree (slice filter)
    for (int e = t; e < m; e += 256) {
        int ln = (int)((uint32)epart[base + e] >> 17) - lo;
        if ((uint32)ln < 128u) atomicAdd(&lcnt[ln], 1);
    }
    __syncthreads();
    // inclusive Hillis-Steele scan over 128 counts
    if (t < 128) loff[t] = lcnt[t];
    __syncthreads();
    for (int off = 1; off < 128; off <<= 1) {
        int a = (t < 128 && t >= off) ? loff[t - off] : 0;
        __syncthreads();
        if (t < 128) loff[t] += a;
        __syncthreads();
    }
    int ex = 0;
    if (t < 128) ex = loff[t] - lcnt[t];          // exclusive offset
    __syncthreads();
    if (t < 128) { loff[t] = ex; lcnt[t] = 0; }   // lcnt reused as cursor
    __syncthreads();
    // pass 2: scatter srcs into per-node runs
    for (int e = t; e < m; e += 256) {
        uint32 v = (uint32)epart[base + e];
        int ln = (int)(v >> 17) - lo;
        if ((uint32)ln < 128u) {
            int slot = atomicAdd(&lcnt[ln], 1);
            lsrc[loff[ln] + slot] = (int)(v & 0x1FFFFu);
        }
    }
    __syncthreads();
    // write rows: data + sentinel pad to deg32, int4 stores; plus cnt
    if (t < nN) {
        int deg = lcnt[t];
        int st  = loff[t];
        int n   = n0 + t;
        cnt[n] = deg;
        int d32 = (deg + 31) & ~31;
        int* row = col + n * CAP;
        for (int s4 = 0; s4 < d32; s4 += 4) {
            int4 qv;
            qv.x = (s4 + 0 < deg) ? lsrc[st + s4 + 0] : N_NODES;
            qv.y = (s4 + 1 < deg) ? lsrc[st + s4 + 1] : N_NODES;
            qv.z = (s4 + 2 < deg) ? lsrc[st + s4 + 2] : N_NODES;
            qv.w = (s4 + 3 < deg) ? lsrc[st + s4 + 3] : N_NODES;
            *(int4*)(row + s4) = qv;
        }
    }
}

// ---------------- fused layer: b128 gather -> MFMA MLP -> pool (+W1n) --------
// FROZEN from round 9. Gather: 8 edge-groups x 8 channels/lane. MLPs on
// matrix cores: T[16][72] bf16 LDS, wave owns one 16-col tile, 2 mfma per
// matmul, frag-ordered weights from global. D: col=lane&15, row=4*(lane>>4)+i.
template <bool HAS_NEXT>
__global__ __launch_bounds__(256, 6)
void layer_fused(const bf16* __restrict__ ybf, const int* __restrict__ cnt,
                 const int* __restrict__ col, const int* __restrict__ batch,
                 const float* __restrict__ b1, const bf16* __restrict__ w2frag,
                 const float* __restrict__ b2, const bf16* __restrict__ w1nfrag,
                 bf16* __restrict__ ynext, float* __restrict__ pooled_l) {
    __shared__ float csh[4][8][65];               // group partials (stride 65: conflict-free)
    __shared__ __align__(16) short Tsh[16][72];   // t rows bf16, 144-B stride
    __shared__ __align__(16) short Hsh[16][72];   // h rows bf16
    const int wave = threadIdx.x >> 6, lane = threadIdx.x & 63;
    const int eg = lane >> 3;                     // edge group 0..7
    const int j  = lane & 7;                      // dword-quad index in row
    const uint32 joff = (uint32)j * 16u;
    const int nA = blockIdx.x * 16;               // 6250 blocks
    const int nW = nA + wave * 4;                 // this wave's first node
    const char* ybase = (const char*)ybf;

    // ---- phase 1: gather + t = relu(y_self + b1 + agg) for 4 nodes ----
    #pragma unroll
    for (int r = 0; r < 4; r++) {
        const int n = __builtin_amdgcn_readfirstlane(nW + r);
        const int deg32 = __builtin_amdgcn_readfirstlane((cnt[n] + 31) & ~31);
        const int s = n * CAP;                    // < 6.4M, fits int
        float acc[8] = {0.f, 0.f, 0.f, 0.f, 0.f, 0.f, 0.f, 0.f};
        for (int i = 0; i < deg32; i += 32) {
            uint4 p[4];
            #pragma unroll
            for (int t = 0; t < 4; t++) {
                int c = col[s + i + 8 * t + eg];   // 8-lane broadcast vector load
                uint32 off = ((uint32)c << 7) + joff;
                p[t] = *(const uint4*)(ybase + off);
            }
            #pragma unroll
            for (int t = 0; t < 4; t++) {
                f32x2 f0 = unpk2(p[t].x); acc[0] += f0.x; acc[1] += f0.y;
                f32x2 f1 = unpk2(p[t].y); acc[2] += f1.x; acc[3] += f1.y;
                f32x2 f2 = unpk2(p[t].z); acc[4] += f2.x; acc[5] += f2.y;
                f32x2 f3 = unpk2(p[t].w); acc[6] += f3.x; acc[7] += f3.y;
            }
        }
        #pragma unroll
        for (int d = 0; d < 8; d++) csh[wave][eg][8 * j + d] = acc[d];
        // per-wave LDS slice: lockstep + compiler lgkmcnt; no barrier
        float sumv = 0.f;
        #pragma unroll
        for (int ee = 0; ee < 8; ee++) sumv += csh[wave][ee][lane];
        float tv = bf2f(ybf[(long)n * 64 + lane]) + b1[lane] + sumv;
        Tsh[4 * wave + r][lane] = f2bs(fmaxf(tv, 0.f));
    }
    __syncthreads();                              // T complete (A spans all 16 rows)

    // ---- phase 2: H = relu(T @ W2 + b2), 2x mfma_f32_16x16x32_bf16 ----
    const int c15 = lane & 15, g16 = lane >> 4;
    s16x8 a0 = *(const s16x8*)((const char*)Tsh + c15 * 144 + g16 * 16);
    s16x8 a1 = *(const s16x8*)((const char*)Tsh + c15 * 144 + g16 * 16 + 64);
    const s16x8* w2q = (const s16x8*)w2frag;
    f32x4 hacc = {0.f, 0.f, 0.f, 0.f};
    hacc = __builtin_amdgcn_mfma_f32_16x16x32_bf16(a0, w2q[(wave * 2 + 0) * 64 + lane], hacc, 0, 0, 0);
    hacc = __builtin_amdgcn_mfma_f32_16x16x32_bf16(a1, w2q[(wave * 2 + 1) * 64 + lane], hacc, 0, 0, 0);
    const float bb = b2[16 * wave + c15];
    float hv[4];
    #pragma unroll
    for (int i = 0; i < 4; i++) hv[i] = fmaxf(hacc[i] + bb, 0.f);

    // ---- phase 3: Y = H @ W1n (no bias), same MFMA structure ----
    if (HAS_NEXT) {
        #pragma unroll
        for (int i = 0; i < 4; i++)                // lane holds H[4*g16+i][16w+c15]
            Hsh[4 * g16 + i][16 * wave + c15] = f2bs(hv[i]);
        __syncthreads();                           // H complete
        s16x8 h0 = *(const s16x8*)((const char*)Hsh + c15 * 144 + g16 * 16);
        s16x8 h1 = *(const s16x8*)((const char*)Hsh + c15 * 144 + g16 * 16 + 64);
        const s16x8* w1q = (const s16x8*)w1nfrag;
        f32x4 yac = {0.f, 0.f, 0.f, 0.f};
        yac = __builtin_amdgcn_mfma_f32_16x16x32_bf16(h0, w1q[(wave * 2 + 0) * 64 + lane], yac, 0, 0, 0);
        yac = __builtin_amdgcn_mfma_f32_16x16x32_bf16(h1, w1q[(wave * 2 + 1) * 64 + lane], yac, 0, 0, 0);
        #pragma unroll
        for (int i = 0; i < 4; i++)
            ynext[(long)(nA + 4 * g16 + i) * 64 + 16 * wave + c15] = __float2bfloat16(yac[i]);
    }

    // ---- pooling from D-layout regs: shfl_xor over the 4 row-groups ----
    const int gA = __builtin_amdgcn_readfirstlane(batch[nA]);
    const int gZ = __builtin_amdgcn_readfirstlane(batch[nA + 15]);
    float* rep = pooled_l + (long)(blockIdx.x & (NREP - 1)) * NUM_GRAPHS * HID;
    if (gA == gZ) {               // ~98% of blocks: whole block same graph
        float ps = (hv[0] + hv[1]) + (hv[2] + hv[3]);
        ps += __shfl_xor(ps, 32);
        ps += __shfl_xor(ps, 16);
        if (g16 == 0)             // lanes 0-15: full col sums for this wave's tile
            atomicAdd(&rep[gA * 64 + 16 * wave + c15], ps);
    } else {                      // graph boundary inside block: per-node atomics
        #pragma unroll
        for (int i = 0; i < 4; i++) {
            int gb = batch[nA + 4 * g16 + i];
            atomicAdd(&rep[gb * 64 + 16 * wave + c15], hv[i]);
        }
    }
}

// ---------------- JK proj + classifier Linear1 + BN-stat atomics -------------
__global__ void jk_cls1(const float* __restrict__ pooled, const int* __restrict__ cntg,
                        const float* __restrict__ Wjk, const float* __restrict__ bjk,
                        const float* __restrict__ Wc1, const float* __restrict__ bc1,
                        float* __restrict__ Z, float* __restrict__ zstats) {
    __shared__ __align__(16) float sh[4][HID];    // per-layer summed pooled rows
    __shared__ float pacc[4][HID];                // per-wave partial pjk
    __shared__ __align__(16) float pj[HID];       // full pjk row
    __shared__ float zacc[4][HID];                // per-wave partial Z
    const int g = blockIdx.x;                     // 128 blocks
    const int wave = threadIdx.x >> 6, j = threadIdx.x & 63;

    // stage 1: wave w = layer w. Sum NREP replicas, then partial JK matmul.
    float s = 0.f;
    for (int r = 0; r < NREP; r++)
        s += pooled[((long)(wave * NREP + r) * NUM_GRAPHS + g) * 64 + j];
    sh[wave][j] = s;                              // own-wave slice: lockstep, no barrier
    const float* W = Wjk + (long)wave * HID * 64;
    float a = 0.f;
    for (int k = 0; k < 64; k += 4) {
        f32x4 sv = *(const f32x4*)&sh[wave][k];
        a += sv.x * W[(k + 0) * 64 + j];
        a += sv.y * W[(k + 1) * 64 + j];
        a += sv.z * W[(k + 2) * 64 + j];
        a += sv.w * W[(k + 3) * 64 + j];
    }
    pacc[wave][j] = a;
    __syncthreads();

    // full pjk row (every thread computes same value for its j)
    if (wave == 0)
        pj[j] = (float)cntg[g] * bjk[j]
              + (pacc[0][j] + pacc[1][j]) + (pacc[2][j] + pacc[3][j]);
    __syncthreads();

    // stage 2: wave w handles k in [16w, 16w+16) of Z = pjk @ Wc1
    float z = 0.f;
    for (int k = 16 * wave; k < 16 * wave + 16; k += 4) {
        f32x4 pv = *(const f32x4*)&pj[k];
        z += pv.x * Wc1[(k + 0) * 64 + j];
        z += pv.y * Wc1[(k + 1) * 64 + j];
        z += pv.z * Wc1[(k + 2) * 64 + j];
        z += pv.w * Wc1[(k + 3) * 64 + j];
    }
    zacc[wave][j] = z;
    __syncthreads();
    if (wave == 0) {
        float zv = bc1[j] + (zacc[0][j] + zacc[1][j]) + (zacc[2][j] + zacc[3][j]);
        Z[g * 64 + j] = zv;
        atomicAdd(&zstats[j], zv);
        atomicAdd(&zstats[HID + j], zv * zv);
    }
}

// ---------------- classifier tail: BN(batch stats) -> ReLU -> Linear ---------
__global__ void cls2(const float* __restrict__ Z, const float* __restrict__ zstats,
                     const float* __restrict__ gamma, const float* __restrict__ beta,
                     const float* __restrict__ Wc2, const float* __restrict__ bc2,
                     float* __restrict__ out) {
    __shared__ float v[HID];
    const int g = blockIdx.x, j = threadIdx.x;    // 128 blocks x 64 threads
    float mu = zstats[j] * (1.f / NUM_GRAPHS);
    float var = zstats[HID + j] * (1.f / NUM_GRAPHS) - mu * mu;
    float rs = rsqrtf(var + BN_EPS);
    float zv = Z[g * 64 + j];
    v[j] = fmaxf(gamma[j] * (zv - mu) * rs + beta[j], 0.f);
    // single wave: lockstep + compiler lgkmcnt; no barrier
    if (j < OUT_CH) {
        float acc = bc2[j];
        for (int k = 0; k < 64; k++) acc += v[k] * Wc2[k * OUT_CH + j];
        out[g * OUT_CH + j] = acc;
    }
}

// -----------------------------------------------------------------------------
extern "C" void kernel_launch(void* const* d_in, const int* in_sizes, int n_in,
                              void* d_out, int out_size, void* d_ws, size_t ws_size,
                              hipStream_t stream) {
    const float* x     = (const float*)d_in[0];
    const int*   ei    = (const int*)d_in[1];
    const int*   batch = (const int*)d_in[2];
    const float* W1f   = (const float*)d_in[3];
    const float* b1f   = (const float*)d_in[4];
    const float* W2f   = (const float*)d_in[5];
    const float* b2f   = (const float*)d_in[6];
    const float* W1r   = (const float*)d_in[7];
    const float* b1r   = (const float*)d_in[8];
    const float* W2r   = (const float*)d_in[9];
    const float* b2r   = (const float*)d_in[10];
    const float* Wjk   = (const float*)d_in[11];
    const float* bjk   = (const float*)d_in[12];
    const float* Wc1   = (const float*)d_in[13];
    const float* bc1   = (const float*)d_in[14];
    const float* gamma = (const float*)d_in[15];
    const float* beta  = (const float*)d_in[16];
    const float* Wc2   = (const float*)d_in[17];
    const float* bc2   = (const float*)d_in[18];

    const int* src = ei;
    const int* dst = ei + N_EDGES;

    // workspace layout (all segments 8-B aligned). ghist sits OUTSIDE the
    // zeroed span (stage1 zeroes concurrently with bhist atomics on ghist).
    float* ws        = (float*)d_ws;
    float* Z         = ws;                                      // 8192 floats (cls Z)
    bf16*  ybfA      = (bf16*)(Z + NUM_GRAPHS * HID);           // (N+1)*64 bf16
    bf16*  ybfB      = ybfA + (long)(N_NODES + 1) * HID;        // (N+1)*64 bf16
    int*   cnt       = (int*)(ybfB + (long)(N_NODES + 1) * HID);// 100000 (written by bfill)
    float* pooled    = (float*)(cnt + N_NODES);                 // 4*8*8192 floats
    int*   gcursor   = (int*)(pooled + (long)N_LAYERS * NREP * NUM_GRAPHS * HID); // 256
    int*   gbase     = gcursor + NBKT;                          // 256
    int*   cntg      = gbase + NBKT;                            // 128
    float* zstats    = (float*)(cntg + NUM_GRAPHS);             // 128 (sum | sumsq)
    int*   ghist     = (int*)(zstats + 2 * HID);                // 256 (zeroed in prep)
    int*   col       = ghist + NBKT;                            // 6.4M ints
    int*   epart     = col + (long)N_NODES * CAP;               // 1.6M packed ints
    bf16*  wfrag     = (bf16*)(epart + N_EDGES);                // 7*4096 + 8192 bf16
    // zeroed span: pooled .. zstats (gcursor/gbase/cntg rewritten by bscan)
    const int ZN = N_LAYERS * NREP * NUM_GRAPHS * HID
                 + 2 * NBKT + NUM_GRAPHS + 2 * HID;

    // ---- prep: ghist zero + all weight fragments (before stage1 reads) ----
    prep<<<1 + NWMAT, 256, 0, stream>>>(ghist, W1f, W2f, W2r, W1r, wfrag);

    // ---- stage1: bhist | zero | proj0-MFMA fused (all independent) ----
    stage1<<<PNB + ZB + P0B, 256, 0, stream>>>(
        dst, ghist, (int*)pooled, ZN, x, wfrag + 7 * HID * HID, ybfA);
    bscan<<<1, 256, 0, stream>>>(ghist, gcursor, gbase, batch, cntg, ybfA, ybfB);
    bpart<<<PNB, 256, 0, stream>>>(src, dst, gcursor, epart);
    bfill<<<NBUCK * 4, 256, 0, stream>>>(epart, gbase, ghist, cnt, col);

    // ---- 4 fused layers (16 nodes per block; MFMA MLP) ----
    const int NB = N_NODES / 16;                                // 6250
    const long PL = (long)NREP * NUM_GRAPHS * HID;
    const int WM = HID * HID;                                   // 4096 elems / matrix
    layer_fused<true><<<NB, 256, 0, stream>>>(
        ybfA, cnt, col, batch, b1f, wfrag + 0 * WM, b2f,
        wfrag + 4 * WM, ybfB, pooled);
    layer_fused<true><<<NB, 256, 0, stream>>>(
        ybfB, cnt, col, batch, b1r, wfrag + 1 * WM, b2r,
        wfrag + 5 * WM, ybfA, pooled + 1 * PL);
    layer_fused<true><<<NB, 256, 0, stream>>>(
        ybfA, cnt, col, batch, b1r + HID, wfrag + 2 * WM, b2r + HID,
        wfrag + 6 * WM, ybfB, pooled + 2 * PL);
    layer_fused<false><<<NB, 256, 0, stream>>>(
        ybfB, cnt, col, batch, b1r + 2 * HID, wfrag + 3 * WM, b2r + 2 * HID,
        nullptr, nullptr, pooled + 3 * PL);

    // ---- JK + classifier: wide tail (128 blocks each) ----
    jk_cls1<<<NUM_GRAPHS, 256, 0, stream>>>(pooled, cntg, Wjk, bjk, Wc1, bc1,
                                            Z, zstats);
    cls2<<<NUM_GRAPHS, 64, 0, stream>>>(Z, zstats, gamma, beta, Wc2, bc2,
                                        (float*)d_out);
}